// Round 1
// baseline (2495.601 us; speedup 1.0000x reference)
//
#include <hip/hip_runtime.h>
#include <stddef.h>

// Output layout (fp32):
//   recon    [200,4096,64] @ 0
//   z0_mean  [4096,3]      @ 52428800
//   z0_logvar[4096,3]      @ 52441088
//   traj     [200,4096,3]  @ 52453376
#define OFF_MEAN 52428800
#define OFF_LV   52441088
#define OFF_TRAJ 52453376

__device__ __forceinline__ float sigm_(float x) { return 1.f / (1.f + __expf(-x)); }
__device__ __forceinline__ float tanh_(float x) { float e = __expf(2.f * x); return 1.f - 2.f / (e + 1.f); }
__device__ __forceinline__ float dot4_(float4 a, float4 b) {
    return a.x * b.x + a.y * b.y + a.z * b.z + a.w * b.w;
}

// ---------------------------------------------------------------- GRU + heads
// 256 blocks x 512 threads; 16 batch rows per block; 50 sequential steps.
// thread (r = tid&15, ty = tid>>4) owns 4 hidden units u0 = ty*4 .. +3.
__global__ __launch_bounds__(512) void k_gru(
    const float* __restrict__ obs, const float* __restrict__ eps,
    const float* __restrict__ Wih, const float* __restrict__ Whh,
    const float* __restrict__ bih, const float* __restrict__ bhh,
    const float* __restrict__ meanW, const float* __restrict__ meanB,
    const float* __restrict__ lvW,  const float* __restrict__ lvB,
    float* __restrict__ o_mean, float* __restrict__ o_lv, float* __restrict__ z0)
{
    __shared__ float xs[16 * 68];
    __shared__ float hs[16 * 132];
    __shared__ float mb[16 * 6];
    const int tid = threadIdx.x;
    const int b0  = blockIdx.x * 16;
    const int r   = tid & 15;
    const int ty  = tid >> 4;
    const int u0  = ty * 4;

    for (int i = tid; i < 16 * 132; i += 512) hs[i] = 0.f;

    // hoist biases
    float bR[4], bZ[4], bNi[4], bNh[4];
    #pragma unroll
    for (int m = 0; m < 4; ++m) {
        int u  = u0 + m;
        bR[m]  = bih[u]       + bhh[u];
        bZ[m]  = bih[128 + u] + bhh[128 + u];
        bNi[m] = bih[256 + u];
        bNh[m] = bhh[256 + u];
    }
    __syncthreads();

    const float4* Wih4 = (const float4*)Wih;   // [384][16] f4
    const float4* Whh4 = (const float4*)Whh;   // [384][32] f4

    for (int t = 0; t < 50; ++t) {
        if (tid < 256) {
            float4 v = ((const float4*)(obs + ((size_t)t * 4096 + b0) * 64))[tid];
            *(float4*)&xs[(tid >> 4) * 68 + (tid & 15) * 4] = v;
        }
        __syncthreads();

        float ar[4], az[4], an[4], hn[4];
        #pragma unroll
        for (int m = 0; m < 4; ++m) { ar[m] = 0.f; az[m] = 0.f; an[m] = 0.f; hn[m] = 0.f; }

        const float4* xr = (const float4*)(xs + r * 68);
        const float4* hr = (const float4*)(hs + r * 132);

        #pragma unroll 2
        for (int kc = 0; kc < 16; ++kc) {
            float4 xv = xr[kc];
            #pragma unroll
            for (int m = 0; m < 4; ++m) {
                const int u = u0 + m;
                float4 w0 = Wih4[(u)       * 16 + kc];
                float4 w1 = Wih4[(128 + u) * 16 + kc];
                float4 w2 = Wih4[(256 + u) * 16 + kc];
                ar[m] += dot4_(w0, xv);
                az[m] += dot4_(w1, xv);
                an[m] += dot4_(w2, xv);
            }
        }
        #pragma unroll 2
        for (int kc = 0; kc < 32; ++kc) {
            float4 hv = hr[kc];
            #pragma unroll
            for (int m = 0; m < 4; ++m) {
                const int u = u0 + m;
                float4 w0 = Whh4[(u)       * 32 + kc];
                float4 w1 = Whh4[(128 + u) * 32 + kc];
                float4 w2 = Whh4[(256 + u) * 32 + kc];
                ar[m] += dot4_(w0, hv);
                az[m] += dot4_(w1, hv);
                hn[m] += dot4_(w2, hv);
            }
        }
        float hnew[4];
        #pragma unroll
        for (int m = 0; m < 4; ++m) {
            float rg = sigm_(ar[m] + bR[m]);
            float zg = sigm_(az[m] + bZ[m]);
            float ng = tanh_(an[m] + bNi[m] + rg * (hn[m] + bNh[m]));
            hnew[m]  = (1.f - zg) * ng + zg * hs[r * 132 + u0 + m];
        }
        __syncthreads();
        #pragma unroll
        for (int m = 0; m < 4; ++m) hs[r * 132 + u0 + m] = hnew[m];
        __syncthreads();
    }

    // heads: z0_mean / z0_logvar / z0
    if (tid < 96) {
        int rr = tid / 6, c = tid - rr * 6, j = (c < 3) ? c : c - 3;
        const float* W = (c < 3) ? meanW : lvW;
        const float* B = (c < 3) ? meanB : lvB;
        float acc = B[j];
        const float4* W4 = (const float4*)(W + j * 128);
        const float4* h4 = (const float4*)(hs + rr * 132);
        #pragma unroll 4
        for (int kc = 0; kc < 32; ++kc) acc += dot4_(W4[kc], h4[kc]);
        mb[rr * 6 + c] = acc;
    }
    __syncthreads();
    if (tid < 48) {
        int rr = tid / 3, j = tid - rr * 3;
        int gb = b0 + rr;
        float m  = mb[rr * 6 + j];
        float lv = mb[rr * 6 + j + 3];
        o_mean[gb * 3 + j] = m;
        o_lv[gb * 3 + j]   = lv;
        z0[gb * 3 + j]     = m + eps[gb * 3 + j] * __expf(0.5f * lv);
    }
}

// ---------------------------------------------------------------- dynamics f()
// 8 rows per block; W2 rows live in registers (w2r, thread uu<100 owns row uu,
// rg in {0,1} selects rows 0-3 / 4-7). h1 consumed via LDS broadcast reads.
__device__ __forceinline__ void feval(
    const float* yin, float* fout,
    const float* W1s, const float* b1s, const float* b2s, const float* b3s,
    const float* W3s, float* h1s, float* h2s, float* parts,
    const float4 (&w2r)[25], int tid, int uu, int rg)
{
    // stage 1: h1 = tanh(W1 z + b1)   (800 tasks)
    for (int i = tid; i < 800; i += 256) {
        int rr = i & 7, u = i >> 3;
        float acc = b1s[u] + W1s[u * 3 + 0] * yin[rr * 4 + 0]
                           + W1s[u * 3 + 1] * yin[rr * 4 + 1]
                           + W1s[u * 3 + 2] * yin[rr * 4 + 2];
        h1s[rr * 104 + u] = tanh_(acc);
    }
    __syncthreads();
    // stage 2: h2 = tanh(W2 h1 + b2); W2 row in registers, 4 rows per thread
    if (tid < 200) {
        const float4* H0 = (const float4*)(h1s + (rg * 4 + 0) * 104);
        const float4* H1 = (const float4*)(h1s + (rg * 4 + 1) * 104);
        const float4* H2 = (const float4*)(h1s + (rg * 4 + 2) * 104);
        const float4* H3 = (const float4*)(h1s + (rg * 4 + 3) * 104);
        float a0 = 0.f, a1 = 0.f, a2 = 0.f, a3 = 0.f;
        #pragma unroll
        for (int kc = 0; kc < 25; ++kc) {
            float4 w = w2r[kc];
            a0 += dot4_(w, H0[kc]);
            a1 += dot4_(w, H1[kc]);
            a2 += dot4_(w, H2[kc]);
            a3 += dot4_(w, H3[kc]);
        }
        float bb = b2s[uu];
        h2s[(rg * 4 + 0) * 104 + uu] = tanh_(a0 + bb);
        h2s[(rg * 4 + 1) * 104 + uu] = tanh_(a1 + bb);
        h2s[(rg * 4 + 2) * 104 + uu] = tanh_(a2 + bb);
        h2s[(rg * 4 + 3) * 104 + uu] = tanh_(a3 + bb);
    }
    __syncthreads();
    // stage 3: f = W3 h2 + b3 (split each 100-dot over 4 threads)
    if (tid < 96) {
        int rr = tid / 12, rem = tid - rr * 12, j = rem >> 2, qc = rem & 3;
        const float4* Wj = (const float4*)(W3s + j * 104);
        const float4* Hr = (const float4*)(h2s + rr * 104);
        float acc = 0.f;
        for (int kc = qc; kc < 25; kc += 4) acc += dot4_(Wj[kc], Hr[kc]);
        parts[(rr * 3 + j) * 4 + qc] = acc;
    }
    __syncthreads();
    if (tid < 24) {
        int rr = tid / 3, j = tid - rr * 3;
        const float* p = parts + (rr * 3 + j) * 4;
        fout[rr * 4 + j] = b3s[j] + p[0] + p[1] + p[2] + p[3];
    }
    __syncthreads();
}

// ---------------------------------------------------------------- ODE kernel
// RK4 with h = 0.08 (24 steps) + final h = 0.07, cubic-Hermite dense output
// at the 0.01 grid. 512 blocks x 256 threads, 8 rows per block.
__global__ __launch_bounds__(256) void k_ode(
    const float* __restrict__ dW1, const float* __restrict__ db1,
    const float* __restrict__ dW2, const float* __restrict__ db2,
    const float* __restrict__ dW3, const float* __restrict__ db3,
    const float* __restrict__ z0, float* __restrict__ traj)
{
    __shared__ float W1s[300], b1s[100], b2s[100], b3s[3];
    __shared__ float W3s[3 * 104];
    __shared__ float h1s[8 * 104], h2s[8 * 104];
    __shared__ float ys[32], yt[32], yn[32], f0[32], fo[32], ks[32];
    __shared__ float parts[8 * 3 * 4];

    const int tid = threadIdx.x;
    const int b0  = blockIdx.x * 8;

    for (int i = tid; i < 300; i += 256) W1s[i] = dW1[i];
    if (tid < 100) { b1s[tid] = db1[tid]; b2s[tid] = db2[tid]; }
    if (tid < 3) b3s[tid] = db3[tid];
    for (int i = tid; i < 300; i += 256) {
        int j = i / 100, k = i - j * 100;
        W3s[j * 104 + k] = dW3[i];
    }
    if (tid < 24) { int rr = tid / 3, j = tid - rr * 3; ys[rr * 4 + j] = z0[(b0 + rr) * 3 + j]; }

    float4 w2r[25];
    const int uu = tid % 100;
    const int rg = tid / 100;
    if (tid < 200) {
        const float4* Wg = (const float4*)(dW2 + uu * 100);
        #pragma unroll
        for (int kc = 0; kc < 25; ++kc) w2r[kc] = Wg[kc];
    }
    __syncthreads();

    // traj[0] = z0
    if (tid < 24) {
        int rr = tid / 3, j = tid - rr * 3;
        traj[((size_t)(b0 + rr)) * 3 + j] = ys[rr * 4 + j];
    }

    feval(ys, fo, W1s, b1s, b2s, b3s, W3s, h1s, h2s, parts, w2r, tid, uu, rg);
    if (tid < 24) { int rr = tid / 3, j = tid - rr * 3; f0[rr * 4 + j] = fo[rr * 4 + j]; }
    __syncthreads();

    for (int s = 0; s < 25; ++s) {
        const int   nInt = (s < 24) ? 8 : 7;
        const float hh   = 0.01f * (float)nInt;
        const int   t0   = s * 8;

        if (tid < 24) {
            int rr = tid / 3, j = tid - rr * 3, q = rr * 4 + j;
            ks[q] = f0[q];
            yt[q] = ys[q] + 0.5f * hh * f0[q];
        }
        __syncthreads();
        feval(yt, fo, W1s, b1s, b2s, b3s, W3s, h1s, h2s, parts, w2r, tid, uu, rg); // k2
        if (tid < 24) {
            int rr = tid / 3, j = tid - rr * 3, q = rr * 4 + j;
            ks[q] += 2.f * fo[q];
            yt[q]  = ys[q] + 0.5f * hh * fo[q];
        }
        __syncthreads();
        feval(yt, fo, W1s, b1s, b2s, b3s, W3s, h1s, h2s, parts, w2r, tid, uu, rg); // k3
        if (tid < 24) {
            int rr = tid / 3, j = tid - rr * 3, q = rr * 4 + j;
            ks[q] += 2.f * fo[q];
            yt[q]  = ys[q] + hh * fo[q];
        }
        __syncthreads();
        feval(yt, fo, W1s, b1s, b2s, b3s, W3s, h1s, h2s, parts, w2r, tid, uu, rg); // k4
        if (tid < 24) {
            int rr = tid / 3, j = tid - rr * 3, q = rr * 4 + j;
            ks[q] += fo[q];
            yn[q]  = ys[q] + (hh / 6.f) * ks[q];
        }
        __syncthreads();
        feval(yn, fo, W1s, b1s, b2s, b3s, W3s, h1s, h2s, parts, w2r, tid, uu, rg); // f1

        // emit outputs t0+1 .. t0+nInt
        if (tid < 24 * nInt) {
            int q = tid / 24, rem = tid - q * 24, rr = rem / 3, j = rem - rr * 3;
            int idx = rr * 4 + j;
            float v;
            if (q == nInt - 1) {
                v = yn[idx];
            } else {
                float th  = (float)(q + 1) / (float)nInt;
                float th2 = th * th, th3 = th2 * th;
                float ca = 2.f * th3 - 3.f * th2 + 1.f;
                float cb = th3 - 2.f * th2 + th;
                float cc = 3.f * th2 - 2.f * th3;
                float cd = th3 - th2;
                v = ca * ys[idx] + cb * hh * f0[idx] + cc * yn[idx] + cd * hh * fo[idx];
            }
            traj[((size_t)(t0 + 1 + q) * 4096 + b0 + rr) * 3 + j] = v;
        }
        __syncthreads();
        if (tid < 24) {
            int rr = tid / 3, j = tid - rr * 3, q = rr * 4 + j;
            ys[q] = yn[q];
            f0[q] = fo[q];
        }
        __syncthreads();
    }
}

// ---------------------------------------------------------------- decoder
// 12800 blocks x 256 threads; 64 (t,b)-pairs per block; lane = output channel,
// dec_W2 row held in 16 float4 registers; hd consumed via LDS broadcast.
__global__ __launch_bounds__(256) void k_dec(
    const float* __restrict__ traj, const float* __restrict__ W1, const float* __restrict__ b1,
    const float* __restrict__ W2, const float* __restrict__ b2, float* __restrict__ recon)
{
    __shared__ float zs[64 * 4];
    __shared__ float hd[64 * 68];
    const int tid = threadIdx.x;
    const size_t p0 = (size_t)blockIdx.x * 64;
    const int o = tid & 63, wv = tid >> 6;

    if (tid < 192) { int p = tid / 3, j = tid - p * 3; zs[p * 4 + j] = traj[p0 * 3 + tid]; }
    float4 w2r[16];
    #pragma unroll
    for (int kc = 0; kc < 16; ++kc) w2r[kc] = ((const float4*)W2)[o * 16 + kc];
    const float b2o = b2[o];
    __syncthreads();

    for (int i = tid; i < 4096; i += 256) {
        int p = i >> 6, u = i & 63;
        float acc = b1[u] + W1[u * 3 + 0] * zs[p * 4 + 0]
                          + W1[u * 3 + 1] * zs[p * 4 + 1]
                          + W1[u * 3 + 2] * zs[p * 4 + 2];
        hd[p * 68 + u] = fmaxf(acc, 0.f);
    }
    __syncthreads();

    #pragma unroll 1
    for (int pi = 0; pi < 16; ++pi) {
        int p = wv * 16 + pi;
        const float4* h4 = (const float4*)(hd + p * 68);
        float acc = b2o;
        #pragma unroll
        for (int kc = 0; kc < 16; ++kc) acc += dot4_(w2r[kc], h4[kc]);
        recon[(p0 + p) * 64 + o] = acc;
    }
}

extern "C" void kernel_launch(void* const* d_in, const int* in_sizes, int n_in,
                              void* d_out, int out_size, void* d_ws, size_t ws_size,
                              hipStream_t stream)
{
    const float* obs   = (const float*)d_in[0];
    const float* eps   = (const float*)d_in[1];
    const float* Wih   = (const float*)d_in[2];
    const float* Whh   = (const float*)d_in[3];
    const float* bih   = (const float*)d_in[4];
    const float* bhh   = (const float*)d_in[5];
    const float* meanW = (const float*)d_in[6];
    const float* meanB = (const float*)d_in[7];
    const float* lvW   = (const float*)d_in[8];
    const float* lvB   = (const float*)d_in[9];
    const float* dW1   = (const float*)d_in[10];
    const float* db1   = (const float*)d_in[11];
    const float* dW2   = (const float*)d_in[12];
    const float* db2   = (const float*)d_in[13];
    const float* dW3   = (const float*)d_in[14];
    const float* db3   = (const float*)d_in[15];
    const float* decW1 = (const float*)d_in[16];
    const float* decb1 = (const float*)d_in[17];
    const float* decW2 = (const float*)d_in[18];
    const float* decb2 = (const float*)d_in[19];

    float* out   = (float*)d_out;
    float* recon = out;
    float* omean = out + OFF_MEAN;
    float* olv   = out + OFF_LV;
    float* traj  = out + OFF_TRAJ;
    float* z0    = (float*)d_ws;

    k_gru<<<dim3(256), dim3(512), 0, stream>>>(obs, eps, Wih, Whh, bih, bhh,
                                               meanW, meanB, lvW, lvB, omean, olv, z0);
    k_ode<<<dim3(512), dim3(256), 0, stream>>>(dW1, db1, dW2, db2, dW3, db3, z0, traj);
    k_dec<<<dim3(12800), dim3(256), 0, stream>>>(traj, decW1, decb1, decW2, decb2, recon);
}

// Round 2
// 844.074 us; speedup vs baseline: 2.9566x; 2.9566x over previous
//
#include <hip/hip_runtime.h>
#include <stddef.h>

// Output layout (fp32):
//   recon    [200,4096,64] @ 0
//   z0_mean  [4096,3]      @ 52428800
//   z0_logvar[4096,3]      @ 52441088
//   traj     [200,4096,3]  @ 52453376
#define OFF_MEAN 52428800
#define OFF_LV   52441088
#define OFF_TRAJ 52453376

typedef _Float16 f16x8 __attribute__((ext_vector_type(8)));
typedef _Float16 f16x4 __attribute__((ext_vector_type(4)));
typedef float    f32x4 __attribute__((ext_vector_type(4)));

#define MFMA16(a, b, c) __builtin_amdgcn_mfma_f32_16x16x32_f16((a), (b), (c), 0, 0, 0)

__device__ __forceinline__ float sigm_(float x) { return 1.f / (1.f + __expf(-x)); }
__device__ __forceinline__ float tanh_(float x) { float e = __expf(2.f * x); return 1.f - 2.f / (e + 1.f); }
__device__ __forceinline__ float dot4_(float4 a, float4 b) {
    return a.x * b.x + a.y * b.y + a.z * b.z + a.w * b.w;
}

// ---------------------------------------------------------------- GRU (MFMA)
// 256 blocks x 512 threads (8 waves). 16 batch rows per block, 50 steps.
// gi = x @ Wih^T  : A = x (f16 hi/lo), B = Wih f16 frags in LDS.
// gh = h @ Whh^T  : A = h (f16 hi/lo, LDS XOR-swizzled), B = Whh f16 hi/lo
//                   frags register-resident (96 VGPR/thread, loaded once).
// Wave w owns output tiles w*3 .. w*3+2 (16 rows x 16 cols each, 24 tiles=384).
__global__ __launch_bounds__(512, 2) void k_gru(
    const float* __restrict__ obs, const float* __restrict__ eps,
    const float* __restrict__ Wih, const float* __restrict__ Whh,
    const float* __restrict__ bih, const float* __restrict__ bhh,
    const float* __restrict__ meanW, const float* __restrict__ meanB,
    const float* __restrict__ lvW,  const float* __restrict__ lvB,
    float* __restrict__ o_mean, float* __restrict__ o_lv, float* __restrict__ z0)
{
    __shared__ alignas(16) unsigned short wih_lds[24576];        // 24 tiles x 2 ks x 64 lanes x 8 f16
    __shared__ alignas(16) float gai_s[16 * 388];
    __shared__ alignas(16) float gah_s[16 * 388];
    __shared__ alignas(16) float hm_s[16 * 132];
    __shared__ alignas(16) unsigned short hhi_s[2048], hlo_s[2048];  // [16][128] f16, XOR-swizzled
    __shared__ alignas(16) unsigned short xhi_s[1024], xlo_s[1024];  // [16][64]  f16, XOR-swizzled
    __shared__ alignas(16) float bR_s[128], bZ_s[128], bNi_s[128], bNh_s[128];
    __shared__ float mb_s[96];

    const int tid  = threadIdx.x;
    const int b0   = blockIdx.x * 16;
    const int lane = tid & 63, wv = tid >> 6;
    const int lrow = lane & 15, lkb = lane >> 4;
    const int swA  = (lrow & 7) << 4;

    char* wih_c = (char*)wih_lds;
    char* hhi_c = (char*)hhi_s; char* hlo_c = (char*)hlo_s;
    char* xhi_c = (char*)xhi_s; char* xlo_c = (char*)xlo_s;

    for (int i = tid; i < 16 * 132; i += 512) hm_s[i] = 0.f;
    for (int i = tid; i < 2048; i += 512) { hhi_s[i] = 0; hlo_s[i] = 0; }
    if (tid < 128) {
        bR_s[tid]  = bih[tid] + bhh[tid];
        bZ_s[tid]  = bih[128 + tid] + bhh[128 + tid];
        bNi_s[tid] = bih[256 + tid];
        bNh_s[tid] = bhh[256 + tid];
    }
    // Wih -> LDS fragment blocks (f16 single)
    for (int i = 0; i < 6; ++i) {
        int idx = i * 512 + tid;
        int blk = idx >> 6, ln = idx & 63;
        int tile = blk >> 1, ks = blk & 1;
        int col = tile * 16 + (ln & 15);
        int kb  = ks * 32 + (ln >> 4) * 8;
        const float* wp = Wih + col * 64 + kb;
        float4 a = *(const float4*)wp, b = *(const float4*)(wp + 4);
        float tmp[8] = {a.x, a.y, a.z, a.w, b.x, b.y, b.z, b.w};
        f16x8 hv;
        #pragma unroll
        for (int j = 0; j < 8; ++j) hv[j] = (_Float16)tmp[j];
        *(f16x8*)(wih_c + idx * 16) = hv;
    }
    // Whh -> register fragments (f16 hi + lo)
    f16x8 whhh[3][4], whhl[3][4];
    #pragma unroll
    for (int t3 = 0; t3 < 3; ++t3) {
        #pragma unroll
        for (int ks = 0; ks < 4; ++ks) {
            int col = (wv * 3 + t3) * 16 + lrow;
            int kb  = ks * 32 + lkb * 8;
            const float* wp = Whh + col * 128 + kb;
            float4 a = *(const float4*)wp, b = *(const float4*)(wp + 4);
            float tmp[8] = {a.x, a.y, a.z, a.w, b.x, b.y, b.z, b.w};
            f16x8 hv, lv;
            #pragma unroll
            for (int j = 0; j < 8; ++j) {
                hv[j] = (_Float16)tmp[j];
                lv[j] = (_Float16)(tmp[j] - (float)hv[j]);
            }
            whhh[t3][ks] = hv;
            whhl[t3][ks] = lv;
        }
    }
    __syncthreads();

    for (int t = 0; t < 50; ++t) {
        // ---- stage x tile (fp32 -> f16 hi/lo, swizzled)
        if (tid < 256) {
            int row = tid >> 4, kq = (tid & 15) * 4;
            float4 v = *(const float4*)(obs + ((size_t)t * 4096 + b0 + row) * 64 + kq);
            float tmp[4] = {v.x, v.y, v.z, v.w};
            f16x4 vh, vl;
            #pragma unroll
            for (int j = 0; j < 4; ++j) {
                vh[j] = (_Float16)tmp[j];
                vl[j] = (_Float16)(tmp[j] - (float)vh[j]);
            }
            int xb = row * 128 + ((kq * 2) ^ ((row & 7) << 4));
            *(f16x4*)(xhi_c + xb) = vh;
            *(f16x4*)(xlo_c + xb) = vl;
        }
        __syncthreads();

        // ---- MFMA phase
        f16x8 xh[2], xl[2], hh[4], hl[4];
        #pragma unroll
        for (int ks = 0; ks < 2; ++ks) {
            int off = lrow * 128 + ((ks * 64 + lkb * 16) ^ swA);
            xh[ks] = *(const f16x8*)(xhi_c + off);
            xl[ks] = *(const f16x8*)(xlo_c + off);
        }
        #pragma unroll
        for (int ks = 0; ks < 4; ++ks) {
            int off = lrow * 256 + ((ks * 64 + lkb * 16) ^ swA);
            hh[ks] = *(const f16x8*)(hhi_c + off);
            hl[ks] = *(const f16x8*)(hlo_c + off);
        }
        f32x4 zero4 = {0.f, 0.f, 0.f, 0.f};
        f32x4 ai[3] = {zero4, zero4, zero4};
        f32x4 ah[3] = {zero4, zero4, zero4};
        #pragma unroll
        for (int t3 = 0; t3 < 3; ++t3) {
            int tile = wv * 3 + t3;
            #pragma unroll
            for (int ks = 0; ks < 2; ++ks) {
                f16x8 bw = *(const f16x8*)(wih_c + ((tile * 2 + ks) * 64 + lane) * 16);
                ai[t3] = MFMA16(xh[ks], bw, ai[t3]);
                ai[t3] = MFMA16(xl[ks], bw, ai[t3]);
            }
            #pragma unroll
            for (int ks = 0; ks < 4; ++ks) {
                ah[t3] = MFMA16(hh[ks], whhh[t3][ks], ah[t3]);
                ah[t3] = MFMA16(hl[ks], whhh[t3][ks], ah[t3]);
                ah[t3] = MFMA16(hh[ks], whhl[t3][ks], ah[t3]);
            }
        }
        #pragma unroll
        for (int t3 = 0; t3 < 3; ++t3) {
            int col = (wv * 3 + t3) * 16 + lrow;
            int r0  = lkb * 4;
            #pragma unroll
            for (int i = 0; i < 4; ++i) {
                gai_s[(r0 + i) * 388 + col] = ai[t3][i];
                gah_s[(r0 + i) * 388 + col] = ah[t3][i];
            }
        }
        __syncthreads();

        // ---- gate phase: 512 threads x 4 consecutive units
        {
            const int grow = tid >> 5;
            const int u0   = (tid & 31) * 4;
            const float* gi = gai_s + grow * 388;
            const float* gh = gah_s + grow * 388;
            f32x4 gir = *(const f32x4*)(gi + u0);
            f32x4 giz = *(const f32x4*)(gi + 128 + u0);
            f32x4 gin = *(const f32x4*)(gi + 256 + u0);
            f32x4 ghr = *(const f32x4*)(gh + u0);
            f32x4 ghz = *(const f32x4*)(gh + 128 + u0);
            f32x4 ghn = *(const f32x4*)(gh + 256 + u0);
            f32x4 br  = *(const f32x4*)(bR_s + u0);
            f32x4 bz  = *(const f32x4*)(bZ_s + u0);
            f32x4 bni = *(const f32x4*)(bNi_s + u0);
            f32x4 bnh = *(const f32x4*)(bNh_s + u0);
            f32x4 hold = *(const f32x4*)(hm_s + grow * 132 + u0);
            f32x4 hnew;
            f16x4 nh, nl;
            #pragma unroll
            for (int i = 0; i < 4; ++i) {
                float r = sigm_(gir[i] + ghr[i] + br[i]);
                float zg = sigm_(giz[i] + ghz[i] + bz[i]);
                float n = tanh_(gin[i] + bni[i] + r * (ghn[i] + bnh[i]));
                float hv = (1.f - zg) * n + zg * hold[i];
                hnew[i] = hv;
                _Float16 hhf = (_Float16)hv;
                nh[i] = hhf;
                nl[i] = (_Float16)(hv - (float)hhf);
            }
            *(f32x4*)(hm_s + grow * 132 + u0) = hnew;
            int hb = grow * 256 + ((u0 * 2) ^ ((grow & 7) << 4));
            *(f16x4*)(hhi_c + hb) = nh;
            *(f16x4*)(hlo_c + hb) = nl;
        }
        __syncthreads();
    }

    // ---- heads
    if (tid < 96) {
        int rr = tid / 6, c = tid - rr * 6, j = (c < 3) ? c : c - 3;
        const float* W = (c < 3) ? meanW : lvW;
        const float* B = (c < 3) ? meanB : lvB;
        float acc = B[j];
        const float4* W4 = (const float4*)(W + j * 128);
        const float4* h4 = (const float4*)(hm_s + rr * 132);
        #pragma unroll 4
        for (int kc = 0; kc < 32; ++kc) acc += dot4_(W4[kc], h4[kc]);
        mb_s[rr * 6 + c] = acc;
    }
    __syncthreads();
    if (tid < 48) {
        int rr = tid / 3, j = tid - rr * 3;
        int gb = b0 + rr;
        float m  = mb_s[rr * 6 + j];
        float lv = mb_s[rr * 6 + j + 3];
        o_mean[gb * 3 + j] = m;
        o_lv[gb * 3 + j]   = lv;
        z0[gb * 3 + j]     = m + eps[gb * 3 + j] * __expf(0.5f * lv);
    }
}

// ---------------------------------------------------------------- dynamics f()
__device__ __forceinline__ void feval(
    const float* yin, float* fout,
    const float* W1s, const float* b1s, const float* b2s, const float* b3s,
    const float* W3s, float* h1s, float* h2s, float* parts,
    const float4 (&w2r)[25], int tid, int uu, int rg)
{
    for (int i = tid; i < 800; i += 256) {
        int rr = i & 7, u = i >> 3;
        float acc = b1s[u] + W1s[u * 3 + 0] * yin[rr * 4 + 0]
                           + W1s[u * 3 + 1] * yin[rr * 4 + 1]
                           + W1s[u * 3 + 2] * yin[rr * 4 + 2];
        h1s[rr * 104 + u] = tanh_(acc);
    }
    __syncthreads();
    if (tid < 200) {
        const float4* H0 = (const float4*)(h1s + (rg * 4 + 0) * 104);
        const float4* H1 = (const float4*)(h1s + (rg * 4 + 1) * 104);
        const float4* H2 = (const float4*)(h1s + (rg * 4 + 2) * 104);
        const float4* H3 = (const float4*)(h1s + (rg * 4 + 3) * 104);
        float a0 = 0.f, a1 = 0.f, a2 = 0.f, a3 = 0.f;
        #pragma unroll
        for (int kc = 0; kc < 25; ++kc) {
            float4 w = w2r[kc];
            a0 += dot4_(w, H0[kc]);
            a1 += dot4_(w, H1[kc]);
            a2 += dot4_(w, H2[kc]);
            a3 += dot4_(w, H3[kc]);
        }
        float bb = b2s[uu];
        h2s[(rg * 4 + 0) * 104 + uu] = tanh_(a0 + bb);
        h2s[(rg * 4 + 1) * 104 + uu] = tanh_(a1 + bb);
        h2s[(rg * 4 + 2) * 104 + uu] = tanh_(a2 + bb);
        h2s[(rg * 4 + 3) * 104 + uu] = tanh_(a3 + bb);
    }
    __syncthreads();
    if (tid < 96) {
        int rr = tid / 12, rem = tid - rr * 12, j = rem >> 2, qc = rem & 3;
        const float4* Wj = (const float4*)(W3s + j * 104);
        const float4* Hr = (const float4*)(h2s + rr * 104);
        float acc = 0.f;
        for (int kc = qc; kc < 25; kc += 4) acc += dot4_(Wj[kc], Hr[kc]);
        parts[(rr * 3 + j) * 4 + qc] = acc;
    }
    __syncthreads();
    if (tid < 24) {
        int rr = tid / 3, j = tid - rr * 3;
        const float* p = parts + (rr * 3 + j) * 4;
        fout[rr * 4 + j] = b3s[j] + p[0] + p[1] + p[2] + p[3];
    }
    __syncthreads();
}

// ---------------------------------------------------------------- ODE kernel
__global__ __launch_bounds__(256) void k_ode(
    const float* __restrict__ dW1, const float* __restrict__ db1,
    const float* __restrict__ dW2, const float* __restrict__ db2,
    const float* __restrict__ dW3, const float* __restrict__ db3,
    const float* __restrict__ z0, float* __restrict__ traj)
{
    __shared__ float W1s[300], b1s[100], b2s[100], b3s[3];
    __shared__ float W3s[3 * 104];
    __shared__ float h1s[8 * 104], h2s[8 * 104];
    __shared__ float ys[32], yt[32], yn[32], f0[32], fo[32], ks[32];
    __shared__ float parts[8 * 3 * 4];

    const int tid = threadIdx.x;
    const int b0  = blockIdx.x * 8;

    for (int i = tid; i < 300; i += 256) W1s[i] = dW1[i];
    if (tid < 100) { b1s[tid] = db1[tid]; b2s[tid] = db2[tid]; }
    if (tid < 3) b3s[tid] = db3[tid];
    for (int i = tid; i < 300; i += 256) {
        int j = i / 100, k = i - j * 100;
        W3s[j * 104 + k] = dW3[i];
    }
    if (tid < 24) { int rr = tid / 3, j = tid - rr * 3; ys[rr * 4 + j] = z0[(b0 + rr) * 3 + j]; }

    float4 w2r[25];
    const int uu = tid % 100;
    const int rg = tid / 100;
    if (tid < 200) {
        const float4* Wg = (const float4*)(dW2 + uu * 100);
        #pragma unroll
        for (int kc = 0; kc < 25; ++kc) w2r[kc] = Wg[kc];
    }
    __syncthreads();

    if (tid < 24) {
        int rr = tid / 3, j = tid - rr * 3;
        traj[((size_t)(b0 + rr)) * 3 + j] = ys[rr * 4 + j];
    }

    feval(ys, fo, W1s, b1s, b2s, b3s, W3s, h1s, h2s, parts, w2r, tid, uu, rg);
    if (tid < 24) { int rr = tid / 3, j = tid - rr * 3; f0[rr * 4 + j] = fo[rr * 4 + j]; }
    __syncthreads();

    for (int s = 0; s < 25; ++s) {
        const int   nInt = (s < 24) ? 8 : 7;
        const float hh   = 0.01f * (float)nInt;
        const int   t0   = s * 8;

        if (tid < 24) {
            int rr = tid / 3, j = tid - rr * 3, q = rr * 4 + j;
            ks[q] = f0[q];
            yt[q] = ys[q] + 0.5f * hh * f0[q];
        }
        __syncthreads();
        feval(yt, fo, W1s, b1s, b2s, b3s, W3s, h1s, h2s, parts, w2r, tid, uu, rg);
        if (tid < 24) {
            int rr = tid / 3, j = tid - rr * 3, q = rr * 4 + j;
            ks[q] += 2.f * fo[q];
            yt[q]  = ys[q] + 0.5f * hh * fo[q];
        }
        __syncthreads();
        feval(yt, fo, W1s, b1s, b2s, b3s, W3s, h1s, h2s, parts, w2r, tid, uu, rg);
        if (tid < 24) {
            int rr = tid / 3, j = tid - rr * 3, q = rr * 4 + j;
            ks[q] += 2.f * fo[q];
            yt[q]  = ys[q] + hh * fo[q];
        }
        __syncthreads();
        feval(yt, fo, W1s, b1s, b2s, b3s, W3s, h1s, h2s, parts, w2r, tid, uu, rg);
        if (tid < 24) {
            int rr = tid / 3, j = tid - rr * 3, q = rr * 4 + j;
            ks[q] += fo[q];
            yn[q]  = ys[q] + (hh / 6.f) * ks[q];
        }
        __syncthreads();
        feval(yn, fo, W1s, b1s, b2s, b3s, W3s, h1s, h2s, parts, w2r, tid, uu, rg);

        if (tid < 24 * nInt) {
            int q = tid / 24, rem = tid - q * 24, rr = rem / 3, j = rem - rr * 3;
            int idx = rr * 4 + j;
            float v;
            if (q == nInt - 1) {
                v = yn[idx];
            } else {
                float th  = (float)(q + 1) / (float)nInt;
                float th2 = th * th, th3 = th2 * th;
                float ca = 2.f * th3 - 3.f * th2 + 1.f;
                float cb = th3 - 2.f * th2 + th;
                float cc = 3.f * th2 - 2.f * th3;
                float cd = th3 - th2;
                v = ca * ys[idx] + cb * hh * f0[idx] + cc * yn[idx] + cd * hh * fo[idx];
            }
            traj[((size_t)(t0 + 1 + q) * 4096 + b0 + rr) * 3 + j] = v;
        }
        __syncthreads();
        if (tid < 24) {
            int rr = tid / 3, j = tid - rr * 3, q = rr * 4 + j;
            ys[q] = yn[q];
            f0[q] = fo[q];
        }
        __syncthreads();
    }
}

// ---------------------------------------------------------------- decoder
__global__ __launch_bounds__(256) void k_dec(
    const float* __restrict__ traj, const float* __restrict__ W1, const float* __restrict__ b1,
    const float* __restrict__ W2, const float* __restrict__ b2, float* __restrict__ recon)
{
    __shared__ float zs[64 * 4];
    __shared__ float hd[64 * 68];
    const int tid = threadIdx.x;
    const size_t p0 = (size_t)blockIdx.x * 64;
    const int o = tid & 63, wv = tid >> 6;

    if (tid < 192) { int p = tid / 3, j = tid - p * 3; zs[p * 4 + j] = traj[p0 * 3 + tid]; }
    float4 w2r[16];
    #pragma unroll
    for (int kc = 0; kc < 16; ++kc) w2r[kc] = ((const float4*)W2)[o * 16 + kc];
    const float b2o = b2[o];
    __syncthreads();

    for (int i = tid; i < 4096; i += 256) {
        int p = i >> 6, u = i & 63;
        float acc = b1[u] + W1[u * 3 + 0] * zs[p * 4 + 0]
                          + W1[u * 3 + 1] * zs[p * 4 + 1]
                          + W1[u * 3 + 2] * zs[p * 4 + 2];
        hd[p * 68 + u] = fmaxf(acc, 0.f);
    }
    __syncthreads();

    #pragma unroll 1
    for (int pi = 0; pi < 16; ++pi) {
        int p = wv * 16 + pi;
        const float4* h4 = (const float4*)(hd + p * 68);
        float acc = b2o;
        #pragma unroll
        for (int kc = 0; kc < 16; ++kc) acc += dot4_(w2r[kc], h4[kc]);
        recon[(p0 + p) * 64 + o] = acc;
    }
}

extern "C" void kernel_launch(void* const* d_in, const int* in_sizes, int n_in,
                              void* d_out, int out_size, void* d_ws, size_t ws_size,
                              hipStream_t stream)
{
    const float* obs   = (const float*)d_in[0];
    const float* eps   = (const float*)d_in[1];
    const float* Wih   = (const float*)d_in[2];
    const float* Whh   = (const float*)d_in[3];
    const float* bih   = (const float*)d_in[4];
    const float* bhh   = (const float*)d_in[5];
    const float* meanW = (const float*)d_in[6];
    const float* meanB = (const float*)d_in[7];
    const float* lvW   = (const float*)d_in[8];
    const float* lvB   = (const float*)d_in[9];
    const float* dW1   = (const float*)d_in[10];
    const float* db1   = (const float*)d_in[11];
    const float* dW2   = (const float*)d_in[12];
    const float* db2   = (const float*)d_in[13];
    const float* dW3   = (const float*)d_in[14];
    const float* db3   = (const float*)d_in[15];
    const float* decW1 = (const float*)d_in[16];
    const float* decb1 = (const float*)d_in[17];
    const float* decW2 = (const float*)d_in[18];
    const float* decb2 = (const float*)d_in[19];

    float* out   = (float*)d_out;
    float* recon = out;
    float* omean = out + OFF_MEAN;
    float* olv   = out + OFF_LV;
    float* traj  = out + OFF_TRAJ;
    float* z0    = (float*)d_ws;

    k_gru<<<dim3(256), dim3(512), 0, stream>>>(obs, eps, Wih, Whh, bih, bhh,
                                               meanW, meanB, lvW, lvB, omean, olv, z0);
    k_ode<<<dim3(512), dim3(256), 0, stream>>>(dW1, db1, dW2, db2, dW3, db3, z0, traj);
    k_dec<<<dim3(12800), dim3(256), 0, stream>>>(traj, decW1, decb1, decW2, decb2, recon);
}

// Round 3
// 552.234 us; speedup vs baseline: 4.5191x; 1.5285x over previous
//
#include <hip/hip_runtime.h>
#include <stddef.h>

// Output layout (fp32):
//   recon    [200,4096,64] @ 0
//   z0_mean  [4096,3]      @ 52428800
//   z0_logvar[4096,3]      @ 52441088
//   traj     [200,4096,3]  @ 52453376
#define OFF_MEAN 52428800
#define OFF_LV   52441088
#define OFF_TRAJ 52453376

typedef _Float16 f16x8 __attribute__((ext_vector_type(8)));
typedef _Float16 f16x4 __attribute__((ext_vector_type(4)));
typedef float    f32x4 __attribute__((ext_vector_type(4)));

#define MFMA16(a, b, c) __builtin_amdgcn_mfma_f32_16x16x32_f16((a), (b), (c), 0, 0, 0)

__device__ __forceinline__ float sigm_(float x) { return 1.f / (1.f + __expf(-x)); }
__device__ __forceinline__ float tanh_(float x) { float e = __expf(2.f * x); return 1.f - 2.f / (e + 1.f); }
__device__ __forceinline__ float dot4_(float4 a, float4 b) {
    return a.x * b.x + a.y * b.y + a.z * b.z + a.w * b.w;
}

// ---------------------------------------------------------------- GRU (MFMA)
// (unchanged from round 2)
__global__ __launch_bounds__(512, 2) void k_gru(
    const float* __restrict__ obs, const float* __restrict__ eps,
    const float* __restrict__ Wih, const float* __restrict__ Whh,
    const float* __restrict__ bih, const float* __restrict__ bhh,
    const float* __restrict__ meanW, const float* __restrict__ meanB,
    const float* __restrict__ lvW,  const float* __restrict__ lvB,
    float* __restrict__ o_mean, float* __restrict__ o_lv, float* __restrict__ z0)
{
    __shared__ alignas(16) unsigned short wih_lds[24576];
    __shared__ alignas(16) float gai_s[16 * 388];
    __shared__ alignas(16) float gah_s[16 * 388];
    __shared__ alignas(16) float hm_s[16 * 132];
    __shared__ alignas(16) unsigned short hhi_s[2048], hlo_s[2048];
    __shared__ alignas(16) unsigned short xhi_s[1024], xlo_s[1024];
    __shared__ alignas(16) float bR_s[128], bZ_s[128], bNi_s[128], bNh_s[128];
    __shared__ float mb_s[96];

    const int tid  = threadIdx.x;
    const int b0   = blockIdx.x * 16;
    const int lane = tid & 63, wv = tid >> 6;
    const int lrow = lane & 15, lkb = lane >> 4;
    const int swA  = (lrow & 7) << 4;

    char* wih_c = (char*)wih_lds;
    char* hhi_c = (char*)hhi_s; char* hlo_c = (char*)hlo_s;
    char* xhi_c = (char*)xhi_s; char* xlo_c = (char*)xlo_s;

    for (int i = tid; i < 16 * 132; i += 512) hm_s[i] = 0.f;
    for (int i = tid; i < 2048; i += 512) { hhi_s[i] = 0; hlo_s[i] = 0; }
    if (tid < 128) {
        bR_s[tid]  = bih[tid] + bhh[tid];
        bZ_s[tid]  = bih[128 + tid] + bhh[128 + tid];
        bNi_s[tid] = bih[256 + tid];
        bNh_s[tid] = bhh[256 + tid];
    }
    for (int i = 0; i < 6; ++i) {
        int idx = i * 512 + tid;
        int blk = idx >> 6, ln = idx & 63;
        int tile = blk >> 1, ks = blk & 1;
        int col = tile * 16 + (ln & 15);
        int kb  = ks * 32 + (ln >> 4) * 8;
        const float* wp = Wih + col * 64 + kb;
        float4 a = *(const float4*)wp, b = *(const float4*)(wp + 4);
        float tmp[8] = {a.x, a.y, a.z, a.w, b.x, b.y, b.z, b.w};
        f16x8 hv;
        #pragma unroll
        for (int j = 0; j < 8; ++j) hv[j] = (_Float16)tmp[j];
        *(f16x8*)(wih_c + idx * 16) = hv;
    }
    f16x8 whhh[3][4], whhl[3][4];
    #pragma unroll
    for (int t3 = 0; t3 < 3; ++t3) {
        #pragma unroll
        for (int ks = 0; ks < 4; ++ks) {
            int col = (wv * 3 + t3) * 16 + lrow;
            int kb  = ks * 32 + lkb * 8;
            const float* wp = Whh + col * 128 + kb;
            float4 a = *(const float4*)wp, b = *(const float4*)(wp + 4);
            float tmp[8] = {a.x, a.y, a.z, a.w, b.x, b.y, b.z, b.w};
            f16x8 hv, lv;
            #pragma unroll
            for (int j = 0; j < 8; ++j) {
                hv[j] = (_Float16)tmp[j];
                lv[j] = (_Float16)(tmp[j] - (float)hv[j]);
            }
            whhh[t3][ks] = hv;
            whhl[t3][ks] = lv;
        }
    }
    __syncthreads();

    for (int t = 0; t < 50; ++t) {
        if (tid < 256) {
            int row = tid >> 4, kq = (tid & 15) * 4;
            float4 v = *(const float4*)(obs + ((size_t)t * 4096 + b0 + row) * 64 + kq);
            float tmp[4] = {v.x, v.y, v.z, v.w};
            f16x4 vh, vl;
            #pragma unroll
            for (int j = 0; j < 4; ++j) {
                vh[j] = (_Float16)tmp[j];
                vl[j] = (_Float16)(tmp[j] - (float)vh[j]);
            }
            int xb = row * 128 + ((kq * 2) ^ ((row & 7) << 4));
            *(f16x4*)(xhi_c + xb) = vh;
            *(f16x4*)(xlo_c + xb) = vl;
        }
        __syncthreads();

        f16x8 xh[2], xl[2], hh[4], hl[4];
        #pragma unroll
        for (int ks = 0; ks < 2; ++ks) {
            int off = lrow * 128 + ((ks * 64 + lkb * 16) ^ swA);
            xh[ks] = *(const f16x8*)(xhi_c + off);
            xl[ks] = *(const f16x8*)(xlo_c + off);
        }
        #pragma unroll
        for (int ks = 0; ks < 4; ++ks) {
            int off = lrow * 256 + ((ks * 64 + lkb * 16) ^ swA);
            hh[ks] = *(const f16x8*)(hhi_c + off);
            hl[ks] = *(const f16x8*)(hlo_c + off);
        }
        f32x4 zero4 = {0.f, 0.f, 0.f, 0.f};
        f32x4 ai[3] = {zero4, zero4, zero4};
        f32x4 ah[3] = {zero4, zero4, zero4};
        #pragma unroll
        for (int t3 = 0; t3 < 3; ++t3) {
            int tile = wv * 3 + t3;
            #pragma unroll
            for (int ks = 0; ks < 2; ++ks) {
                f16x8 bw = *(const f16x8*)(wih_c + ((tile * 2 + ks) * 64 + lane) * 16);
                ai[t3] = MFMA16(xh[ks], bw, ai[t3]);
                ai[t3] = MFMA16(xl[ks], bw, ai[t3]);
            }
            #pragma unroll
            for (int ks = 0; ks < 4; ++ks) {
                ah[t3] = MFMA16(hh[ks], whhh[t3][ks], ah[t3]);
                ah[t3] = MFMA16(hl[ks], whhh[t3][ks], ah[t3]);
                ah[t3] = MFMA16(hh[ks], whhl[t3][ks], ah[t3]);
            }
        }
        #pragma unroll
        for (int t3 = 0; t3 < 3; ++t3) {
            int col = (wv * 3 + t3) * 16 + lrow;
            int r0  = lkb * 4;
            #pragma unroll
            for (int i = 0; i < 4; ++i) {
                gai_s[(r0 + i) * 388 + col] = ai[t3][i];
                gah_s[(r0 + i) * 388 + col] = ah[t3][i];
            }
        }
        __syncthreads();

        {
            const int grow = tid >> 5;
            const int u0   = (tid & 31) * 4;
            const float* gi = gai_s + grow * 388;
            const float* gh = gah_s + grow * 388;
            f32x4 gir = *(const f32x4*)(gi + u0);
            f32x4 giz = *(const f32x4*)(gi + 128 + u0);
            f32x4 gin = *(const f32x4*)(gi + 256 + u0);
            f32x4 ghr = *(const f32x4*)(gh + u0);
            f32x4 ghz = *(const f32x4*)(gh + 128 + u0);
            f32x4 ghn = *(const f32x4*)(gh + 256 + u0);
            f32x4 br  = *(const f32x4*)(bR_s + u0);
            f32x4 bz  = *(const f32x4*)(bZ_s + u0);
            f32x4 bni = *(const f32x4*)(bNi_s + u0);
            f32x4 bnh = *(const f32x4*)(bNh_s + u0);
            f32x4 hold = *(const f32x4*)(hm_s + grow * 132 + u0);
            f32x4 hnew;
            f16x4 nh, nl;
            #pragma unroll
            for (int i = 0; i < 4; ++i) {
                float r = sigm_(gir[i] + ghr[i] + br[i]);
                float zg = sigm_(giz[i] + ghz[i] + bz[i]);
                float n = tanh_(gin[i] + bni[i] + r * (ghn[i] + bnh[i]));
                float hv = (1.f - zg) * n + zg * hold[i];
                hnew[i] = hv;
                _Float16 hhf = (_Float16)hv;
                nh[i] = hhf;
                nl[i] = (_Float16)(hv - (float)hhf);
            }
            *(f32x4*)(hm_s + grow * 132 + u0) = hnew;
            int hb = grow * 256 + ((u0 * 2) ^ ((grow & 7) << 4));
            *(f16x4*)(hhi_c + hb) = nh;
            *(f16x4*)(hlo_c + hb) = nl;
        }
        __syncthreads();
    }

    if (tid < 96) {
        int rr = tid / 6, c = tid - rr * 6, j = (c < 3) ? c : c - 3;
        const float* W = (c < 3) ? meanW : lvW;
        const float* B = (c < 3) ? meanB : lvB;
        float acc = B[j];
        const float4* W4 = (const float4*)(W + j * 128);
        const float4* h4 = (const float4*)(hm_s + rr * 132);
        #pragma unroll 4
        for (int kc = 0; kc < 32; ++kc) acc += dot4_(W4[kc], h4[kc]);
        mb_s[rr * 6 + c] = acc;
    }
    __syncthreads();
    if (tid < 48) {
        int rr = tid / 3, j = tid - rr * 3;
        int gb = b0 + rr;
        float m  = mb_s[rr * 6 + j];
        float lv = mb_s[rr * 6 + j + 3];
        o_mean[gb * 3 + j] = m;
        o_lv[gb * 3 + j]   = lv;
        z0[gb * 3 + j]     = m + eps[gb * 3 + j] * __expf(0.5f * lv);
    }
}

// ---------------------------------------------------------------- dynamics f() (MFMA stage-2)
// 8 rows/block, 256 threads (4 waves). h1/h2 padded to K=128 (f16 hi/lo).
// A-frag rows 8..15 are pre-zeroed. Ends with parts[] ready (post-barrier).
__device__ __forceinline__ void feval8(
    const float* yin, char* h1h_c, char* h1l_c, float* h2f,
    const float* W3s, const float* b2s, float* parts,
    const float (&w1r)[12], const float (&b1r)[4],
    const f16x8 (&w2h)[2][4], const f16x8 (&w2l)[2][4],
    int tid, int lane, int wv)
{
    // phase A: h1 = tanh(W1 y + b1), f16 hi/lo, swizzled LDS
    {
        int r = tid >> 5, q = tid & 31, k0 = q * 4;
        float y0 = yin[r * 4 + 0], y1 = yin[r * 4 + 1], y2 = yin[r * 4 + 2];
        f16x4 hh_, hl_;
        #pragma unroll
        for (int i = 0; i < 4; ++i) {
            float acc = b1r[i] + w1r[3 * i] * y0 + w1r[3 * i + 1] * y1 + w1r[3 * i + 2] * y2;
            float h = tanh_(acc);                       // == 0 for padded k (weights/bias 0)
            _Float16 hf = (_Float16)h;
            hh_[i] = hf;
            hl_[i] = (_Float16)(h - (float)hf);
        }
        int off = r * 256 + ((k0 * 2) ^ (r << 4));
        *(f16x4*)(h1h_c + off) = hh_;
        *(f16x4*)(h1l_c + off) = hl_;
    }
    __syncthreads();

    // phase B: MFMA  h2_acc = h1 @ W2^T  (2 col-tiles per wave)
    const int lrow = lane & 15, lkb = lane >> 4;
    const int swA  = (lrow & 7) << 4;
    f16x8 ah[4], al[4];
    #pragma unroll
    for (int ks = 0; ks < 4; ++ks) {
        int off = lrow * 256 + ((ks * 64 + lkb * 16) ^ swA);
        ah[ks] = *(const f16x8*)(h1h_c + off);
        al[ks] = *(const f16x8*)(h1l_c + off);
    }
    f32x4 z4 = {0.f, 0.f, 0.f, 0.f};
    f32x4 acc0 = z4, acc1 = z4;
    #pragma unroll
    for (int ks = 0; ks < 4; ++ks) {
        acc0 = MFMA16(ah[ks], w2h[0][ks], acc0);
        acc0 = MFMA16(al[ks], w2h[0][ks], acc0);
        acc0 = MFMA16(ah[ks], w2l[0][ks], acc0);
        acc1 = MFMA16(ah[ks], w2h[1][ks], acc1);
        acc1 = MFMA16(al[ks], w2h[1][ks], acc1);
        acc1 = MFMA16(ah[ks], w2l[1][ks], acc1);
    }
    // phase C: h2 = tanh(acc + b2) -> fp32 LDS (rows 0..7 only)
    if (lkb < 2) {
        int r0 = lkb * 4;
        #pragma unroll
        for (int tile = 0; tile < 2; ++tile) {
            int col = (wv * 2 + tile) * 16 + lrow;
            f32x4 a = tile ? acc1 : acc0;
            if (col < 100) {
                float bb = b2s[col];
                #pragma unroll
                for (int i = 0; i < 4; ++i)
                    h2f[(r0 + i) * 104 + col] = tanh_(a[i] + bb);
            }
        }
    }
    __syncthreads();

    // phase D: parts = quarter-dots of W3 @ h2
    if (tid < 96) {
        int rr = tid / 12, rem = tid - rr * 12, j = rem >> 2, qc = rem & 3;
        const float4* Wj = (const float4*)(W3s + j * 104);
        const float4* Hr = (const float4*)(h2f + rr * 104);
        float acc = 0.f;
        #pragma unroll
        for (int kc = 0; kc < 7; ++kc) {
            int k = qc + kc * 4;
            if (k < 26) acc += dot4_(Wj[k], Hr[k]);
        }
        parts[(rr * 3 + j) * 4 + qc] = acc;
    }
    __syncthreads();
}

// ---------------------------------------------------------------- ODE kernel
// RK4 h=0.08 (24 steps) + final 0.07, cubic-Hermite dense output.
// 512 blocks x 256 threads, 8 rows per block, 2 blocks/CU.
__global__ __launch_bounds__(256, 2) void k_ode(
    const float* __restrict__ dW1, const float* __restrict__ db1,
    const float* __restrict__ dW2, const float* __restrict__ db2,
    const float* __restrict__ dW3, const float* __restrict__ db3,
    const float* __restrict__ z0, float* __restrict__ traj)
{
    __shared__ alignas(16) unsigned short h1h_s[2048], h1l_s[2048]; // [16][128] f16
    __shared__ alignas(16) float h2f[8 * 104];
    __shared__ alignas(16) float W3s[312];
    __shared__ float b2s[100], b3s[3];
    __shared__ float ys[32], yt[32], yn[32], f0[32], fo[32], kacc[32];
    __shared__ float parts[96];

    const int tid  = threadIdx.x;
    const int b0   = blockIdx.x * 8;
    const int lane = tid & 63, wv = tid >> 6;

    char* h1h_c = (char*)h1h_s;
    char* h1l_c = (char*)h1l_s;

    // ---- init: zero h1 rows 8..15, zero h2f pad cols, load W3/b2/b3
    for (int i = tid; i < 512; i += 256) {
        ((unsigned int*)(h1h_c + 2048))[i] = 0u;
        ((unsigned int*)(h1l_c + 2048))[i] = 0u;
    }
    if (tid < 32) h2f[(tid >> 2) * 104 + 100 + (tid & 3)] = 0.f;
    for (int i = tid; i < 312; i += 256) {
        int j = i / 104, k = i - j * 104;
        W3s[i] = (k < 100) ? dW3[j * 100 + k] : 0.f;
    }
    if (tid < 100) b2s[tid] = db2[tid];
    if (tid < 3)   b3s[tid] = db3[tid];

    // stage-1 weights in registers (4 consecutive k rows per thread)
    float w1r[12];
    float b1r[4];
    {
        int k0 = (tid & 31) * 4;
        #pragma unroll
        for (int i = 0; i < 4; ++i) {
            int k = k0 + i;
            if (k < 100) {
                w1r[3 * i + 0] = dW1[k * 3 + 0];
                w1r[3 * i + 1] = dW1[k * 3 + 1];
                w1r[3 * i + 2] = dW1[k * 3 + 2];
                b1r[i] = db1[k];
            } else {
                w1r[3 * i + 0] = 0.f; w1r[3 * i + 1] = 0.f; w1r[3 * i + 2] = 0.f;
                b1r[i] = 0.f;
            }
        }
    }
    // W2 B-fragments (hi/lo), 2 col-tiles per wave
    f16x8 w2h[2][4], w2l[2][4];
    {
        const int lrow = lane & 15, lkb = lane >> 4;
        #pragma unroll
        for (int tile = 0; tile < 2; ++tile) {
            int col = (wv * 2 + tile) * 16 + lrow;
            #pragma unroll
            for (int ks = 0; ks < 4; ++ks) {
                f16x8 hv, lv;
                #pragma unroll
                for (int j = 0; j < 8; ++j) {
                    int k = ks * 32 + lkb * 8 + j;
                    float v = (col < 100 && k < 100) ? dW2[col * 100 + k] : 0.f;
                    _Float16 hf = (_Float16)v;
                    hv[j] = hf;
                    lv[j] = (_Float16)(v - (float)hf);
                }
                w2h[tile][ks] = hv;
                w2l[tile][ks] = lv;
            }
        }
    }
    if (tid < 24) {
        int rr = tid / 3, j = tid - rr * 3, qd = rr * 4 + j;
        float v = z0[(b0 + rr) * 3 + j];
        yn[qd] = v;
        ys[qd] = v;
    }
    __syncthreads();

    // traj[0] = z0
    if (tid < 24) {
        int rr = tid / 3, j = tid - rr * 3;
        traj[((size_t)(b0 + rr)) * 3 + j] = yn[rr * 4 + j];
    }

    // initial f
    feval8(yn, h1h_c, h1l_c, h2f, W3s, b2s, parts, w1r, b1r, w2h, w2l, tid, lane, wv);
    if (tid < 24) {
        int rr = tid / 3, j = tid - rr * 3, qd = rr * 4 + j;
        fo[qd] = b3s[j] + parts[tid * 4] + parts[tid * 4 + 1] + parts[tid * 4 + 2] + parts[tid * 4 + 3];
    }
    __syncthreads();

    #pragma unroll 1
    for (int s = 0; s < 25; ++s) {
        const int   nInt = (s < 24) ? 8 : 7;
        const float hh   = 0.01f * (float)nInt;
        const int   t0   = s * 8;

        // k1 phase: commit prev step state, set yt
        if (tid < 24) {
            int rr = tid / 3, j = tid - rr * 3, qd = rr * 4 + j;
            float yv = yn[qd], fv = fo[qd];
            ys[qd] = yv;
            f0[qd] = fv;
            kacc[qd] = fv;
            yt[qd] = yv + 0.5f * hh * fv;
        }
        __syncthreads();
        feval8(yt, h1h_c, h1l_c, h2f, W3s, b2s, parts, w1r, b1r, w2h, w2l, tid, lane, wv); // k2
        if (tid < 24) {
            int rr = tid / 3, j = tid - rr * 3, qd = rr * 4 + j;
            float fv = b3s[j] + parts[tid * 4] + parts[tid * 4 + 1] + parts[tid * 4 + 2] + parts[tid * 4 + 3];
            kacc[qd] += 2.f * fv;
            yt[qd] = ys[qd] + 0.5f * hh * fv;
        }
        __syncthreads();
        feval8(yt, h1h_c, h1l_c, h2f, W3s, b2s, parts, w1r, b1r, w2h, w2l, tid, lane, wv); // k3
        if (tid < 24) {
            int rr = tid / 3, j = tid - rr * 3, qd = rr * 4 + j;
            float fv = b3s[j] + parts[tid * 4] + parts[tid * 4 + 1] + parts[tid * 4 + 2] + parts[tid * 4 + 3];
            kacc[qd] += 2.f * fv;
            yt[qd] = ys[qd] + hh * fv;
        }
        __syncthreads();
        feval8(yt, h1h_c, h1l_c, h2f, W3s, b2s, parts, w1r, b1r, w2h, w2l, tid, lane, wv); // k4
        if (tid < 24) {
            int rr = tid / 3, j = tid - rr * 3, qd = rr * 4 + j;
            float fv = b3s[j] + parts[tid * 4] + parts[tid * 4 + 1] + parts[tid * 4 + 2] + parts[tid * 4 + 3];
            kacc[qd] += fv;
            yn[qd] = ys[qd] + (hh / 6.f) * kacc[qd];
        }
        __syncthreads();
        feval8(yn, h1h_c, h1l_c, h2f, W3s, b2s, parts, w1r, b1r, w2h, w2l, tid, lane, wv); // f1
        if (tid < 24) {
            int rr = tid / 3, j = tid - rr * 3, qd = rr * 4 + j;
            fo[qd] = b3s[j] + parts[tid * 4] + parts[tid * 4 + 1] + parts[tid * 4 + 2] + parts[tid * 4 + 3];
        }
        __syncthreads();

        // dense output t0+1 .. t0+nInt (cubic Hermite)
        if (tid < 24 * nInt) {
            int q = tid / 24, rem = tid - q * 24, rr = rem / 3, j = rem - rr * 3;
            int idx = rr * 4 + j;
            float v;
            if (q == nInt - 1) {
                v = yn[idx];
            } else {
                float th  = (float)(q + 1) / (float)nInt;
                float th2 = th * th, th3 = th2 * th;
                float ca = 2.f * th3 - 3.f * th2 + 1.f;
                float cb = th3 - 2.f * th2 + th;
                float cc = 3.f * th2 - 2.f * th3;
                float cd = th3 - th2;
                v = ca * ys[idx] + cb * hh * f0[idx] + cc * yn[idx] + cd * hh * fo[idx];
            }
            traj[((size_t)(t0 + 1 + q) * 4096 + b0 + rr) * 3 + j] = v;
        }
        __syncthreads();
    }
}

// ---------------------------------------------------------------- decoder
__global__ __launch_bounds__(256) void k_dec(
    const float* __restrict__ traj, const float* __restrict__ W1, const float* __restrict__ b1,
    const float* __restrict__ W2, const float* __restrict__ b2, float* __restrict__ recon)
{
    __shared__ float zs[64 * 4];
    __shared__ float hd[64 * 68];
    const int tid = threadIdx.x;
    const size_t p0 = (size_t)blockIdx.x * 64;
    const int o = tid & 63, wv = tid >> 6;

    if (tid < 192) { int p = tid / 3, j = tid - p * 3; zs[p * 4 + j] = traj[p0 * 3 + tid]; }
    float4 w2r[16];
    #pragma unroll
    for (int kc = 0; kc < 16; ++kc) w2r[kc] = ((const float4*)W2)[o * 16 + kc];
    const float b2o = b2[o];
    __syncthreads();

    for (int i = tid; i < 4096; i += 256) {
        int p = i >> 6, u = i & 63;
        float acc = b1[u] + W1[u * 3 + 0] * zs[p * 4 + 0]
                          + W1[u * 3 + 1] * zs[p * 4 + 1]
                          + W1[u * 3 + 2] * zs[p * 4 + 2];
        hd[p * 68 + u] = fmaxf(acc, 0.f);
    }
    __syncthreads();

    #pragma unroll 1
    for (int pi = 0; pi < 16; ++pi) {
        int p = wv * 16 + pi;
        const float4* h4 = (const float4*)(hd + p * 68);
        float acc = b2o;
        #pragma unroll
        for (int kc = 0; kc < 16; ++kc) acc += dot4_(w2r[kc], h4[kc]);
        recon[(p0 + p) * 64 + o] = acc;
    }
}

extern "C" void kernel_launch(void* const* d_in, const int* in_sizes, int n_in,
                              void* d_out, int out_size, void* d_ws, size_t ws_size,
                              hipStream_t stream)
{
    const float* obs   = (const float*)d_in[0];
    const float* eps   = (const float*)d_in[1];
    const float* Wih   = (const float*)d_in[2];
    const float* Whh   = (const float*)d_in[3];
    const float* bih   = (const float*)d_in[4];
    const float* bhh   = (const float*)d_in[5];
    const float* meanW = (const float*)d_in[6];
    const float* meanB = (const float*)d_in[7];
    const float* lvW   = (const float*)d_in[8];
    const float* lvB   = (const float*)d_in[9];
    const float* dW1   = (const float*)d_in[10];
    const float* db1   = (const float*)d_in[11];
    const float* dW2   = (const float*)d_in[12];
    const float* db2   = (const float*)d_in[13];
    const float* dW3   = (const float*)d_in[14];
    const float* db3   = (const float*)d_in[15];
    const float* decW1 = (const float*)d_in[16];
    const float* decb1 = (const float*)d_in[17];
    const float* decW2 = (const float*)d_in[18];
    const float* decb2 = (const float*)d_in[19];

    float* out   = (float*)d_out;
    float* recon = out;
    float* omean = out + OFF_MEAN;
    float* olv   = out + OFF_LV;
    float* traj  = out + OFF_TRAJ;
    float* z0    = (float*)d_ws;

    k_gru<<<dim3(256), dim3(512), 0, stream>>>(obs, eps, Wih, Whh, bih, bhh,
                                               meanW, meanB, lvW, lvB, omean, olv, z0);
    k_ode<<<dim3(512), dim3(256), 0, stream>>>(dW1, db1, dW2, db2, dW3, db3, z0, traj);
    k_dec<<<dim3(12800), dim3(256), 0, stream>>>(traj, decW1, decb1, decW2, decb2, recon);
}

// Round 4
// 392.398 us; speedup vs baseline: 6.3599x; 1.4073x over previous
//
#include <hip/hip_runtime.h>
#include <stddef.h>

// Output layout (fp32):
//   recon    [200,4096,64] @ 0
//   z0_mean  [4096,3]      @ 52428800
//   z0_logvar[4096,3]      @ 52441088
//   traj     [200,4096,3]  @ 52453376
#define OFF_MEAN 52428800
#define OFF_LV   52441088
#define OFF_TRAJ 52453376

typedef _Float16 f16x8 __attribute__((ext_vector_type(8)));
typedef _Float16 f16x4 __attribute__((ext_vector_type(4)));
typedef float    f32x4 __attribute__((ext_vector_type(4)));

#define MFMA16(a, b, c) __builtin_amdgcn_mfma_f32_16x16x32_f16((a), (b), (c), 0, 0, 0)

__device__ __forceinline__ float sigm_(float x) { return 1.f / (1.f + __expf(-x)); }
__device__ __forceinline__ float tanh_(float x) { float e = __expf(2.f * x); return 1.f - 2.f / (e + 1.f); }
__device__ __forceinline__ float dot4_(float4 a, float4 b) {
    return a.x * b.x + a.y * b.y + a.z * b.z + a.w * b.w;
}

// ---------------------------------------------------------------- GRU (MFMA)
// (unchanged from round 2)
__global__ __launch_bounds__(512, 2) void k_gru(
    const float* __restrict__ obs, const float* __restrict__ eps,
    const float* __restrict__ Wih, const float* __restrict__ Whh,
    const float* __restrict__ bih, const float* __restrict__ bhh,
    const float* __restrict__ meanW, const float* __restrict__ meanB,
    const float* __restrict__ lvW,  const float* __restrict__ lvB,
    float* __restrict__ o_mean, float* __restrict__ o_lv, float* __restrict__ z0)
{
    __shared__ alignas(16) unsigned short wih_lds[24576];
    __shared__ alignas(16) float gai_s[16 * 388];
    __shared__ alignas(16) float gah_s[16 * 388];
    __shared__ alignas(16) float hm_s[16 * 132];
    __shared__ alignas(16) unsigned short hhi_s[2048], hlo_s[2048];
    __shared__ alignas(16) unsigned short xhi_s[1024], xlo_s[1024];
    __shared__ alignas(16) float bR_s[128], bZ_s[128], bNi_s[128], bNh_s[128];
    __shared__ float mb_s[96];

    const int tid  = threadIdx.x;
    const int b0   = blockIdx.x * 16;
    const int lane = tid & 63, wv = tid >> 6;
    const int lrow = lane & 15, lkb = lane >> 4;
    const int swA  = (lrow & 7) << 4;

    char* wih_c = (char*)wih_lds;
    char* hhi_c = (char*)hhi_s; char* hlo_c = (char*)hlo_s;
    char* xhi_c = (char*)xhi_s; char* xlo_c = (char*)xlo_s;

    for (int i = tid; i < 16 * 132; i += 512) hm_s[i] = 0.f;
    for (int i = tid; i < 2048; i += 512) { hhi_s[i] = 0; hlo_s[i] = 0; }
    if (tid < 128) {
        bR_s[tid]  = bih[tid] + bhh[tid];
        bZ_s[tid]  = bih[128 + tid] + bhh[128 + tid];
        bNi_s[tid] = bih[256 + tid];
        bNh_s[tid] = bhh[256 + tid];
    }
    for (int i = 0; i < 6; ++i) {
        int idx = i * 512 + tid;
        int blk = idx >> 6, ln = idx & 63;
        int tile = blk >> 1, ks = blk & 1;
        int col = tile * 16 + (ln & 15);
        int kb  = ks * 32 + (ln >> 4) * 8;
        const float* wp = Wih + col * 64 + kb;
        float4 a = *(const float4*)wp, b = *(const float4*)(wp + 4);
        float tmp[8] = {a.x, a.y, a.z, a.w, b.x, b.y, b.z, b.w};
        f16x8 hv;
        #pragma unroll
        for (int j = 0; j < 8; ++j) hv[j] = (_Float16)tmp[j];
        *(f16x8*)(wih_c + idx * 16) = hv;
    }
    f16x8 whhh[3][4], whhl[3][4];
    #pragma unroll
    for (int t3 = 0; t3 < 3; ++t3) {
        #pragma unroll
        for (int ks = 0; ks < 4; ++ks) {
            int col = (wv * 3 + t3) * 16 + lrow;
            int kb  = ks * 32 + lkb * 8;
            const float* wp = Whh + col * 128 + kb;
            float4 a = *(const float4*)wp, b = *(const float4*)(wp + 4);
            float tmp[8] = {a.x, a.y, a.z, a.w, b.x, b.y, b.z, b.w};
            f16x8 hv, lv;
            #pragma unroll
            for (int j = 0; j < 8; ++j) {
                hv[j] = (_Float16)tmp[j];
                lv[j] = (_Float16)(tmp[j] - (float)hv[j]);
            }
            whhh[t3][ks] = hv;
            whhl[t3][ks] = lv;
        }
    }
    __syncthreads();

    for (int t = 0; t < 50; ++t) {
        if (tid < 256) {
            int row = tid >> 4, kq = (tid & 15) * 4;
            float4 v = *(const float4*)(obs + ((size_t)t * 4096 + b0 + row) * 64 + kq);
            float tmp[4] = {v.x, v.y, v.z, v.w};
            f16x4 vh, vl;
            #pragma unroll
            for (int j = 0; j < 4; ++j) {
                vh[j] = (_Float16)tmp[j];
                vl[j] = (_Float16)(tmp[j] - (float)vh[j]);
            }
            int xb = row * 128 + ((kq * 2) ^ ((row & 7) << 4));
            *(f16x4*)(xhi_c + xb) = vh;
            *(f16x4*)(xlo_c + xb) = vl;
        }
        __syncthreads();

        f16x8 xh[2], xl[2], hh[4], hl[4];
        #pragma unroll
        for (int ks = 0; ks < 2; ++ks) {
            int off = lrow * 128 + ((ks * 64 + lkb * 16) ^ swA);
            xh[ks] = *(const f16x8*)(xhi_c + off);
            xl[ks] = *(const f16x8*)(xlo_c + off);
        }
        #pragma unroll
        for (int ks = 0; ks < 4; ++ks) {
            int off = lrow * 256 + ((ks * 64 + lkb * 16) ^ swA);
            hh[ks] = *(const f16x8*)(hhi_c + off);
            hl[ks] = *(const f16x8*)(hlo_c + off);
        }
        f32x4 zero4 = {0.f, 0.f, 0.f, 0.f};
        f32x4 ai[3] = {zero4, zero4, zero4};
        f32x4 ah[3] = {zero4, zero4, zero4};
        #pragma unroll
        for (int t3 = 0; t3 < 3; ++t3) {
            int tile = wv * 3 + t3;
            #pragma unroll
            for (int ks = 0; ks < 2; ++ks) {
                f16x8 bw = *(const f16x8*)(wih_c + ((tile * 2 + ks) * 64 + lane) * 16);
                ai[t3] = MFMA16(xh[ks], bw, ai[t3]);
                ai[t3] = MFMA16(xl[ks], bw, ai[t3]);
            }
            #pragma unroll
            for (int ks = 0; ks < 4; ++ks) {
                ah[t3] = MFMA16(hh[ks], whhh[t3][ks], ah[t3]);
                ah[t3] = MFMA16(hl[ks], whhh[t3][ks], ah[t3]);
                ah[t3] = MFMA16(hh[ks], whhl[t3][ks], ah[t3]);
            }
        }
        #pragma unroll
        for (int t3 = 0; t3 < 3; ++t3) {
            int col = (wv * 3 + t3) * 16 + lrow;
            int r0  = lkb * 4;
            #pragma unroll
            for (int i = 0; i < 4; ++i) {
                gai_s[(r0 + i) * 388 + col] = ai[t3][i];
                gah_s[(r0 + i) * 388 + col] = ah[t3][i];
            }
        }
        __syncthreads();

        {
            const int grow = tid >> 5;
            const int u0   = (tid & 31) * 4;
            const float* gi = gai_s + grow * 388;
            const float* gh = gah_s + grow * 388;
            f32x4 gir = *(const f32x4*)(gi + u0);
            f32x4 giz = *(const f32x4*)(gi + 128 + u0);
            f32x4 gin = *(const f32x4*)(gi + 256 + u0);
            f32x4 ghr = *(const f32x4*)(gh + u0);
            f32x4 ghz = *(const f32x4*)(gh + 128 + u0);
            f32x4 ghn = *(const f32x4*)(gh + 256 + u0);
            f32x4 br  = *(const f32x4*)(bR_s + u0);
            f32x4 bz  = *(const f32x4*)(bZ_s + u0);
            f32x4 bni = *(const f32x4*)(bNi_s + u0);
            f32x4 bnh = *(const f32x4*)(bNh_s + u0);
            f32x4 hold = *(const f32x4*)(hm_s + grow * 132 + u0);
            f32x4 hnew;
            f16x4 nh, nl;
            #pragma unroll
            for (int i = 0; i < 4; ++i) {
                float r = sigm_(gir[i] + ghr[i] + br[i]);
                float zg = sigm_(giz[i] + ghz[i] + bz[i]);
                float n = tanh_(gin[i] + bni[i] + r * (ghn[i] + bnh[i]));
                float hv = (1.f - zg) * n + zg * hold[i];
                hnew[i] = hv;
                _Float16 hhf = (_Float16)hv;
                nh[i] = hhf;
                nl[i] = (_Float16)(hv - (float)hhf);
            }
            *(f32x4*)(hm_s + grow * 132 + u0) = hnew;
            int hb = grow * 256 + ((u0 * 2) ^ ((grow & 7) << 4));
            *(f16x4*)(hhi_c + hb) = nh;
            *(f16x4*)(hlo_c + hb) = nl;
        }
        __syncthreads();
    }

    if (tid < 96) {
        int rr = tid / 6, c = tid - rr * 6, j = (c < 3) ? c : c - 3;
        const float* W = (c < 3) ? meanW : lvW;
        const float* B = (c < 3) ? meanB : lvB;
        float acc = B[j];
        const float4* W4 = (const float4*)(W + j * 128);
        const float4* h4 = (const float4*)(hm_s + rr * 132);
        #pragma unroll 4
        for (int kc = 0; kc < 32; ++kc) acc += dot4_(W4[kc], h4[kc]);
        mb_s[rr * 6 + c] = acc;
    }
    __syncthreads();
    if (tid < 48) {
        int rr = tid / 3, j = tid - rr * 3;
        int gb = b0 + rr;
        float m  = mb_s[rr * 6 + j];
        float lv = mb_s[rr * 6 + j + 3];
        o_mean[gb * 3 + j] = m;
        o_lv[gb * 3 + j]   = lv;
        z0[gb * 3 + j]     = m + eps[gb * 3 + j] * __expf(0.5f * lv);
    }
}

// ---------------------------------------------------------------- dynamics f() (MFMA stage-2)
// (unchanged from round 3)
__device__ __forceinline__ void feval8(
    const float* yin, char* h1h_c, char* h1l_c, float* h2f,
    const float* W3s, const float* b2s, float* parts,
    const float (&w1r)[12], const float (&b1r)[4],
    const f16x8 (&w2h)[2][4], const f16x8 (&w2l)[2][4],
    int tid, int lane, int wv)
{
    {
        int r = tid >> 5, q = tid & 31, k0 = q * 4;
        float y0 = yin[r * 4 + 0], y1 = yin[r * 4 + 1], y2 = yin[r * 4 + 2];
        f16x4 hh_, hl_;
        #pragma unroll
        for (int i = 0; i < 4; ++i) {
            float acc = b1r[i] + w1r[3 * i] * y0 + w1r[3 * i + 1] * y1 + w1r[3 * i + 2] * y2;
            float h = tanh_(acc);
            _Float16 hf = (_Float16)h;
            hh_[i] = hf;
            hl_[i] = (_Float16)(h - (float)hf);
        }
        int off = r * 256 + ((k0 * 2) ^ (r << 4));
        *(f16x4*)(h1h_c + off) = hh_;
        *(f16x4*)(h1l_c + off) = hl_;
    }
    __syncthreads();

    const int lrow = lane & 15, lkb = lane >> 4;
    const int swA  = (lrow & 7) << 4;
    f16x8 ah[4], al[4];
    #pragma unroll
    for (int ks = 0; ks < 4; ++ks) {
        int off = lrow * 256 + ((ks * 64 + lkb * 16) ^ swA);
        ah[ks] = *(const f16x8*)(h1h_c + off);
        al[ks] = *(const f16x8*)(h1l_c + off);
    }
    f32x4 z4 = {0.f, 0.f, 0.f, 0.f};
    f32x4 acc0 = z4, acc1 = z4;
    #pragma unroll
    for (int ks = 0; ks < 4; ++ks) {
        acc0 = MFMA16(ah[ks], w2h[0][ks], acc0);
        acc0 = MFMA16(al[ks], w2h[0][ks], acc0);
        acc0 = MFMA16(ah[ks], w2l[0][ks], acc0);
        acc1 = MFMA16(ah[ks], w2h[1][ks], acc1);
        acc1 = MFMA16(al[ks], w2h[1][ks], acc1);
        acc1 = MFMA16(ah[ks], w2l[1][ks], acc1);
    }
    if (lkb < 2) {
        int r0 = lkb * 4;
        #pragma unroll
        for (int tile = 0; tile < 2; ++tile) {
            int col = (wv * 2 + tile) * 16 + lrow;
            f32x4 a = tile ? acc1 : acc0;
            if (col < 100) {
                float bb = b2s[col];
                #pragma unroll
                for (int i = 0; i < 4; ++i)
                    h2f[(r0 + i) * 104 + col] = tanh_(a[i] + bb);
            }
        }
    }
    __syncthreads();

    if (tid < 96) {
        int rr = tid / 12, rem = tid - rr * 12, j = rem >> 2, qc = rem & 3;
        const float4* Wj = (const float4*)(W3s + j * 104);
        const float4* Hr = (const float4*)(h2f + rr * 104);
        float acc = 0.f;
        #pragma unroll
        for (int kc = 0; kc < 7; ++kc) {
            int k = qc + kc * 4;
            if (k < 26) acc += dot4_(Wj[k], Hr[k]);
        }
        parts[(rr * 3 + j) * 4 + qc] = acc;
    }
    __syncthreads();
}

// ---------------------------------------------------------------- ODE kernel
// (unchanged from round 3)
__global__ __launch_bounds__(256, 2) void k_ode(
    const float* __restrict__ dW1, const float* __restrict__ db1,
    const float* __restrict__ dW2, const float* __restrict__ db2,
    const float* __restrict__ dW3, const float* __restrict__ db3,
    const float* __restrict__ z0, float* __restrict__ traj)
{
    __shared__ alignas(16) unsigned short h1h_s[2048], h1l_s[2048];
    __shared__ alignas(16) float h2f[8 * 104];
    __shared__ alignas(16) float W3s[312];
    __shared__ float b2s[100], b3s[3];
    __shared__ float ys[32], yt[32], yn[32], f0[32], fo[32], kacc[32];
    __shared__ float parts[96];

    const int tid  = threadIdx.x;
    const int b0   = blockIdx.x * 8;
    const int lane = tid & 63, wv = tid >> 6;

    char* h1h_c = (char*)h1h_s;
    char* h1l_c = (char*)h1l_s;

    for (int i = tid; i < 512; i += 256) {
        ((unsigned int*)(h1h_c + 2048))[i] = 0u;
        ((unsigned int*)(h1l_c + 2048))[i] = 0u;
    }
    if (tid < 32) h2f[(tid >> 2) * 104 + 100 + (tid & 3)] = 0.f;
    for (int i = tid; i < 312; i += 256) {
        int j = i / 104, k = i - j * 104;
        W3s[i] = (k < 100) ? dW3[j * 100 + k] : 0.f;
    }
    if (tid < 100) b2s[tid] = db2[tid];
    if (tid < 3)   b3s[tid] = db3[tid];

    float w1r[12];
    float b1r[4];
    {
        int k0 = (tid & 31) * 4;
        #pragma unroll
        for (int i = 0; i < 4; ++i) {
            int k = k0 + i;
            if (k < 100) {
                w1r[3 * i + 0] = dW1[k * 3 + 0];
                w1r[3 * i + 1] = dW1[k * 3 + 1];
                w1r[3 * i + 2] = dW1[k * 3 + 2];
                b1r[i] = db1[k];
            } else {
                w1r[3 * i + 0] = 0.f; w1r[3 * i + 1] = 0.f; w1r[3 * i + 2] = 0.f;
                b1r[i] = 0.f;
            }
        }
    }
    f16x8 w2h[2][4], w2l[2][4];
    {
        const int lrow = lane & 15, lkb = lane >> 4;
        #pragma unroll
        for (int tile = 0; tile < 2; ++tile) {
            int col = (wv * 2 + tile) * 16 + lrow;
            #pragma unroll
            for (int ks = 0; ks < 4; ++ks) {
                f16x8 hv, lv;
                #pragma unroll
                for (int j = 0; j < 8; ++j) {
                    int k = ks * 32 + lkb * 8 + j;
                    float v = (col < 100 && k < 100) ? dW2[col * 100 + k] : 0.f;
                    _Float16 hf = (_Float16)v;
                    hv[j] = hf;
                    lv[j] = (_Float16)(v - (float)hf);
                }
                w2h[tile][ks] = hv;
                w2l[tile][ks] = lv;
            }
        }
    }
    if (tid < 24) {
        int rr = tid / 3, j = tid - rr * 3, qd = rr * 4 + j;
        float v = z0[(b0 + rr) * 3 + j];
        yn[qd] = v;
        ys[qd] = v;
    }
    __syncthreads();

    if (tid < 24) {
        int rr = tid / 3, j = tid - rr * 3;
        traj[((size_t)(b0 + rr)) * 3 + j] = yn[rr * 4 + j];
    }

    feval8(yn, h1h_c, h1l_c, h2f, W3s, b2s, parts, w1r, b1r, w2h, w2l, tid, lane, wv);
    if (tid < 24) {
        int rr = tid / 3, j = tid - rr * 3, qd = rr * 4 + j;
        fo[qd] = b3s[j] + parts[tid * 4] + parts[tid * 4 + 1] + parts[tid * 4 + 2] + parts[tid * 4 + 3];
    }
    __syncthreads();

    #pragma unroll 1
    for (int s = 0; s < 25; ++s) {
        const int   nInt = (s < 24) ? 8 : 7;
        const float hh   = 0.01f * (float)nInt;
        const int   t0   = s * 8;

        if (tid < 24) {
            int rr = tid / 3, j = tid - rr * 3, qd = rr * 4 + j;
            float yv = yn[qd], fv = fo[qd];
            ys[qd] = yv;
            f0[qd] = fv;
            kacc[qd] = fv;
            yt[qd] = yv + 0.5f * hh * fv;
        }
        __syncthreads();
        feval8(yt, h1h_c, h1l_c, h2f, W3s, b2s, parts, w1r, b1r, w2h, w2l, tid, lane, wv);
        if (tid < 24) {
            int rr = tid / 3, j = tid - rr * 3, qd = rr * 4 + j;
            float fv = b3s[j] + parts[tid * 4] + parts[tid * 4 + 1] + parts[tid * 4 + 2] + parts[tid * 4 + 3];
            kacc[qd] += 2.f * fv;
            yt[qd] = ys[qd] + 0.5f * hh * fv;
        }
        __syncthreads();
        feval8(yt, h1h_c, h1l_c, h2f, W3s, b2s, parts, w1r, b1r, w2h, w2l, tid, lane, wv);
        if (tid < 24) {
            int rr = tid / 3, j = tid - rr * 3, qd = rr * 4 + j;
            float fv = b3s[j] + parts[tid * 4] + parts[tid * 4 + 1] + parts[tid * 4 + 2] + parts[tid * 4 + 3];
            kacc[qd] += 2.f * fv;
            yt[qd] = ys[qd] + hh * fv;
        }
        __syncthreads();
        feval8(yt, h1h_c, h1l_c, h2f, W3s, b2s, parts, w1r, b1r, w2h, w2l, tid, lane, wv);
        if (tid < 24) {
            int rr = tid / 3, j = tid - rr * 3, qd = rr * 4 + j;
            float fv = b3s[j] + parts[tid * 4] + parts[tid * 4 + 1] + parts[tid * 4 + 2] + parts[tid * 4 + 3];
            kacc[qd] += fv;
            yn[qd] = ys[qd] + (hh / 6.f) * kacc[qd];
        }
        __syncthreads();
        feval8(yn, h1h_c, h1l_c, h2f, W3s, b2s, parts, w1r, b1r, w2h, w2l, tid, lane, wv);
        if (tid < 24) {
            int rr = tid / 3, j = tid - rr * 3, qd = rr * 4 + j;
            fo[qd] = b3s[j] + parts[tid * 4] + parts[tid * 4 + 1] + parts[tid * 4 + 2] + parts[tid * 4 + 3];
        }
        __syncthreads();

        if (tid < 24 * nInt) {
            int q = tid / 24, rem = tid - q * 24, rr = rem / 3, j = rem - rr * 3;
            int idx = rr * 4 + j;
            float v;
            if (q == nInt - 1) {
                v = yn[idx];
            } else {
                float th  = (float)(q + 1) / (float)nInt;
                float th2 = th * th, th3 = th2 * th;
                float ca = 2.f * th3 - 3.f * th2 + 1.f;
                float cb = th3 - 2.f * th2 + th;
                float cc = 3.f * th2 - 2.f * th3;
                float cd = th3 - th2;
                v = ca * ys[idx] + cb * hh * f0[idx] + cc * yn[idx] + cd * hh * fo[idx];
            }
            traj[((size_t)(t0 + 1 + q) * 4096 + b0 + rr) * 3 + j] = v;
        }
        __syncthreads();
    }
}

// ---------------------------------------------------------------- decoder (MFMA)
// 6400 blocks x 256 threads (4 waves); 128 (t,b)-pairs per block.
// hd = relu(W1 z + b1) staged in LDS as f16 hi/lo, swizzled [128][64].
// decW2 as hi/lo B-fragments (one 16-col tile per wave, 16 VGPR).
// 8 row-tiles x (4 ds_read_b128 + 6 MFMA + 4 coalesced dword stores).
__global__ __launch_bounds__(256, 2) void k_dec(
    const float* __restrict__ traj, const float* __restrict__ W1, const float* __restrict__ b1,
    const float* __restrict__ W2, const float* __restrict__ b2, float* __restrict__ recon)
{
    __shared__ alignas(16) unsigned short hdh_s[8192], hdl_s[8192];  // [128][64] f16
    __shared__ alignas(16) float zs[384];
    __shared__ float w1s[192], b1s_[64];

    const int tid  = threadIdx.x;
    const size_t p0 = (size_t)blockIdx.x * 128;
    const int lane = tid & 63, wv = tid >> 6;
    const int lrow = lane & 15, lkb = lane >> 4;

    char* hdh_c = (char*)hdh_s;
    char* hdl_c = (char*)hdl_s;

    // stage z (traj slice), W1, b1 into LDS
    if (tid < 96) *(float4*)&zs[tid * 4] = ((const float4*)(traj + p0 * 3))[tid];
    if (tid < 192) w1s[tid] = W1[tid];
    if (tid < 64)  b1s_[tid] = b1[tid];

    // B-fragments: decW2 col-tile wv (hi/lo), loaded from global once
    f16x8 bh[2], bl[2];
    {
        int col = wv * 16 + lrow;
        #pragma unroll
        for (int ks = 0; ks < 2; ++ks) {
            const float* wp = W2 + col * 64 + ks * 32 + lkb * 8;
            float4 a = *(const float4*)wp, b = *(const float4*)(wp + 4);
            float tmp[8] = {a.x, a.y, a.z, a.w, b.x, b.y, b.z, b.w};
            f16x8 hv, lv;
            #pragma unroll
            for (int j = 0; j < 8; ++j) {
                hv[j] = (_Float16)tmp[j];
                lv[j] = (_Float16)(tmp[j] - (float)hv[j]);
            }
            bh[ks] = hv;
            bl[ks] = lv;
        }
    }
    const float bo = b2[wv * 16 + lrow];
    __syncthreads();

    // stage 1: hd = relu(W1 z + b1) -> f16 hi/lo swizzled LDS
    {
        const int p  = tid >> 1;
        const int u0 = (tid & 1) * 32;
        const float z0v = zs[p * 3 + 0], z1v = zs[p * 3 + 1], z2v = zs[p * 3 + 2];
        const int sw = (p & 7) << 4;
        #pragma unroll
        for (int c = 0; c < 8; ++c) {
            f16x4 hh_, hl_;
            #pragma unroll
            for (int i = 0; i < 4; ++i) {
                int u = u0 + c * 4 + i;
                float acc = b1s_[u] + w1s[u * 3 + 0] * z0v
                                    + w1s[u * 3 + 1] * z1v
                                    + w1s[u * 3 + 2] * z2v;
                float h = fmaxf(acc, 0.f);
                _Float16 hf = (_Float16)h;
                hh_[i] = hf;
                hl_[i] = (_Float16)(h - (float)hf);
            }
            int off = p * 128 + (((u0 + c * 4) * 2) ^ sw);
            *(f16x4*)(hdh_c + off) = hh_;
            *(f16x4*)(hdl_c + off) = hl_;
        }
    }
    __syncthreads();

    // stage 2: MFMA over 8 row-tiles; wave wv owns col-tile wv
    const int swA = (lrow & 7) << 4;
    #pragma unroll
    for (int rt = 0; rt < 8; ++rt) {
        f16x8 ahh[2], all_[2];
        #pragma unroll
        for (int ks = 0; ks < 2; ++ks) {
            int off = (rt * 16 + lrow) * 128 + ((ks * 64 + lkb * 16) ^ swA);
            ahh[ks]  = *(const f16x8*)(hdh_c + off);
            all_[ks] = *(const f16x8*)(hdl_c + off);
        }
        f32x4 acc = {0.f, 0.f, 0.f, 0.f};
        #pragma unroll
        for (int ks = 0; ks < 2; ++ks) {
            acc = MFMA16(ahh[ks],  bh[ks], acc);
            acc = MFMA16(all_[ks], bh[ks], acc);
            acc = MFMA16(ahh[ks],  bl[ks], acc);
        }
        const size_t rowg = p0 + rt * 16 + lkb * 4;
        #pragma unroll
        for (int i = 0; i < 4; ++i)
            recon[(rowg + i) * 64 + wv * 16 + lrow] = acc[i] + bo;
    }
}

extern "C" void kernel_launch(void* const* d_in, const int* in_sizes, int n_in,
                              void* d_out, int out_size, void* d_ws, size_t ws_size,
                              hipStream_t stream)
{
    const float* obs   = (const float*)d_in[0];
    const float* eps   = (const float*)d_in[1];
    const float* Wih   = (const float*)d_in[2];
    const float* Whh   = (const float*)d_in[3];
    const float* bih   = (const float*)d_in[4];
    const float* bhh   = (const float*)d_in[5];
    const float* meanW = (const float*)d_in[6];
    const float* meanB = (const float*)d_in[7];
    const float* lvW   = (const float*)d_in[8];
    const float* lvB   = (const float*)d_in[9];
    const float* dW1   = (const float*)d_in[10];
    const float* db1   = (const float*)d_in[11];
    const float* dW2   = (const float*)d_in[12];
    const float* db2   = (const float*)d_in[13];
    const float* dW3   = (const float*)d_in[14];
    const float* db3   = (const float*)d_in[15];
    const float* decW1 = (const float*)d_in[16];
    const float* decb1 = (const float*)d_in[17];
    const float* decW2 = (const float*)d_in[18];
    const float* decb2 = (const float*)d_in[19];

    float* out   = (float*)d_out;
    float* recon = out;
    float* omean = out + OFF_MEAN;
    float* olv   = out + OFF_LV;
    float* traj  = out + OFF_TRAJ;
    float* z0    = (float*)d_ws;

    k_gru<<<dim3(256), dim3(512), 0, stream>>>(obs, eps, Wih, Whh, bih, bhh,
                                               meanW, meanB, lvW, lvB, omean, olv, z0);
    k_ode<<<dim3(512), dim3(256), 0, stream>>>(dW1, db1, dW2, db2, dW3, db3, z0, traj);
    k_dec<<<dim3(6400), dim3(256), 0, stream>>>(traj, decW1, decb1, decW2, decb2, recon);
}

// Round 5
// 256.706 us; speedup vs baseline: 9.7216x; 1.5286x over previous
//
#include <hip/hip_runtime.h>
#include <stddef.h>

// Output layout (fp32):
//   recon    [200,4096,64] @ 0
//   z0_mean  [4096,3]      @ 52428800
//   z0_logvar[4096,3]      @ 52441088
//   traj     [200,4096,3]  @ 52453376
#define OFF_MEAN 52428800
#define OFF_LV   52441088
#define OFF_TRAJ 52453376

typedef _Float16 f16x8 __attribute__((ext_vector_type(8)));
typedef _Float16 f16x4 __attribute__((ext_vector_type(4)));
typedef float    f32x4 __attribute__((ext_vector_type(4)));

#define MFMA16(a, b, c) __builtin_amdgcn_mfma_f32_16x16x32_f16((a), (b), (c), 0, 0, 0)

// fast transcendentals: v_exp_f32 + v_rcp_f32 (error ~1e-6, far below our budget)
__device__ __forceinline__ float sigm_(float x) {
    float e = __builtin_amdgcn_exp2f(x * -1.442695041f);
    return __builtin_amdgcn_rcpf(1.f + e);
}
__device__ __forceinline__ float tanh_(float x) {
    float e = __builtin_amdgcn_exp2f(x * 2.885390082f);
    return 1.f - 2.f * __builtin_amdgcn_rcpf(e + 1.f);
}
__device__ __forceinline__ float dot4_(float4 a, float4 b) {
    return a.x * b.x + a.y * b.y + a.z * b.z + a.w * b.w;
}

// ---------------------------------------------------------------- GRU (MFMA)
// (structure unchanged from round 2; gate phase now uses fast sigm_/tanh_)
__global__ __launch_bounds__(512, 2) void k_gru(
    const float* __restrict__ obs, const float* __restrict__ eps,
    const float* __restrict__ Wih, const float* __restrict__ Whh,
    const float* __restrict__ bih, const float* __restrict__ bhh,
    const float* __restrict__ meanW, const float* __restrict__ meanB,
    const float* __restrict__ lvW,  const float* __restrict__ lvB,
    float* __restrict__ o_mean, float* __restrict__ o_lv, float* __restrict__ z0)
{
    __shared__ alignas(16) unsigned short wih_lds[24576];
    __shared__ alignas(16) float gai_s[16 * 388];
    __shared__ alignas(16) float gah_s[16 * 388];
    __shared__ alignas(16) float hm_s[16 * 132];
    __shared__ alignas(16) unsigned short hhi_s[2048], hlo_s[2048];
    __shared__ alignas(16) unsigned short xhi_s[1024], xlo_s[1024];
    __shared__ alignas(16) float bR_s[128], bZ_s[128], bNi_s[128], bNh_s[128];
    __shared__ float mb_s[96];

    const int tid  = threadIdx.x;
    const int b0   = blockIdx.x * 16;
    const int lane = tid & 63, wv = tid >> 6;
    const int lrow = lane & 15, lkb = lane >> 4;
    const int swA  = (lrow & 7) << 4;

    char* wih_c = (char*)wih_lds;
    char* hhi_c = (char*)hhi_s; char* hlo_c = (char*)hlo_s;
    char* xhi_c = (char*)xhi_s; char* xlo_c = (char*)xlo_s;

    for (int i = tid; i < 16 * 132; i += 512) hm_s[i] = 0.f;
    for (int i = tid; i < 2048; i += 512) { hhi_s[i] = 0; hlo_s[i] = 0; }
    if (tid < 128) {
        bR_s[tid]  = bih[tid] + bhh[tid];
        bZ_s[tid]  = bih[128 + tid] + bhh[128 + tid];
        bNi_s[tid] = bih[256 + tid];
        bNh_s[tid] = bhh[256 + tid];
    }
    for (int i = 0; i < 6; ++i) {
        int idx = i * 512 + tid;
        int blk = idx >> 6, ln = idx & 63;
        int tile = blk >> 1, ks = blk & 1;
        int col = tile * 16 + (ln & 15);
        int kb  = ks * 32 + (ln >> 4) * 8;
        const float* wp = Wih + col * 64 + kb;
        float4 a = *(const float4*)wp, b = *(const float4*)(wp + 4);
        float tmp[8] = {a.x, a.y, a.z, a.w, b.x, b.y, b.z, b.w};
        f16x8 hv;
        #pragma unroll
        for (int j = 0; j < 8; ++j) hv[j] = (_Float16)tmp[j];
        *(f16x8*)(wih_c + idx * 16) = hv;
    }
    f16x8 whhh[3][4], whhl[3][4];
    #pragma unroll
    for (int t3 = 0; t3 < 3; ++t3) {
        #pragma unroll
        for (int ks = 0; ks < 4; ++ks) {
            int col = (wv * 3 + t3) * 16 + lrow;
            int kb  = ks * 32 + lkb * 8;
            const float* wp = Whh + col * 128 + kb;
            float4 a = *(const float4*)wp, b = *(const float4*)(wp + 4);
            float tmp[8] = {a.x, a.y, a.z, a.w, b.x, b.y, b.z, b.w};
            f16x8 hv, lv;
            #pragma unroll
            for (int j = 0; j < 8; ++j) {
                hv[j] = (_Float16)tmp[j];
                lv[j] = (_Float16)(tmp[j] - (float)hv[j]);
            }
            whhh[t3][ks] = hv;
            whhl[t3][ks] = lv;
        }
    }
    __syncthreads();

    for (int t = 0; t < 50; ++t) {
        if (tid < 256) {
            int row = tid >> 4, kq = (tid & 15) * 4;
            float4 v = *(const float4*)(obs + ((size_t)t * 4096 + b0 + row) * 64 + kq);
            float tmp[4] = {v.x, v.y, v.z, v.w};
            f16x4 vh, vl;
            #pragma unroll
            for (int j = 0; j < 4; ++j) {
                vh[j] = (_Float16)tmp[j];
                vl[j] = (_Float16)(tmp[j] - (float)vh[j]);
            }
            int xb = row * 128 + ((kq * 2) ^ ((row & 7) << 4));
            *(f16x4*)(xhi_c + xb) = vh;
            *(f16x4*)(xlo_c + xb) = vl;
        }
        __syncthreads();

        f16x8 xh[2], xl[2], hh[4], hl[4];
        #pragma unroll
        for (int ks = 0; ks < 2; ++ks) {
            int off = lrow * 128 + ((ks * 64 + lkb * 16) ^ swA);
            xh[ks] = *(const f16x8*)(xhi_c + off);
            xl[ks] = *(const f16x8*)(xlo_c + off);
        }
        #pragma unroll
        for (int ks = 0; ks < 4; ++ks) {
            int off = lrow * 256 + ((ks * 64 + lkb * 16) ^ swA);
            hh[ks] = *(const f16x8*)(hhi_c + off);
            hl[ks] = *(const f16x8*)(hlo_c + off);
        }
        f32x4 zero4 = {0.f, 0.f, 0.f, 0.f};
        f32x4 ai[3] = {zero4, zero4, zero4};
        f32x4 ah[3] = {zero4, zero4, zero4};
        #pragma unroll
        for (int t3 = 0; t3 < 3; ++t3) {
            int tile = wv * 3 + t3;
            #pragma unroll
            for (int ks = 0; ks < 2; ++ks) {
                f16x8 bw = *(const f16x8*)(wih_c + ((tile * 2 + ks) * 64 + lane) * 16);
                ai[t3] = MFMA16(xh[ks], bw, ai[t3]);
                ai[t3] = MFMA16(xl[ks], bw, ai[t3]);
            }
            #pragma unroll
            for (int ks = 0; ks < 4; ++ks) {
                ah[t3] = MFMA16(hh[ks], whhh[t3][ks], ah[t3]);
                ah[t3] = MFMA16(hl[ks], whhh[t3][ks], ah[t3]);
                ah[t3] = MFMA16(hh[ks], whhl[t3][ks], ah[t3]);
            }
        }
        #pragma unroll
        for (int t3 = 0; t3 < 3; ++t3) {
            int col = (wv * 3 + t3) * 16 + lrow;
            int r0  = lkb * 4;
            #pragma unroll
            for (int i = 0; i < 4; ++i) {
                gai_s[(r0 + i) * 388 + col] = ai[t3][i];
                gah_s[(r0 + i) * 388 + col] = ah[t3][i];
            }
        }
        __syncthreads();

        {
            const int grow = tid >> 5;
            const int u0   = (tid & 31) * 4;
            const float* gi = gai_s + grow * 388;
            const float* gh = gah_s + grow * 388;
            f32x4 gir = *(const f32x4*)(gi + u0);
            f32x4 giz = *(const f32x4*)(gi + 128 + u0);
            f32x4 gin = *(const f32x4*)(gi + 256 + u0);
            f32x4 ghr = *(const f32x4*)(gh + u0);
            f32x4 ghz = *(const f32x4*)(gh + 128 + u0);
            f32x4 ghn = *(const f32x4*)(gh + 256 + u0);
            f32x4 br  = *(const f32x4*)(bR_s + u0);
            f32x4 bz  = *(const f32x4*)(bZ_s + u0);
            f32x4 bni = *(const f32x4*)(bNi_s + u0);
            f32x4 bnh = *(const f32x4*)(bNh_s + u0);
            f32x4 hold = *(const f32x4*)(hm_s + grow * 132 + u0);
            f32x4 hnew;
            f16x4 nh, nl;
            #pragma unroll
            for (int i = 0; i < 4; ++i) {
                float r = sigm_(gir[i] + ghr[i] + br[i]);
                float zg = sigm_(giz[i] + ghz[i] + bz[i]);
                float n = tanh_(gin[i] + bni[i] + r * (ghn[i] + bnh[i]));
                float hv = (1.f - zg) * n + zg * hold[i];
                hnew[i] = hv;
                _Float16 hhf = (_Float16)hv;
                nh[i] = hhf;
                nl[i] = (_Float16)(hv - (float)hhf);
            }
            *(f32x4*)(hm_s + grow * 132 + u0) = hnew;
            int hb = grow * 256 + ((u0 * 2) ^ ((grow & 7) << 4));
            *(f16x4*)(hhi_c + hb) = nh;
            *(f16x4*)(hlo_c + hb) = nl;
        }
        __syncthreads();
    }

    if (tid < 96) {
        int rr = tid / 6, c = tid - rr * 6, j = (c < 3) ? c : c - 3;
        const float* W = (c < 3) ? meanW : lvW;
        const float* B = (c < 3) ? meanB : lvB;
        float acc = B[j];
        const float4* W4 = (const float4*)(W + j * 128);
        const float4* h4 = (const float4*)(hm_s + rr * 132);
        #pragma unroll 4
        for (int kc = 0; kc < 32; ++kc) acc += dot4_(W4[kc], h4[kc]);
        mb_s[rr * 6 + c] = acc;
    }
    __syncthreads();
    if (tid < 48) {
        int rr = tid / 3, j = tid - rr * 3;
        int gb = b0 + rr;
        float m  = mb_s[rr * 6 + j];
        float lv = mb_s[rr * 6 + j + 3];
        o_mean[gb * 3 + j] = m;
        o_lv[gb * 3 + j]   = lv;
        z0[gb * 3 + j]     = m + eps[gb * 3 + j] * __expf(0.5f * lv);
    }
}

// ---------------------------------------------------------------- ODE kernel
// RK4 h=0.16 (12 steps) + final h=0.07, cubic-Hermite dense output at 0.01.
// 512 blocks x 256 threads, 8 rows/block, 2 blocks/CU. RK state (y, kacc, k1)
// private per thread (row r = tid>>5, 32-way redundant); 3 barriers/feval.
__global__ __launch_bounds__(256, 2) void k_ode(
    const float* __restrict__ dW1, const float* __restrict__ db1,
    const float* __restrict__ dW2, const float* __restrict__ db2,
    const float* __restrict__ dW3, const float* __restrict__ db3,
    const float* __restrict__ z0, float* __restrict__ traj)
{
    __shared__ alignas(16) unsigned short h1h_s[2048];   // [16][128] f16, swizzled
    __shared__ alignas(16) float h2f[8 * 104];
    __shared__ alignas(16) float W3s[312];
    __shared__ float b2s[100], b3s[3];
    __shared__ float fparts[24];

    const int tid  = threadIdx.x;
    const int b0   = blockIdx.x * 8;
    const int lane = tid & 63, wv = tid >> 6;
    const int r    = tid >> 5;           // row owned by this thread
    char* h1h_c = (char*)h1h_s;

    // init: zero pad rows 8..15 of h1, pad cols of h2f; stage W3/b2/b3
    for (int i = tid; i < 512; i += 256)
        ((unsigned int*)(h1h_c + 2048))[i] = 0u;
    if (tid < 32) h2f[(tid >> 2) * 104 + 100 + (tid & 3)] = 0.f;
    for (int i = tid; i < 312; i += 256) {
        int j = i / 104, k = i - j * 104;
        W3s[i] = (k < 100) ? dW3[j * 100 + k] : 0.f;
    }
    if (tid < 100) b2s[tid] = db2[tid];
    if (tid < 3)   b3s[tid] = db3[tid];

    // stage-1 weights in registers (4 consecutive k rows per thread)
    float w1r[12], b1r[4];
    {
        int k0 = (tid & 31) * 4;
        #pragma unroll
        for (int i = 0; i < 4; ++i) {
            int k = k0 + i;
            if (k < 100) {
                w1r[3 * i + 0] = dW1[k * 3 + 0];
                w1r[3 * i + 1] = dW1[k * 3 + 1];
                w1r[3 * i + 2] = dW1[k * 3 + 2];
                b1r[i] = db1[k];
            } else {
                w1r[3 * i + 0] = 0.f; w1r[3 * i + 1] = 0.f; w1r[3 * i + 2] = 0.f;
                b1r[i] = 0.f;
            }
        }
    }
    // W2 B-fragments (hi/lo), 2 col-tiles per wave
    f16x8 w2h[2][4], w2l[2][4];
    {
        const int lrow = lane & 15, lkb = lane >> 4;
        #pragma unroll
        for (int tile = 0; tile < 2; ++tile) {
            int col = (wv * 2 + tile) * 16 + lrow;
            #pragma unroll
            for (int ks = 0; ks < 4; ++ks) {
                f16x8 hv, lv;
                #pragma unroll
                for (int j = 0; j < 8; ++j) {
                    int k = ks * 32 + lkb * 8 + j;
                    float v = (col < 100 && k < 100) ? dW2[col * 100 + k] : 0.f;
                    _Float16 hf = (_Float16)v;
                    hv[j] = hf;
                    lv[j] = (_Float16)(v - (float)hf);
                }
                w2h[tile][ks] = hv;
                w2l[tile][ks] = lv;
            }
        }
    }

    // private RK state
    float yv0 = z0[(b0 + r) * 3 + 0];
    float yv1 = z0[(b0 + r) * 3 + 1];
    float yv2 = z0[(b0 + r) * 3 + 2];
    float ka0, ka1, ka2, k10, k11, k12, yn0, yn1, yn2;

    if (tid < 24) {
        int rr = tid / 3, j = tid - rr * 3;
        traj[((size_t)(b0 + rr)) * 3 + j] = z0[(b0 + rr) * 3 + j];
    }
    __syncthreads();

    const int lrow = lane & 15, lkb = lane >> 4;
    const int swA  = (lrow & 7) << 4;

    // one dynamics evaluation at (yt0,yt1,yt2); leaves f in fparts
#define FEVAL(yt0_, yt1_, yt2_)                                                  \
    do {                                                                          \
        { /* phase A: h1 = tanh(W1 yt + b1) -> f16 swizzled LDS */                \
            int q = tid & 31, k0 = q * 4;                                         \
            f16x4 hh_;                                                            \
            _Pragma("unroll")                                                     \
            for (int i = 0; i < 4; ++i) {                                         \
                float acc = b1r[i] + w1r[3 * i] * (yt0_)                          \
                          + w1r[3 * i + 1] * (yt1_) + w1r[3 * i + 2] * (yt2_);    \
                hh_[i] = (_Float16)tanh_(acc);                                    \
            }                                                                     \
            int off = r * 256 + ((k0 * 2) ^ (r << 4));                            \
            *(f16x4*)(h1h_c + off) = hh_;                                         \
        }                                                                         \
        __syncthreads();                                                          \
        { /* phase B: MFMA h2acc = h1 @ W2^T ; phase C: tanh -> h2f */            \
            f16x8 ah[4];                                                          \
            _Pragma("unroll")                                                     \
            for (int ks = 0; ks < 4; ++ks) {                                      \
                int off = lrow * 256 + ((ks * 64 + lkb * 16) ^ swA);              \
                ah[ks] = *(const f16x8*)(h1h_c + off);                            \
            }                                                                     \
            f32x4 acc0 = {0.f, 0.f, 0.f, 0.f}, acc1 = {0.f, 0.f, 0.f, 0.f};       \
            _Pragma("unroll")                                                     \
            for (int ks = 0; ks < 4; ++ks) {                                      \
                acc0 = MFMA16(ah[ks], w2h[0][ks], acc0);                          \
                acc0 = MFMA16(ah[ks], w2l[0][ks], acc0);                          \
                acc1 = MFMA16(ah[ks], w2h[1][ks], acc1);                          \
                acc1 = MFMA16(ah[ks], w2l[1][ks], acc1);                          \
            }                                                                     \
            if (lkb < 2) {                                                        \
                int r0 = lkb * 4;                                                 \
                _Pragma("unroll")                                                 \
                for (int tile = 0; tile < 2; ++tile) {                            \
                    int col = (wv * 2 + tile) * 16 + lrow;                        \
                    f32x4 a = tile ? acc1 : acc0;                                 \
                    if (col < 100) {                                              \
                        float bb = b2s[col];                                      \
                        _Pragma("unroll")                                         \
                        for (int i = 0; i < 4; ++i)                               \
                            h2f[(r0 + i) * 104 + col] = tanh_(a[i] + bb);         \
                    }                                                             \
                }                                                                 \
            }                                                                     \
        }                                                                         \
        __syncthreads();                                                          \
        { /* phase D: f = W3 h2 + b3 via quarter-dots + shfl reduce */            \
            if (tid < 96) {                                                       \
                int rr = tid / 12, rem = tid - rr * 12, j = rem >> 2, qc = rem & 3;\
                const float4* Wj = (const float4*)(W3s + j * 104);                \
                const float4* Hr = (const float4*)(h2f + rr * 104);               \
                float acc = 0.f;                                                  \
                _Pragma("unroll")                                                 \
                for (int kc = 0; kc < 7; ++kc) {                                  \
                    int k = qc + kc * 4;                                          \
                    if (k < 26) acc += dot4_(Wj[k], Hr[k]);                       \
                }                                                                 \
                acc += __shfl_xor(acc, 1);                                        \
                acc += __shfl_xor(acc, 2);                                        \
                if (qc == 0) fparts[rr * 3 + j] = acc + b3s[j];                   \
            }                                                                     \
        }                                                                         \
        __syncthreads();                                                          \
    } while (0)

    // initial f(z0)
    FEVAL(yv0, yv1, yv2);

    #pragma unroll 1
    for (int s = 0; s < 13; ++s) {
        const int   nInt = (s < 12) ? 16 : 7;
        const float hh   = 0.01f * (float)nInt;
        const int   t0   = s * 16;
        const float invN = (s < 12) ? 0.0625f : (1.f / 7.f);

        // k1 -> yt
        float f0_ = fparts[r * 3 + 0], f1_ = fparts[r * 3 + 1], f2_ = fparts[r * 3 + 2];
        k10 = f0_; k11 = f1_; k12 = f2_;
        ka0 = f0_; ka1 = f1_; ka2 = f2_;
        float yt0 = yv0 + 0.5f * hh * f0_, yt1 = yv1 + 0.5f * hh * f1_, yt2 = yv2 + 0.5f * hh * f2_;
        FEVAL(yt0, yt1, yt2);                                   // k2
        f0_ = fparts[r * 3 + 0]; f1_ = fparts[r * 3 + 1]; f2_ = fparts[r * 3 + 2];
        ka0 += 2.f * f0_; ka1 += 2.f * f1_; ka2 += 2.f * f2_;
        yt0 = yv0 + 0.5f * hh * f0_; yt1 = yv1 + 0.5f * hh * f1_; yt2 = yv2 + 0.5f * hh * f2_;
        FEVAL(yt0, yt1, yt2);                                   // k3
        f0_ = fparts[r * 3 + 0]; f1_ = fparts[r * 3 + 1]; f2_ = fparts[r * 3 + 2];
        ka0 += 2.f * f0_; ka1 += 2.f * f1_; ka2 += 2.f * f2_;
        yt0 = yv0 + hh * f0_; yt1 = yv1 + hh * f1_; yt2 = yv2 + hh * f2_;
        FEVAL(yt0, yt1, yt2);                                   // k4
        f0_ = fparts[r * 3 + 0]; f1_ = fparts[r * 3 + 1]; f2_ = fparts[r * 3 + 2];
        ka0 += f0_; ka1 += f1_; ka2 += f2_;
        const float h6 = hh * (1.f / 6.f);
        yn0 = yv0 + h6 * ka0; yn1 = yv1 + h6 * ka1; yn2 = yv2 + h6 * ka2;
        FEVAL(yn0, yn1, yn2);                                   // f at t+h (next k1)
        float fn0 = fparts[r * 3 + 0], fn1 = fparts[r * 3 + 1], fn2 = fparts[r * 3 + 2];

        // dense output: 3*nInt values per row, emitted by the row's 32 threads
        {
            int tot = 3 * nInt;
            for (int ii = (tid & 31); ii < tot; ii += 32) {
                int q = ii / 3, j = ii - q * 3;
                float ysj = (j == 0) ? yv0 : (j == 1) ? yv1 : yv2;
                float f0j = (j == 0) ? k10 : (j == 1) ? k11 : k12;
                float ynj = (j == 0) ? yn0 : (j == 1) ? yn1 : yn2;
                float fnj = (j == 0) ? fn0 : (j == 1) ? fn1 : fn2;
                float th  = (float)(q + 1) * invN;
                float th2 = th * th, th3 = th2 * th;
                float ca = 2.f * th3 - 3.f * th2 + 1.f;
                float cb = th3 - 2.f * th2 + th;
                float cc = 3.f * th2 - 2.f * th3;
                float cd = th3 - th2;
                float v = ca * ysj + cb * hh * f0j + cc * ynj + cd * hh * fnj;
                traj[((size_t)(t0 + 1 + q) * 4096 + b0 + r) * 3 + j] = v;
            }
        }
        yv0 = yn0; yv1 = yn1; yv2 = yn2;
    }
#undef FEVAL
}

// ---------------------------------------------------------------- decoder (MFMA)
// (unchanged from round 4)
__global__ __launch_bounds__(256, 2) void k_dec(
    const float* __restrict__ traj, const float* __restrict__ W1, const float* __restrict__ b1,
    const float* __restrict__ W2, const float* __restrict__ b2, float* __restrict__ recon)
{
    __shared__ alignas(16) unsigned short hdh_s[8192], hdl_s[8192];
    __shared__ alignas(16) float zs[384];
    __shared__ float w1s[192], b1s_[64];

    const int tid  = threadIdx.x;
    const size_t p0 = (size_t)blockIdx.x * 128;
    const int lane = tid & 63, wv = tid >> 6;
    const int lrow = lane & 15, lkb = lane >> 4;

    char* hdh_c = (char*)hdh_s;
    char* hdl_c = (char*)hdl_s;

    if (tid < 96) *(float4*)&zs[tid * 4] = ((const float4*)(traj + p0 * 3))[tid];
    if (tid < 192) w1s[tid] = W1[tid];
    if (tid < 64)  b1s_[tid] = b1[tid];

    f16x8 bh[2], bl[2];
    {
        int col = wv * 16 + lrow;
        #pragma unroll
        for (int ks = 0; ks < 2; ++ks) {
            const float* wp = W2 + col * 64 + ks * 32 + lkb * 8;
            float4 a = *(const float4*)wp, b = *(const float4*)(wp + 4);
            float tmp[8] = {a.x, a.y, a.z, a.w, b.x, b.y, b.z, b.w};
            f16x8 hv, lv;
            #pragma unroll
            for (int j = 0; j < 8; ++j) {
                hv[j] = (_Float16)tmp[j];
                lv[j] = (_Float16)(tmp[j] - (float)hv[j]);
            }
            bh[ks] = hv;
            bl[ks] = lv;
        }
    }
    const float bo = b2[wv * 16 + lrow];
    __syncthreads();

    {
        const int p  = tid >> 1;
        const int u0 = (tid & 1) * 32;
        const float z0v = zs[p * 3 + 0], z1v = zs[p * 3 + 1], z2v = zs[p * 3 + 2];
        const int sw = (p & 7) << 4;
        #pragma unroll
        for (int c = 0; c < 8; ++c) {
            f16x4 hh_, hl_;
            #pragma unroll
            for (int i = 0; i < 4; ++i) {
                int u = u0 + c * 4 + i;
                float acc = b1s_[u] + w1s[u * 3 + 0] * z0v
                                    + w1s[u * 3 + 1] * z1v
                                    + w1s[u * 3 + 2] * z2v;
                float h = fmaxf(acc, 0.f);
                _Float16 hf = (_Float16)h;
                hh_[i] = hf;
                hl_[i] = (_Float16)(h - (float)hf);
            }
            int off = p * 128 + (((u0 + c * 4) * 2) ^ sw);
            *(f16x4*)(hdh_c + off) = hh_;
            *(f16x4*)(hdl_c + off) = hl_;
        }
    }
    __syncthreads();

    const int swA = (lrow & 7) << 4;
    #pragma unroll
    for (int rt = 0; rt < 8; ++rt) {
        f16x8 ahh[2], all_[2];
        #pragma unroll
        for (int ks = 0; ks < 2; ++ks) {
            int off = (rt * 16 + lrow) * 128 + ((ks * 64 + lkb * 16) ^ swA);
            ahh[ks]  = *(const f16x8*)(hdh_c + off);
            all_[ks] = *(const f16x8*)(hdl_c + off);
        }
        f32x4 acc = {0.f, 0.f, 0.f, 0.f};
        #pragma unroll
        for (int ks = 0; ks < 2; ++ks) {
            acc = MFMA16(ahh[ks],  bh[ks], acc);
            acc = MFMA16(all_[ks], bh[ks], acc);
            acc = MFMA16(ahh[ks],  bl[ks], acc);
        }
        const size_t rowg = p0 + rt * 16 + lkb * 4;
        #pragma unroll
        for (int i = 0; i < 4; ++i)
            recon[(rowg + i) * 64 + wv * 16 + lrow] = acc[i] + bo;
    }
}

extern "C" void kernel_launch(void* const* d_in, const int* in_sizes, int n_in,
                              void* d_out, int out_size, void* d_ws, size_t ws_size,
                              hipStream_t stream)
{
    const float* obs   = (const float*)d_in[0];
    const float* eps   = (const float*)d_in[1];
    const float* Wih   = (const float*)d_in[2];
    const float* Whh   = (const float*)d_in[3];
    const float* bih   = (const float*)d_in[4];
    const float* bhh   = (const float*)d_in[5];
    const float* meanW = (const float*)d_in[6];
    const float* meanB = (const float*)d_in[7];
    const float* lvW   = (const float*)d_in[8];
    const float* lvB   = (const float*)d_in[9];
    const float* dW1   = (const float*)d_in[10];
    const float* db1   = (const float*)d_in[11];
    const float* dW2   = (const float*)d_in[12];
    const float* db2   = (const float*)d_in[13];
    const float* dW3   = (const float*)d_in[14];
    const float* db3   = (const float*)d_in[15];
    const float* decW1 = (const float*)d_in[16];
    const float* decb1 = (const float*)d_in[17];
    const float* decW2 = (const float*)d_in[18];
    const float* decb2 = (const float*)d_in[19];

    float* out   = (float*)d_out;
    float* recon = out;
    float* omean = out + OFF_MEAN;
    float* olv   = out + OFF_LV;
    float* traj  = out + OFF_TRAJ;
    float* z0    = (float*)d_ws;

    k_gru<<<dim3(256), dim3(512), 0, stream>>>(obs, eps, Wih, Whh, bih, bhh,
                                               meanW, meanB, lvW, lvB, omean, olv, z0);
    k_ode<<<dim3(512), dim3(256), 0, stream>>>(dW1, db1, dW2, db2, dW3, db3, z0, traj);
    k_dec<<<dim3(6400), dim3(256), 0, stream>>>(traj, decW1, decb1, decW2, decb2, recon);
}

// Round 6
// 228.014 us; speedup vs baseline: 10.9450x; 1.1258x over previous
//
#include <hip/hip_runtime.h>
#include <stddef.h>

// Output layout (fp32):
//   recon    [200,4096,64] @ 0
//   z0_mean  [4096,3]      @ 52428800
//   z0_logvar[4096,3]      @ 52441088
//   traj     [200,4096,3]  @ 52453376
#define OFF_MEAN 52428800
#define OFF_LV   52441088
#define OFF_TRAJ 52453376

typedef _Float16 f16x8 __attribute__((ext_vector_type(8)));
typedef _Float16 f16x4 __attribute__((ext_vector_type(4)));
typedef float    f32x4 __attribute__((ext_vector_type(4)));

#define MFMA16(a, b, c) __builtin_amdgcn_mfma_f32_16x16x32_f16((a), (b), (c), 0, 0, 0)

// fast transcendentals: v_exp_f32 + v_rcp_f32 (error ~1e-6, far below budget)
__device__ __forceinline__ float sigm_(float x) {
    float e = __builtin_amdgcn_exp2f(x * -1.442695041f);
    return __builtin_amdgcn_rcpf(1.f + e);
}
__device__ __forceinline__ float tanh_(float x) {
    float e = __builtin_amdgcn_exp2f(x * 2.885390082f);
    return 1.f - 2.f * __builtin_amdgcn_rcpf(e + 1.f);
}
__device__ __forceinline__ float dot4_(float4 a, float4 b) {
    return a.x * b.x + a.y * b.y + a.z * b.z + a.w * b.w;
}

// ---------------------------------------------------------------- GRU (MFMA, gate-aligned tiles)
// 256 blocks x 512 threads (8 waves); 16 batch rows/block; 50 steps.
// Wave w owns gate tiles {w, 8+w, 16+w} -> lane (lrow,lkb) owns unit
// u = w*16+lrow, batch rows lkb*4..+3, with r/z/n accumulators all local.
// Gate math entirely in registers; h hi/lo written straight back to the
// swizzled A-frag buffers. 2 barriers/step, no intermediate LDS tensors.
__global__ __launch_bounds__(512, 2) void k_gru(
    const float* __restrict__ obs, const float* __restrict__ eps,
    const float* __restrict__ Wih, const float* __restrict__ Whh,
    const float* __restrict__ bih, const float* __restrict__ bhh,
    const float* __restrict__ meanW, const float* __restrict__ meanB,
    const float* __restrict__ lvW,  const float* __restrict__ lvB,
    float* __restrict__ o_mean, float* __restrict__ o_lv, float* __restrict__ z0)
{
    __shared__ alignas(16) unsigned short hhi_s[2048], hlo_s[2048];  // [16][128] f16, swizzled
    __shared__ alignas(16) unsigned short xhi_s[1024], xlo_s[1024];  // [16][64]  f16, swizzled
    __shared__ alignas(16) float hm_s[16 * 132];
    __shared__ float mb_s[96];

    const int tid  = threadIdx.x;
    const int b0   = blockIdx.x * 16;
    const int lane = tid & 63, wv = tid >> 6;
    const int lrow = lane & 15, lkb = lane >> 4;
    const int swA  = (lrow & 7) << 4;
    const int u    = wv * 16 + lrow;          // unit owned by this lane

    char* hhi_c = (char*)hhi_s; char* hlo_c = (char*)hlo_s;
    char* xhi_c = (char*)xhi_s; char* xlo_c = (char*)xlo_s;

    for (int i = tid; i < 2048; i += 512) { hhi_s[i] = 0; hlo_s[i] = 0; }

    // biases (per-lane scalars)
    const float bR  = bih[u]       + bhh[u];
    const float bZ  = bih[128 + u] + bhh[128 + u];
    const float bNi = bih[256 + u];
    const float bNh = bhh[256 + u];

    // Wih B-fragments (f16 single), tiles {u, 128+u, 256+u} rows
    f16x8 wihf[3][2];
    #pragma unroll
    for (int g = 0; g < 3; ++g) {
        int col = g * 128 + u;
        #pragma unroll
        for (int ks = 0; ks < 2; ++ks) {
            const float* wp = Wih + col * 64 + ks * 32 + lkb * 8;
            float4 a = *(const float4*)wp, b = *(const float4*)(wp + 4);
            float tmp[8] = {a.x, a.y, a.z, a.w, b.x, b.y, b.z, b.w};
            f16x8 hv;
            #pragma unroll
            for (int j = 0; j < 8; ++j) hv[j] = (_Float16)tmp[j];
            wihf[g][ks] = hv;
        }
    }
    // Whh B-fragments (f16 hi+lo)
    f16x8 whhh[3][4], whhl[3][4];
    #pragma unroll
    for (int g = 0; g < 3; ++g) {
        int col = g * 128 + u;
        #pragma unroll
        for (int ks = 0; ks < 4; ++ks) {
            const float* wp = Whh + col * 128 + ks * 32 + lkb * 8;
            float4 a = *(const float4*)wp, b = *(const float4*)(wp + 4);
            float tmp[8] = {a.x, a.y, a.z, a.w, b.x, b.y, b.z, b.w};
            f16x8 hv, lv;
            #pragma unroll
            for (int j = 0; j < 8; ++j) {
                hv[j] = (_Float16)tmp[j];
                lv[j] = (_Float16)(tmp[j] - (float)hv[j]);
            }
            whhh[g][ks] = hv;
            whhl[g][ks] = lv;
        }
    }

    f32x4 hold = {0.f, 0.f, 0.f, 0.f};        // h_prev for (rows lkb*4..+3, unit u)

    for (int t = 0; t < 50; ++t) {
        // stage x(t): 16 rows x 64 cols fp32 -> f16 hi/lo swizzled
        if (tid < 256) {
            int row = tid >> 4, kq = (tid & 15) * 4;
            float4 v = *(const float4*)(obs + ((size_t)t * 4096 + b0 + row) * 64 + kq);
            float tmp[4] = {v.x, v.y, v.z, v.w};
            f16x4 vh, vl;
            #pragma unroll
            for (int j = 0; j < 4; ++j) {
                vh[j] = (_Float16)tmp[j];
                vl[j] = (_Float16)(tmp[j] - (float)vh[j]);
            }
            int xb = row * 128 + ((kq * 2) ^ ((row & 7) << 4));
            *(f16x4*)(xhi_c + xb) = vh;
            *(f16x4*)(xlo_c + xb) = vl;
        }
        __syncthreads();

        // A-fragments
        f16x8 xh[2], xl[2], hh[4], hl[4];
        #pragma unroll
        for (int ks = 0; ks < 2; ++ks) {
            int off = lrow * 128 + ((ks * 64 + lkb * 16) ^ swA);
            xh[ks] = *(const f16x8*)(xhi_c + off);
            xl[ks] = *(const f16x8*)(xlo_c + off);
        }
        #pragma unroll
        for (int ks = 0; ks < 4; ++ks) {
            int off = lrow * 256 + ((ks * 64 + lkb * 16) ^ swA);
            hh[ks] = *(const f16x8*)(hhi_c + off);
            hl[ks] = *(const f16x8*)(hlo_c + off);
        }

        f32x4 z4 = {0.f, 0.f, 0.f, 0.f};
        f32x4 aR = z4, aZ = z4, aNi = z4, aNh = z4;
        #pragma unroll
        for (int ks = 0; ks < 2; ++ks) {
            aR  = MFMA16(xh[ks], wihf[0][ks], aR);
            aR  = MFMA16(xl[ks], wihf[0][ks], aR);
            aZ  = MFMA16(xh[ks], wihf[1][ks], aZ);
            aZ  = MFMA16(xl[ks], wihf[1][ks], aZ);
            aNi = MFMA16(xh[ks], wihf[2][ks], aNi);
            aNi = MFMA16(xl[ks], wihf[2][ks], aNi);
        }
        #pragma unroll
        for (int ks = 0; ks < 4; ++ks) {
            aR  = MFMA16(hh[ks], whhh[0][ks], aR);
            aR  = MFMA16(hl[ks], whhh[0][ks], aR);
            aR  = MFMA16(hh[ks], whhl[0][ks], aR);
            aZ  = MFMA16(hh[ks], whhh[1][ks], aZ);
            aZ  = MFMA16(hl[ks], whhh[1][ks], aZ);
            aZ  = MFMA16(hh[ks], whhl[1][ks], aZ);
            aNh = MFMA16(hh[ks], whhh[2][ks], aNh);
            aNh = MFMA16(hl[ks], whhh[2][ks], aNh);
            aNh = MFMA16(hh[ks], whhl[2][ks], aNh);
        }

        // gates in registers; write h(t) hi/lo back to swizzled A-frag buffers
        #pragma unroll
        for (int i = 0; i < 4; ++i) {
            float r  = sigm_(aR[i] + bR);
            float zg = sigm_(aZ[i] + bZ);
            float n  = tanh_(aNi[i] + bNi + r * (aNh[i] + bNh));
            float hv = (1.f - zg) * n + zg * hold[i];
            hold[i] = hv;
            _Float16 nh = (_Float16)hv;
            _Float16 nl = (_Float16)(hv - (float)nh);
            int ri = lkb * 4 + i;
            int hb = ri * 256 + ((u * 2) ^ ((ri & 7) << 4));
            *(_Float16*)(hhi_c + hb) = nh;
            *(_Float16*)(hlo_c + hb) = nl;
        }
        __syncthreads();
    }

    // dump h_last to LDS for the heads
    #pragma unroll
    for (int i = 0; i < 4; ++i)
        hm_s[(lkb * 4 + i) * 132 + u] = hold[i];
    __syncthreads();

    if (tid < 96) {
        int rr = tid / 6, c = tid - rr * 6, j = (c < 3) ? c : c - 3;
        const float* W = (c < 3) ? meanW : lvW;
        const float* B = (c < 3) ? meanB : lvB;
        float acc = B[j];
        const float4* W4 = (const float4*)(W + j * 128);
        const float4* h4 = (const float4*)(hm_s + rr * 132);
        #pragma unroll 4
        for (int kc = 0; kc < 32; ++kc) acc += dot4_(W4[kc], h4[kc]);
        mb_s[rr * 6 + c] = acc;
    }
    __syncthreads();
    if (tid < 48) {
        int rr = tid / 3, j = tid - rr * 3;
        int gb = b0 + rr;
        float m  = mb_s[rr * 6 + j];
        float lv = mb_s[rr * 6 + j + 3];
        o_mean[gb * 3 + j] = m;
        o_lv[gb * 3 + j]   = lv;
        z0[gb * 3 + j]     = m + eps[gb * 3 + j] * __expf(0.5f * lv);
    }
}

// ---------------------------------------------------------------- ODE kernel
// (unchanged from round 5)
__global__ __launch_bounds__(256, 2) void k_ode(
    const float* __restrict__ dW1, const float* __restrict__ db1,
    const float* __restrict__ dW2, const float* __restrict__ db2,
    const float* __restrict__ dW3, const float* __restrict__ db3,
    const float* __restrict__ z0, float* __restrict__ traj)
{
    __shared__ alignas(16) unsigned short h1h_s[2048];
    __shared__ alignas(16) float h2f[8 * 104];
    __shared__ alignas(16) float W3s[312];
    __shared__ float b2s[100], b3s[3];
    __shared__ float fparts[24];

    const int tid  = threadIdx.x;
    const int b0   = blockIdx.x * 8;
    const int lane = tid & 63, wv = tid >> 6;
    const int r    = tid >> 5;
    char* h1h_c = (char*)h1h_s;

    for (int i = tid; i < 512; i += 256)
        ((unsigned int*)(h1h_c + 2048))[i] = 0u;
    if (tid < 32) h2f[(tid >> 2) * 104 + 100 + (tid & 3)] = 0.f;
    for (int i = tid; i < 312; i += 256) {
        int j = i / 104, k = i - j * 104;
        W3s[i] = (k < 100) ? dW3[j * 100 + k] : 0.f;
    }
    if (tid < 100) b2s[tid] = db2[tid];
    if (tid < 3)   b3s[tid] = db3[tid];

    float w1r[12], b1r[4];
    {
        int k0 = (tid & 31) * 4;
        #pragma unroll
        for (int i = 0; i < 4; ++i) {
            int k = k0 + i;
            if (k < 100) {
                w1r[3 * i + 0] = dW1[k * 3 + 0];
                w1r[3 * i + 1] = dW1[k * 3 + 1];
                w1r[3 * i + 2] = dW1[k * 3 + 2];
                b1r[i] = db1[k];
            } else {
                w1r[3 * i + 0] = 0.f; w1r[3 * i + 1] = 0.f; w1r[3 * i + 2] = 0.f;
                b1r[i] = 0.f;
            }
        }
    }
    f16x8 w2h[2][4], w2l[2][4];
    {
        const int lrow = lane & 15, lkb = lane >> 4;
        #pragma unroll
        for (int tile = 0; tile < 2; ++tile) {
            int col = (wv * 2 + tile) * 16 + lrow;
            #pragma unroll
            for (int ks = 0; ks < 4; ++ks) {
                f16x8 hv, lv;
                #pragma unroll
                for (int j = 0; j < 8; ++j) {
                    int k = ks * 32 + lkb * 8 + j;
                    float v = (col < 100 && k < 100) ? dW2[col * 100 + k] : 0.f;
                    _Float16 hf = (_Float16)v;
                    hv[j] = hf;
                    lv[j] = (_Float16)(v - (float)hf);
                }
                w2h[tile][ks] = hv;
                w2l[tile][ks] = lv;
            }
        }
    }

    float yv0 = z0[(b0 + r) * 3 + 0];
    float yv1 = z0[(b0 + r) * 3 + 1];
    float yv2 = z0[(b0 + r) * 3 + 2];
    float ka0, ka1, ka2, k10, k11, k12, yn0, yn1, yn2;

    if (tid < 24) {
        int rr = tid / 3, j = tid - rr * 3;
        traj[((size_t)(b0 + rr)) * 3 + j] = z0[(b0 + rr) * 3 + j];
    }
    __syncthreads();

    const int lrow = lane & 15, lkb = lane >> 4;
    const int swA  = (lrow & 7) << 4;

#define FEVAL(yt0_, yt1_, yt2_)                                                  \
    do {                                                                          \
        {                                                                         \
            int q = tid & 31, k0 = q * 4;                                         \
            f16x4 hh_;                                                            \
            _Pragma("unroll")                                                     \
            for (int i = 0; i < 4; ++i) {                                         \
                float acc = b1r[i] + w1r[3 * i] * (yt0_)                          \
                          + w1r[3 * i + 1] * (yt1_) + w1r[3 * i + 2] * (yt2_);    \
                hh_[i] = (_Float16)tanh_(acc);                                    \
            }                                                                     \
            int off = r * 256 + ((k0 * 2) ^ (r << 4));                            \
            *(f16x4*)(h1h_c + off) = hh_;                                         \
        }                                                                         \
        __syncthreads();                                                          \
        {                                                                         \
            f16x8 ah[4];                                                          \
            _Pragma("unroll")                                                     \
            for (int ks = 0; ks < 4; ++ks) {                                      \
                int off = lrow * 256 + ((ks * 64 + lkb * 16) ^ swA);              \
                ah[ks] = *(const f16x8*)(h1h_c + off);                            \
            }                                                                     \
            f32x4 acc0 = {0.f, 0.f, 0.f, 0.f}, acc1 = {0.f, 0.f, 0.f, 0.f};       \
            _Pragma("unroll")                                                     \
            for (int ks = 0; ks < 4; ++ks) {                                      \
                acc0 = MFMA16(ah[ks], w2h[0][ks], acc0);                          \
                acc0 = MFMA16(ah[ks], w2l[0][ks], acc0);                          \
                acc1 = MFMA16(ah[ks], w2h[1][ks], acc1);                          \
                acc1 = MFMA16(ah[ks], w2l[1][ks], acc1);                          \
            }                                                                     \
            if (lkb < 2) {                                                        \
                int r0 = lkb * 4;                                                 \
                _Pragma("unroll")                                                 \
                for (int tile = 0; tile < 2; ++tile) {                            \
                    int col = (wv * 2 + tile) * 16 + lrow;                        \
                    f32x4 a = tile ? acc1 : acc0;                                 \
                    if (col < 100) {                                              \
                        float bb = b2s[col];                                      \
                        _Pragma("unroll")                                         \
                        for (int i = 0; i < 4; ++i)                               \
                            h2f[(r0 + i) * 104 + col] = tanh_(a[i] + bb);         \
                    }                                                             \
                }                                                                 \
            }                                                                     \
        }                                                                         \
        __syncthreads();                                                          \
        {                                                                         \
            if (tid < 96) {                                                       \
                int rr = tid / 12, rem = tid - rr * 12, j = rem >> 2, qc = rem & 3;\
                const float4* Wj = (const float4*)(W3s + j * 104);                \
                const float4* Hr = (const float4*)(h2f + rr * 104);               \
                float acc = 0.f;                                                  \
                _Pragma("unroll")                                                 \
                for (int kc = 0; kc < 7; ++kc) {                                  \
                    int k = qc + kc * 4;                                          \
                    if (k < 26) acc += dot4_(Wj[k], Hr[k]);                       \
                }                                                                 \
                acc += __shfl_xor(acc, 1);                                        \
                acc += __shfl_xor(acc, 2);                                        \
                if (qc == 0) fparts[rr * 3 + j] = acc + b3s[j];                   \
            }                                                                     \
        }                                                                         \
        __syncthreads();                                                          \
    } while (0)

    FEVAL(yv0, yv1, yv2);

    #pragma unroll 1
    for (int s = 0; s < 13; ++s) {
        const int   nInt = (s < 12) ? 16 : 7;
        const float hh   = 0.01f * (float)nInt;
        const int   t0   = s * 16;
        const float invN = (s < 12) ? 0.0625f : (1.f / 7.f);

        float f0_ = fparts[r * 3 + 0], f1_ = fparts[r * 3 + 1], f2_ = fparts[r * 3 + 2];
        k10 = f0_; k11 = f1_; k12 = f2_;
        ka0 = f0_; ka1 = f1_; ka2 = f2_;
        float yt0 = yv0 + 0.5f * hh * f0_, yt1 = yv1 + 0.5f * hh * f1_, yt2 = yv2 + 0.5f * hh * f2_;
        FEVAL(yt0, yt1, yt2);
        f0_ = fparts[r * 3 + 0]; f1_ = fparts[r * 3 + 1]; f2_ = fparts[r * 3 + 2];
        ka0 += 2.f * f0_; ka1 += 2.f * f1_; ka2 += 2.f * f2_;
        yt0 = yv0 + 0.5f * hh * f0_; yt1 = yv1 + 0.5f * hh * f1_; yt2 = yv2 + 0.5f * hh * f2_;
        FEVAL(yt0, yt1, yt2);
        f0_ = fparts[r * 3 + 0]; f1_ = fparts[r * 3 + 1]; f2_ = fparts[r * 3 + 2];
        ka0 += 2.f * f0_; ka1 += 2.f * f1_; ka2 += 2.f * f2_;
        yt0 = yv0 + hh * f0_; yt1 = yv1 + hh * f1_; yt2 = yv2 + hh * f2_;
        FEVAL(yt0, yt1, yt2);
        f0_ = fparts[r * 3 + 0]; f1_ = fparts[r * 3 + 1]; f2_ = fparts[r * 3 + 2];
        ka0 += f0_; ka1 += f1_; ka2 += f2_;
        const float h6 = hh * (1.f / 6.f);
        yn0 = yv0 + h6 * ka0; yn1 = yv1 + h6 * ka1; yn2 = yv2 + h6 * ka2;
        FEVAL(yn0, yn1, yn2);
        float fn0 = fparts[r * 3 + 0], fn1 = fparts[r * 3 + 1], fn2 = fparts[r * 3 + 2];

        {
            int tot = 3 * nInt;
            for (int ii = (tid & 31); ii < tot; ii += 32) {
                int q = ii / 3, j = ii - q * 3;
                float ysj = (j == 0) ? yv0 : (j == 1) ? yv1 : yv2;
                float f0j = (j == 0) ? k10 : (j == 1) ? k11 : k12;
                float ynj = (j == 0) ? yn0 : (j == 1) ? yn1 : yn2;
                float fnj = (j == 0) ? fn0 : (j == 1) ? fn1 : fn2;
                float th  = (float)(q + 1) * invN;
                float th2 = th * th, th3 = th2 * th;
                float ca = 2.f * th3 - 3.f * th2 + 1.f;
                float cb = th3 - 2.f * th2 + th;
                float cc = 3.f * th2 - 2.f * th3;
                float cd = th3 - th2;
                float v = ca * ysj + cb * hh * f0j + cc * ynj + cd * hh * fnj;
                traj[((size_t)(t0 + 1 + q) * 4096 + b0 + r) * 3 + j] = v;
            }
        }
        yv0 = yn0; yv1 = yn1; yv2 = yn2;
    }
#undef FEVAL
}

// ---------------------------------------------------------------- decoder (MFMA)
// (unchanged from round 4)
__global__ __launch_bounds__(256, 2) void k_dec(
    const float* __restrict__ traj, const float* __restrict__ W1, const float* __restrict__ b1,
    const float* __restrict__ W2, const float* __restrict__ b2, float* __restrict__ recon)
{
    __shared__ alignas(16) unsigned short hdh_s[8192], hdl_s[8192];
    __shared__ alignas(16) float zs[384];
    __shared__ float w1s[192], b1s_[64];

    const int tid  = threadIdx.x;
    const size_t p0 = (size_t)blockIdx.x * 128;
    const int lane = tid & 63, wv = tid >> 6;
    const int lrow = lane & 15, lkb = lane >> 4;

    char* hdh_c = (char*)hdh_s;
    char* hdl_c = (char*)hdl_s;

    if (tid < 96) *(float4*)&zs[tid * 4] = ((const float4*)(traj + p0 * 3))[tid];
    if (tid < 192) w1s[tid] = W1[tid];
    if (tid < 64)  b1s_[tid] = b1[tid];

    f16x8 bh[2], bl[2];
    {
        int col = wv * 16 + lrow;
        #pragma unroll
        for (int ks = 0; ks < 2; ++ks) {
            const float* wp = W2 + col * 64 + ks * 32 + lkb * 8;
            float4 a = *(const float4*)wp, b = *(const float4*)(wp + 4);
            float tmp[8] = {a.x, a.y, a.z, a.w, b.x, b.y, b.z, b.w};
            f16x8 hv, lv;
            #pragma unroll
            for (int j = 0; j < 8; ++j) {
                hv[j] = (_Float16)tmp[j];
                lv[j] = (_Float16)(tmp[j] - (float)hv[j]);
            }
            bh[ks] = hv;
            bl[ks] = lv;
        }
    }
    const float bo = b2[wv * 16 + lrow];
    __syncthreads();

    {
        const int p  = tid >> 1;
        const int u0 = (tid & 1) * 32;
        const float z0v = zs[p * 3 + 0], z1v = zs[p * 3 + 1], z2v = zs[p * 3 + 2];
        const int sw = (p & 7) << 4;
        #pragma unroll
        for (int c = 0; c < 8; ++c) {
            f16x4 hh_, hl_;
            #pragma unroll
            for (int i = 0; i < 4; ++i) {
                int u = u0 + c * 4 + i;
                float acc = b1s_[u] + w1s[u * 3 + 0] * z0v
                                    + w1s[u * 3 + 1] * z1v
                                    + w1s[u * 3 + 2] * z2v;
                float h = fmaxf(acc, 0.f);
                _Float16 hf = (_Float16)h;
                hh_[i] = hf;
                hl_[i] = (_Float16)(h - (float)hf);
            }
            int off = p * 128 + (((u0 + c * 4) * 2) ^ sw);
            *(f16x4*)(hdh_c + off) = hh_;
            *(f16x4*)(hdl_c + off) = hl_;
        }
    }
    __syncthreads();

    const int swA = (lrow & 7) << 4;
    #pragma unroll
    for (int rt = 0; rt < 8; ++rt) {
        f16x8 ahh[2], all_[2];
        #pragma unroll
        for (int ks = 0; ks < 2; ++ks) {
            int off = (rt * 16 + lrow) * 128 + ((ks * 64 + lkb * 16) ^ swA);
            ahh[ks]  = *(const f16x8*)(hdh_c + off);
            all_[ks] = *(const f16x8*)(hdl_c + off);
        }
        f32x4 acc = {0.f, 0.f, 0.f, 0.f};
        #pragma unroll
        for (int ks = 0; ks < 2; ++ks) {
            acc = MFMA16(ahh[ks],  bh[ks], acc);
            acc = MFMA16(all_[ks], bh[ks], acc);
            acc = MFMA16(ahh[ks],  bl[ks], acc);
        }
        const size_t rowg = p0 + rt * 16 + lkb * 4;
        #pragma unroll
        for (int i = 0; i < 4; ++i)
            recon[(rowg + i) * 64 + wv * 16 + lrow] = acc[i] + bo;
    }
}

extern "C" void kernel_launch(void* const* d_in, const int* in_sizes, int n_in,
                              void* d_out, int out_size, void* d_ws, size_t ws_size,
                              hipStream_t stream)
{
    const float* obs   = (const float*)d_in[0];
    const float* eps   = (const float*)d_in[1];
    const float* Wih   = (const float*)d_in[2];
    const float* Whh   = (const float*)d_in[3];
    const float* bih   = (const float*)d_in[4];
    const float* bhh   = (const float*)d_in[5];
    const float* meanW = (const float*)d_in[6];
    const float* meanB = (const float*)d_in[7];
    const float* lvW   = (const float*)d_in[8];
    const float* lvB   = (const float*)d_in[9];
    const float* dW1   = (const float*)d_in[10];
    const float* db1   = (const float*)d_in[11];
    const float* dW2   = (const float*)d_in[12];
    const float* db2   = (const float*)d_in[13];
    const float* dW3   = (const float*)d_in[14];
    const float* db3   = (const float*)d_in[15];
    const float* decW1 = (const float*)d_in[16];
    const float* decb1 = (const float*)d_in[17];
    const float* decW2 = (const float*)d_in[18];
    const float* decb2 = (const float*)d_in[19];

    float* out   = (float*)d_out;
    float* recon = out;
    float* omean = out + OFF_MEAN;
    float* olv   = out + OFF_LV;
    float* traj  = out + OFF_TRAJ;
    float* z0    = (float*)d_ws;

    k_gru<<<dim3(256), dim3(512), 0, stream>>>(obs, eps, Wih, Whh, bih, bhh,
                                               meanW, meanB, lvW, lvB, omean, olv, z0);
    k_ode<<<dim3(512), dim3(256), 0, stream>>>(dW1, db1, dW2, db2, dW3, db3, z0, traj);
    k_dec<<<dim3(6400), dim3(256), 0, stream>>>(traj, decW1, decb1, decW2, decb2, recon);
}

// Round 7
// 215.034 us; speedup vs baseline: 11.6056x; 1.0604x over previous
//
#include <hip/hip_runtime.h>
#include <stddef.h>

// Output layout (fp32):
//   recon    [200,4096,64] @ 0
//   z0_mean  [4096,3]      @ 52428800
//   z0_logvar[4096,3]      @ 52441088
//   traj     [200,4096,3]  @ 52453376
#define OFF_MEAN 52428800
#define OFF_LV   52441088
#define OFF_TRAJ 52453376

typedef _Float16 f16x8 __attribute__((ext_vector_type(8)));
typedef _Float16 f16x4 __attribute__((ext_vector_type(4)));
typedef float    f32x4 __attribute__((ext_vector_type(4)));

#define MFMA16(a, b, c) __builtin_amdgcn_mfma_f32_16x16x32_f16((a), (b), (c), 0, 0, 0)

// fast transcendentals: v_exp_f32 + v_rcp_f32 (error ~1e-6, far below budget)
__device__ __forceinline__ float sigm_(float x) {
    float e = __builtin_amdgcn_exp2f(x * -1.442695041f);
    return __builtin_amdgcn_rcpf(1.f + e);
}
__device__ __forceinline__ float tanh_(float x) {
    float e = __builtin_amdgcn_exp2f(x * 2.885390082f);
    return 1.f - 2.f * __builtin_amdgcn_rcpf(e + 1.f);
}
__device__ __forceinline__ float dot4_(float4 a, float4 b) {
    return a.x * b.x + a.y * b.y + a.z * b.z + a.w * b.w;
}

// ---------------------------------------------------------------- GRU (MFMA, gate-aligned, dbuf, prefetch)
// 256 blocks x 512 threads (8 waves); 16 batch rows/block; 50 steps.
// Wave w owns gate tiles {w, 8+w, 16+w}: lane (lrow,lkb) owns unit u=w*16+lrow,
// batch rows lkb*4..+3 -> r/z/n accumulators and h_prev all thread-local.
// h and x live in DOUBLE-BUFFERED swizzled LDS: iter t reads buf[t&1], writes
// buf[(t+1)&1] -> ONE barrier per step. obs(t+1) prefetched into registers at
// iter start; converted + staged after the MFMA/gate phase (latency hidden).
__global__ __launch_bounds__(512, 2) void k_gru(
    const float* __restrict__ obs, const float* __restrict__ eps,
    const float* __restrict__ Wih, const float* __restrict__ Whh,
    const float* __restrict__ bih, const float* __restrict__ bhh,
    const float* __restrict__ meanW, const float* __restrict__ meanB,
    const float* __restrict__ lvW,  const float* __restrict__ lvB,
    float* __restrict__ o_mean, float* __restrict__ o_lv, float* __restrict__ z0)
{
    __shared__ alignas(16) unsigned short hhi_s[2][2048], hlo_s[2][2048]; // [16][128] f16 swz
    __shared__ alignas(16) unsigned short xhi_s[2][1024], xlo_s[2][1024]; // [16][64]  f16 swz
    __shared__ alignas(16) float hm_s[16 * 132];
    __shared__ float mb_s[96];

    const int tid  = threadIdx.x;
    const int b0   = blockIdx.x * 16;
    const int lane = tid & 63, wv = tid >> 6;
    const int lrow = lane & 15, lkb = lane >> 4;
    const int swA  = (lrow & 7) << 4;
    const int u    = wv * 16 + lrow;          // unit owned by this lane

    // biases (per-lane scalars)
    const float bR  = bih[u]       + bhh[u];
    const float bZ  = bih[128 + u] + bhh[128 + u];
    const float bNi = bih[256 + u];
    const float bNh = bhh[256 + u];

    // Wih B-fragments (f16 single)
    f16x8 wihf[3][2];
    #pragma unroll
    for (int g = 0; g < 3; ++g) {
        int col = g * 128 + u;
        #pragma unroll
        for (int ks = 0; ks < 2; ++ks) {
            const float* wp = Wih + col * 64 + ks * 32 + lkb * 8;
            float4 a = *(const float4*)wp, b = *(const float4*)(wp + 4);
            float tmp[8] = {a.x, a.y, a.z, a.w, b.x, b.y, b.z, b.w};
            f16x8 hv;
            #pragma unroll
            for (int j = 0; j < 8; ++j) hv[j] = (_Float16)tmp[j];
            wihf[g][ks] = hv;
        }
    }
    // Whh B-fragments (f16 hi+lo)
    f16x8 whhh[3][4], whhl[3][4];
    #pragma unroll
    for (int g = 0; g < 3; ++g) {
        int col = g * 128 + u;
        #pragma unroll
        for (int ks = 0; ks < 4; ++ks) {
            const float* wp = Whh + col * 128 + ks * 32 + lkb * 8;
            float4 a = *(const float4*)wp, b = *(const float4*)(wp + 4);
            float tmp[8] = {a.x, a.y, a.z, a.w, b.x, b.y, b.z, b.w};
            f16x8 hv, lv;
            #pragma unroll
            for (int j = 0; j < 8; ++j) {
                hv[j] = (_Float16)tmp[j];
                lv[j] = (_Float16)(tmp[j] - (float)hv[j]);
            }
            whhh[g][ks] = hv;
            whhl[g][ks] = lv;
        }
    }

    // prologue: zero hbuf[0]; stage x(0) into xbuf[0]
    for (int i = tid; i < 2048; i += 512) { hhi_s[0][i] = 0; hlo_s[0][i] = 0; }
    const int srow = tid >> 4, skq = (tid & 15) * 4;       // staging coords (tid<256)
    const int sxb  = srow * 128 + ((skq * 2) ^ ((srow & 7) << 4));
    float4 xn;
    if (tid < 256)
        xn = *(const float4*)(obs + ((size_t)0 * 4096 + b0 + srow) * 64 + skq);
    if (tid < 256) {
        float tmp[4] = {xn.x, xn.y, xn.z, xn.w};
        f16x4 vh, vl;
        #pragma unroll
        for (int j = 0; j < 4; ++j) {
            vh[j] = (_Float16)tmp[j];
            vl[j] = (_Float16)(tmp[j] - (float)vh[j]);
        }
        *(f16x4*)((char*)xhi_s[0] + sxb) = vh;
        *(f16x4*)((char*)xlo_s[0] + sxb) = vl;
    }
    f32x4 hold = {0.f, 0.f, 0.f, 0.f};        // h_prev for (rows lkb*4..+3, unit u)
    __syncthreads();

    for (int t = 0; t < 50; ++t) {
        const int cur = t & 1, nxt = cur ^ 1;
        char* xhi_c = (char*)xhi_s[cur]; char* xlo_c = (char*)xlo_s[cur];
        char* hhi_c = (char*)hhi_s[cur]; char* hlo_c = (char*)hlo_s[cur];

        // prefetch x(t+1) into registers (latency hidden under MFMA phase)
        if (tid < 256) {
            int tt = (t < 49) ? t + 1 : t;
            xn = *(const float4*)(obs + ((size_t)tt * 4096 + b0 + srow) * 64 + skq);
        }

        // A-fragments
        f16x8 xh[2], xl[2], hh[4], hl[4];
        #pragma unroll
        for (int ks = 0; ks < 2; ++ks) {
            int off = lrow * 128 + ((ks * 64 + lkb * 16) ^ swA);
            xh[ks] = *(const f16x8*)(xhi_c + off);
            xl[ks] = *(const f16x8*)(xlo_c + off);
        }
        #pragma unroll
        for (int ks = 0; ks < 4; ++ks) {
            int off = lrow * 256 + ((ks * 64 + lkb * 16) ^ swA);
            hh[ks] = *(const f16x8*)(hhi_c + off);
            hl[ks] = *(const f16x8*)(hlo_c + off);
        }

        f32x4 z4 = {0.f, 0.f, 0.f, 0.f};
        f32x4 aR = z4, aZ = z4, aNi = z4, aNh = z4;
        #pragma unroll
        for (int ks = 0; ks < 2; ++ks) {
            aR  = MFMA16(xh[ks], wihf[0][ks], aR);
            aR  = MFMA16(xl[ks], wihf[0][ks], aR);
            aZ  = MFMA16(xh[ks], wihf[1][ks], aZ);
            aZ  = MFMA16(xl[ks], wihf[1][ks], aZ);
            aNi = MFMA16(xh[ks], wihf[2][ks], aNi);
            aNi = MFMA16(xl[ks], wihf[2][ks], aNi);
        }
        #pragma unroll
        for (int ks = 0; ks < 4; ++ks) {
            aR  = MFMA16(hh[ks], whhh[0][ks], aR);
            aR  = MFMA16(hl[ks], whhh[0][ks], aR);
            aR  = MFMA16(hh[ks], whhl[0][ks], aR);
            aZ  = MFMA16(hh[ks], whhh[1][ks], aZ);
            aZ  = MFMA16(hl[ks], whhh[1][ks], aZ);
            aZ  = MFMA16(hh[ks], whhl[1][ks], aZ);
            aNh = MFMA16(hh[ks], whhh[2][ks], aNh);
            aNh = MFMA16(hl[ks], whhh[2][ks], aNh);
            aNh = MFMA16(hh[ks], whhl[2][ks], aNh);
        }

        // gates in registers; write h(t) hi/lo into the NEXT h buffer
        char* hhin_c = (char*)hhi_s[nxt]; char* hlon_c = (char*)hlo_s[nxt];
        #pragma unroll
        for (int i = 0; i < 4; ++i) {
            float r  = sigm_(aR[i] + bR);
            float zg = sigm_(aZ[i] + bZ);
            float n  = tanh_(aNi[i] + bNi + r * (aNh[i] + bNh));
            float hv = (1.f - zg) * n + zg * hold[i];
            hold[i] = hv;
            _Float16 nh = (_Float16)hv;
            _Float16 nl = (_Float16)(hv - (float)nh);
            int ri = lkb * 4 + i;
            int hb = ri * 256 + ((u * 2) ^ ((ri & 7) << 4));
            *(_Float16*)(hhin_c + hb) = nh;
            *(_Float16*)(hlon_c + hb) = nl;
        }

        // stage prefetched x(t+1) into the NEXT x buffer
        if (tid < 256 && t < 49) {
            float tmp[4] = {xn.x, xn.y, xn.z, xn.w};
            f16x4 vh, vl;
            #pragma unroll
            for (int j = 0; j < 4; ++j) {
                vh[j] = (_Float16)tmp[j];
                vl[j] = (_Float16)(tmp[j] - (float)vh[j]);
            }
            *(f16x4*)((char*)xhi_s[nxt] + sxb) = vh;
            *(f16x4*)((char*)xlo_s[nxt] + sxb) = vl;
        }
        __syncthreads();
    }

    // dump h_last to LDS for the heads
    #pragma unroll
    for (int i = 0; i < 4; ++i)
        hm_s[(lkb * 4 + i) * 132 + u] = hold[i];
    __syncthreads();

    if (tid < 96) {
        int rr = tid / 6, c = tid - rr * 6, j = (c < 3) ? c : c - 3;
        const float* W = (c < 3) ? meanW : lvW;
        const float* B = (c < 3) ? meanB : lvB;
        float acc = B[j];
        const float4* W4 = (const float4*)(W + j * 128);
        const float4* h4 = (const float4*)(hm_s + rr * 132);
        #pragma unroll 4
        for (int kc = 0; kc < 32; ++kc) acc += dot4_(W4[kc], h4[kc]);
        mb_s[rr * 6 + c] = acc;
    }
    __syncthreads();
    if (tid < 48) {
        int rr = tid / 3, j = tid - rr * 3;
        int gb = b0 + rr;
        float m  = mb_s[rr * 6 + j];
        float lv = mb_s[rr * 6 + j + 3];
        o_mean[gb * 3 + j] = m;
        o_lv[gb * 3 + j]   = lv;
        z0[gb * 3 + j]     = m + eps[gb * 3 + j] * __expf(0.5f * lv);
    }
}

// ---------------------------------------------------------------- ODE kernel
// (unchanged from round 5)
__global__ __launch_bounds__(256, 2) void k_ode(
    const float* __restrict__ dW1, const float* __restrict__ db1,
    const float* __restrict__ dW2, const float* __restrict__ db2,
    const float* __restrict__ dW3, const float* __restrict__ db3,
    const float* __restrict__ z0, float* __restrict__ traj)
{
    __shared__ alignas(16) unsigned short h1h_s[2048];
    __shared__ alignas(16) float h2f[8 * 104];
    __shared__ alignas(16) float W3s[312];
    __shared__ float b2s[100], b3s[3];
    __shared__ float fparts[24];

    const int tid  = threadIdx.x;
    const int b0   = blockIdx.x * 8;
    const int lane = tid & 63, wv = tid >> 6;
    const int r    = tid >> 5;
    char* h1h_c = (char*)h1h_s;

    for (int i = tid; i < 512; i += 256)
        ((unsigned int*)(h1h_c + 2048))[i] = 0u;
    if (tid < 32) h2f[(tid >> 2) * 104 + 100 + (tid & 3)] = 0.f;
    for (int i = tid; i < 312; i += 256) {
        int j = i / 104, k = i - j * 104;
        W3s[i] = (k < 100) ? dW3[j * 100 + k] : 0.f;
    }
    if (tid < 100) b2s[tid] = db2[tid];
    if (tid < 3)   b3s[tid] = db3[tid];

    float w1r[12], b1r[4];
    {
        int k0 = (tid & 31) * 4;
        #pragma unroll
        for (int i = 0; i < 4; ++i) {
            int k = k0 + i;
            if (k < 100) {
                w1r[3 * i + 0] = dW1[k * 3 + 0];
                w1r[3 * i + 1] = dW1[k * 3 + 1];
                w1r[3 * i + 2] = dW1[k * 3 + 2];
                b1r[i] = db1[k];
            } else {
                w1r[3 * i + 0] = 0.f; w1r[3 * i + 1] = 0.f; w1r[3 * i + 2] = 0.f;
                b1r[i] = 0.f;
            }
        }
    }
    f16x8 w2h[2][4], w2l[2][4];
    {
        const int lrow = lane & 15, lkb = lane >> 4;
        #pragma unroll
        for (int tile = 0; tile < 2; ++tile) {
            int col = (wv * 2 + tile) * 16 + lrow;
            #pragma unroll
            for (int ks = 0; ks < 4; ++ks) {
                f16x8 hv, lv;
                #pragma unroll
                for (int j = 0; j < 8; ++j) {
                    int k = ks * 32 + lkb * 8 + j;
                    float v = (col < 100 && k < 100) ? dW2[col * 100 + k] : 0.f;
                    _Float16 hf = (_Float16)v;
                    hv[j] = hf;
                    lv[j] = (_Float16)(v - (float)hf);
                }
                w2h[tile][ks] = hv;
                w2l[tile][ks] = lv;
            }
        }
    }

    float yv0 = z0[(b0 + r) * 3 + 0];
    float yv1 = z0[(b0 + r) * 3 + 1];
    float yv2 = z0[(b0 + r) * 3 + 2];
    float ka0, ka1, ka2, k10, k11, k12, yn0, yn1, yn2;

    if (tid < 24) {
        int rr = tid / 3, j = tid - rr * 3;
        traj[((size_t)(b0 + rr)) * 3 + j] = z0[(b0 + rr) * 3 + j];
    }
    __syncthreads();

    const int lrow = lane & 15, lkb = lane >> 4;
    const int swA  = (lrow & 7) << 4;

#define FEVAL(yt0_, yt1_, yt2_)                                                  \
    do {                                                                          \
        {                                                                         \
            int q = tid & 31, k0 = q * 4;                                         \
            f16x4 hh_;                                                            \
            _Pragma("unroll")                                                     \
            for (int i = 0; i < 4; ++i) {                                         \
                float acc = b1r[i] + w1r[3 * i] * (yt0_)                          \
                          + w1r[3 * i + 1] * (yt1_) + w1r[3 * i + 2] * (yt2_);    \
                hh_[i] = (_Float16)tanh_(acc);                                    \
            }                                                                     \
            int off = r * 256 + ((k0 * 2) ^ (r << 4));                            \
            *(f16x4*)(h1h_c + off) = hh_;                                         \
        }                                                                         \
        __syncthreads();                                                          \
        {                                                                         \
            f16x8 ah[4];                                                          \
            _Pragma("unroll")                                                     \
            for (int ks = 0; ks < 4; ++ks) {                                      \
                int off = lrow * 256 + ((ks * 64 + lkb * 16) ^ swA);              \
                ah[ks] = *(const f16x8*)(h1h_c + off);                            \
            }                                                                     \
            f32x4 acc0 = {0.f, 0.f, 0.f, 0.f}, acc1 = {0.f, 0.f, 0.f, 0.f};       \
            _Pragma("unroll")                                                     \
            for (int ks = 0; ks < 4; ++ks) {                                      \
                acc0 = MFMA16(ah[ks], w2h[0][ks], acc0);                          \
                acc0 = MFMA16(ah[ks], w2l[0][ks], acc0);                          \
                acc1 = MFMA16(ah[ks], w2h[1][ks], acc1);                          \
                acc1 = MFMA16(ah[ks], w2l[1][ks], acc1);                          \
            }                                                                     \
            if (lkb < 2) {                                                        \
                int r0 = lkb * 4;                                                 \
                _Pragma("unroll")                                                 \
                for (int tile = 0; tile < 2; ++tile) {                            \
                    int col = (wv * 2 + tile) * 16 + lrow;                        \
                    f32x4 a = tile ? acc1 : acc0;                                 \
                    if (col < 100) {                                              \
                        float bb = b2s[col];                                      \
                        _Pragma("unroll")                                         \
                        for (int i = 0; i < 4; ++i)                               \
                            h2f[(r0 + i) * 104 + col] = tanh_(a[i] + bb);         \
                    }                                                             \
                }                                                                 \
            }                                                                     \
        }                                                                         \
        __syncthreads();                                                          \
        {                                                                         \
            if (tid < 96) {                                                       \
                int rr = tid / 12, rem = tid - rr * 12, j = rem >> 2, qc = rem & 3;\
                const float4* Wj = (const float4*)(W3s + j * 104);                \
                const float4* Hr = (const float4*)(h2f + rr * 104);               \
                float acc = 0.f;                                                  \
                _Pragma("unroll")                                                 \
                for (int kc = 0; kc < 7; ++kc) {                                  \
                    int k = qc + kc * 4;                                          \
                    if (k < 26) acc += dot4_(Wj[k], Hr[k]);                       \
                }                                                                 \
                acc += __shfl_xor(acc, 1);                                        \
                acc += __shfl_xor(acc, 2);                                        \
                if (qc == 0) fparts[rr * 3 + j] = acc + b3s[j];                   \
            }                                                                     \
        }                                                                         \
        __syncthreads();                                                          \
    } while (0)

    FEVAL(yv0, yv1, yv2);

    #pragma unroll 1
    for (int s = 0; s < 13; ++s) {
        const int   nInt = (s < 12) ? 16 : 7;
        const float hh   = 0.01f * (float)nInt;
        const int   t0   = s * 16;
        const float invN = (s < 12) ? 0.0625f : (1.f / 7.f);

        float f0_ = fparts[r * 3 + 0], f1_ = fparts[r * 3 + 1], f2_ = fparts[r * 3 + 2];
        k10 = f0_; k11 = f1_; k12 = f2_;
        ka0 = f0_; ka1 = f1_; ka2 = f2_;
        float yt0 = yv0 + 0.5f * hh * f0_, yt1 = yv1 + 0.5f * hh * f1_, yt2 = yv2 + 0.5f * hh * f2_;
        FEVAL(yt0, yt1, yt2);
        f0_ = fparts[r * 3 + 0]; f1_ = fparts[r * 3 + 1]; f2_ = fparts[r * 3 + 2];
        ka0 += 2.f * f0_; ka1 += 2.f * f1_; ka2 += 2.f * f2_;
        yt0 = yv0 + 0.5f * hh * f0_; yt1 = yv1 + 0.5f * hh * f1_; yt2 = yv2 + 0.5f * hh * f2_;
        FEVAL(yt0, yt1, yt2);
        f0_ = fparts[r * 3 + 0]; f1_ = fparts[r * 3 + 1]; f2_ = fparts[r * 3 + 2];
        ka0 += 2.f * f0_; ka1 += 2.f * f1_; ka2 += 2.f * f2_;
        yt0 = yv0 + hh * f0_; yt1 = yv1 + hh * f1_; yt2 = yv2 + hh * f2_;
        FEVAL(yt0, yt1, yt2);
        f0_ = fparts[r * 3 + 0]; f1_ = fparts[r * 3 + 1]; f2_ = fparts[r * 3 + 2];
        ka0 += f0_; ka1 += f1_; ka2 += f2_;
        const float h6 = hh * (1.f / 6.f);
        yn0 = yv0 + h6 * ka0; yn1 = yv1 + h6 * ka1; yn2 = yv2 + h6 * ka2;
        FEVAL(yn0, yn1, yn2);
        float fn0 = fparts[r * 3 + 0], fn1 = fparts[r * 3 + 1], fn2 = fparts[r * 3 + 2];

        {
            int tot = 3 * nInt;
            for (int ii = (tid & 31); ii < tot; ii += 32) {
                int q = ii / 3, j = ii - q * 3;
                float ysj = (j == 0) ? yv0 : (j == 1) ? yv1 : yv2;
                float f0j = (j == 0) ? k10 : (j == 1) ? k11 : k12;
                float ynj = (j == 0) ? yn0 : (j == 1) ? yn1 : yn2;
                float fnj = (j == 0) ? fn0 : (j == 1) ? fn1 : fn2;
                float th  = (float)(q + 1) * invN;
                float th2 = th * th, th3 = th2 * th;
                float ca = 2.f * th3 - 3.f * th2 + 1.f;
                float cb = th3 - 2.f * th2 + th;
                float cc = 3.f * th2 - 2.f * th3;
                float cd = th3 - th2;
                float v = ca * ysj + cb * hh * f0j + cc * ynj + cd * hh * fnj;
                traj[((size_t)(t0 + 1 + q) * 4096 + b0 + r) * 3 + j] = v;
            }
        }
        yv0 = yn0; yv1 = yn1; yv2 = yn2;
    }
#undef FEVAL
}

// ---------------------------------------------------------------- decoder (MFMA)
// (unchanged from round 4)
__global__ __launch_bounds__(256, 2) void k_dec(
    const float* __restrict__ traj, const float* __restrict__ W1, const float* __restrict__ b1,
    const float* __restrict__ W2, const float* __restrict__ b2, float* __restrict__ recon)
{
    __shared__ alignas(16) unsigned short hdh_s[8192], hdl_s[8192];
    __shared__ alignas(16) float zs[384];
    __shared__ float w1s[192], b1s_[64];

    const int tid  = threadIdx.x;
    const size_t p0 = (size_t)blockIdx.x * 128;
    const int lane = tid & 63, wv = tid >> 6;
    const int lrow = lane & 15, lkb = lane >> 4;

    char* hdh_c = (char*)hdh_s;
    char* hdl_c = (char*)hdl_s;

    if (tid < 96) *(float4*)&zs[tid * 4] = ((const float4*)(traj + p0 * 3))[tid];
    if (tid < 192) w1s[tid] = W1[tid];
    if (tid < 64)  b1s_[tid] = b1[tid];

    f16x8 bh[2], bl[2];
    {
        int col = wv * 16 + lrow;
        #pragma unroll
        for (int ks = 0; ks < 2; ++ks) {
            const float* wp = W2 + col * 64 + ks * 32 + lkb * 8;
            float4 a = *(const float4*)wp, b = *(const float4*)(wp + 4);
            float tmp[8] = {a.x, a.y, a.z, a.w, b.x, b.y, b.z, b.w};
            f16x8 hv, lv;
            #pragma unroll
            for (int j = 0; j < 8; ++j) {
                hv[j] = (_Float16)tmp[j];
                lv[j] = (_Float16)(tmp[j] - (float)hv[j]);
            }
            bh[ks] = hv;
            bl[ks] = lv;
        }
    }
    const float bo = b2[wv * 16 + lrow];
    __syncthreads();

    {
        const int p  = tid >> 1;
        const int u0 = (tid & 1) * 32;
        const float z0v = zs[p * 3 + 0], z1v = zs[p * 3 + 1], z2v = zs[p * 3 + 2];
        const int sw = (p & 7) << 4;
        #pragma unroll
        for (int c = 0; c < 8; ++c) {
            f16x4 hh_, hl_;
            #pragma unroll
            for (int i = 0; i < 4; ++i) {
                int u = u0 + c * 4 + i;
                float acc = b1s_[u] + w1s[u * 3 + 0] * z0v
                                    + w1s[u * 3 + 1] * z1v
                                    + w1s[u * 3 + 2] * z2v;
                float h = fmaxf(acc, 0.f);
                _Float16 hf = (_Float16)h;
                hh_[i] = hf;
                hl_[i] = (_Float16)(h - (float)hf);
            }
            int off = p * 128 + (((u0 + c * 4) * 2) ^ sw);
            *(f16x4*)(hdh_c + off) = hh_;
            *(f16x4*)(hdl_c + off) = hl_;
        }
    }
    __syncthreads();

    const int swA = (lrow & 7) << 4;
    #pragma unroll
    for (int rt = 0; rt < 8; ++rt) {
        f16x8 ahh[2], all_[2];
        #pragma unroll
        for (int ks = 0; ks < 2; ++ks) {
            int off = (rt * 16 + lrow) * 128 + ((ks * 64 + lkb * 16) ^ swA);
            ahh[ks]  = *(const f16x8*)(hdh_c + off);
            all_[ks] = *(const f16x8*)(hdl_c + off);
        }
        f32x4 acc = {0.f, 0.f, 0.f, 0.f};
        #pragma unroll
        for (int ks = 0; ks < 2; ++ks) {
            acc = MFMA16(ahh[ks],  bh[ks], acc);
            acc = MFMA16(all_[ks], bh[ks], acc);
            acc = MFMA16(ahh[ks],  bl[ks], acc);
        }
        const size_t rowg = p0 + rt * 16 + lkb * 4;
        #pragma unroll
        for (int i = 0; i < 4; ++i)
            recon[(rowg + i) * 64 + wv * 16 + lrow] = acc[i] + bo;
    }
}

extern "C" void kernel_launch(void* const* d_in, const int* in_sizes, int n_in,
                              void* d_out, int out_size, void* d_ws, size_t ws_size,
                              hipStream_t stream)
{
    const float* obs   = (const float*)d_in[0];
    const float* eps   = (const float*)d_in[1];
    const float* Wih   = (const float*)d_in[2];
    const float* Whh   = (const float*)d_in[3];
    const float* bih   = (const float*)d_in[4];
    const float* bhh   = (const float*)d_in[5];
    const float* meanW = (const float*)d_in[6];
    const float* meanB = (const float*)d_in[7];
    const float* lvW   = (const float*)d_in[8];
    const float* lvB   = (const float*)d_in[9];
    const float* dW1   = (const float*)d_in[10];
    const float* db1   = (const float*)d_in[11];
    const float* dW2   = (const float*)d_in[12];
    const float* db2   = (const float*)d_in[13];
    const float* dW3   = (const float*)d_in[14];
    const float* db3   = (const float*)d_in[15];
    const float* decW1 = (const float*)d_in[16];
    const float* decb1 = (const float*)d_in[17];
    const float* decW2 = (const float*)d_in[18];
    const float* decb2 = (const float*)d_in[19];

    float* out   = (float*)d_out;
    float* recon = out;
    float* omean = out + OFF_MEAN;
    float* olv   = out + OFF_LV;
    float* traj  = out + OFF_TRAJ;
    float* z0    = (float*)d_ws;

    k_gru<<<dim3(256), dim3(512), 0, stream>>>(obs, eps, Wih, Whh, bih, bhh,
                                               meanW, meanB, lvW, lvB, omean, olv, z0);
    k_ode<<<dim3(512), dim3(256), 0, stream>>>(dW1, db1, dW2, db2, dW3, db3, z0, traj);
    k_dec<<<dim3(6400), dim3(256), 0, stream>>>(traj, decW1, decb1, decW2, decb2, recon);
}

// Round 8
// 202.671 us; speedup vs baseline: 12.3136x; 1.0610x over previous
//
#include <hip/hip_runtime.h>
#include <stddef.h>

// Output layout (fp32):
//   recon    [200,4096,64] @ 0
//   z0_mean  [4096,3]      @ 52428800
//   z0_logvar[4096,3]      @ 52441088
//   traj     [200,4096,3]  @ 52453376
#define OFF_MEAN 52428800
#define OFF_LV   52441088
#define OFF_TRAJ 52453376

typedef _Float16 f16x8 __attribute__((ext_vector_type(8)));
typedef _Float16 f16x4 __attribute__((ext_vector_type(4)));
typedef float    f32x4 __attribute__((ext_vector_type(4)));

#define MFMA16(a, b, c) __builtin_amdgcn_mfma_f32_16x16x32_f16((a), (b), (c), 0, 0, 0)

// fast transcendentals: v_exp_f32 + v_rcp_f32 (error ~1e-6, far below budget)
__device__ __forceinline__ float sigm_(float x) {
    float e = __builtin_amdgcn_exp2f(x * -1.442695041f);
    return __builtin_amdgcn_rcpf(1.f + e);
}
__device__ __forceinline__ float tanh_(float x) {
    float e = __builtin_amdgcn_exp2f(x * 2.885390082f);
    return 1.f - 2.f * __builtin_amdgcn_rcpf(e + 1.f);
}
__device__ __forceinline__ float dot4_(float4 a, float4 b) {
    return a.x * b.x + a.y * b.y + a.z * b.z + a.w * b.w;
}

// ---------------------------------------------------------------- GRU (MFMA, gate-aligned, dbuf, prefetch)
// 256 blocks x 512 threads (8 waves); 16 batch rows/block; 50 steps.
// Wave w owns gate tiles {w, 8+w, 16+w}: lane (lrow,lkb) owns unit u=w*16+lrow,
// batch rows lkb*4..+3 -> r/z/n accumulators and h_prev all thread-local.
// Compensation: x hi/lo vs Wih-f16 (2-term); h hi/lo vs Whh-f16 (2-term, W-lo
// term dropped: ~2^-12 relative, below the bf16 comparison floor).
// h buffer swizzle uses the FULL 4-bit row index (256B row = 16 slots of 16B,
// bijective per 16-lane group on both write and read sides).
__global__ __launch_bounds__(512, 2) void k_gru(
    const float* __restrict__ obs, const float* __restrict__ eps,
    const float* __restrict__ Wih, const float* __restrict__ Whh,
    const float* __restrict__ bih, const float* __restrict__ bhh,
    const float* __restrict__ meanW, const float* __restrict__ meanB,
    const float* __restrict__ lvW,  const float* __restrict__ lvB,
    float* __restrict__ o_mean, float* __restrict__ o_lv, float* __restrict__ z0)
{
    __shared__ alignas(16) unsigned short hhi_s[2][2048], hlo_s[2][2048]; // [16][128] f16 swz(4b)
    __shared__ alignas(16) unsigned short xhi_s[2][1024], xlo_s[2][1024]; // [16][64]  f16 swz(3b)
    __shared__ alignas(16) float hm_s[16 * 132];
    __shared__ float mb_s[96];

    const int tid  = threadIdx.x;
    const int b0   = blockIdx.x * 16;
    const int lane = tid & 63, wv = tid >> 6;
    const int lrow = lane & 15, lkb = lane >> 4;
    const int swX  = (lrow & 7) << 4;          // x buffer: 128B rows, 3-bit swizzle
    const int swH  = lrow << 4;                // h buffer: 256B rows, 4-bit swizzle
    const int u    = wv * 16 + lrow;           // unit owned by this lane

    // biases (per-lane scalars)
    const float bR  = bih[u]       + bhh[u];
    const float bZ  = bih[128 + u] + bhh[128 + u];
    const float bNi = bih[256 + u];
    const float bNh = bhh[256 + u];

    // Wih B-fragments (f16 single)
    f16x8 wihf[3][2];
    #pragma unroll
    for (int g = 0; g < 3; ++g) {
        int col = g * 128 + u;
        #pragma unroll
        for (int ks = 0; ks < 2; ++ks) {
            const float* wp = Wih + col * 64 + ks * 32 + lkb * 8;
            float4 a = *(const float4*)wp, b = *(const float4*)(wp + 4);
            float tmp[8] = {a.x, a.y, a.z, a.w, b.x, b.y, b.z, b.w};
            f16x8 hv;
            #pragma unroll
            for (int j = 0; j < 8; ++j) hv[j] = (_Float16)tmp[j];
            wihf[g][ks] = hv;
        }
    }
    // Whh B-fragments (f16 hi only; W-lo compensation term dropped)
    f16x8 whhh[3][4];
    #pragma unroll
    for (int g = 0; g < 3; ++g) {
        int col = g * 128 + u;
        #pragma unroll
        for (int ks = 0; ks < 4; ++ks) {
            const float* wp = Whh + col * 128 + ks * 32 + lkb * 8;
            float4 a = *(const float4*)wp, b = *(const float4*)(wp + 4);
            float tmp[8] = {a.x, a.y, a.z, a.w, b.x, b.y, b.z, b.w};
            f16x8 hv;
            #pragma unroll
            for (int j = 0; j < 8; ++j) hv[j] = (_Float16)tmp[j];
            whhh[g][ks] = hv;
        }
    }

    // prologue: zero hbuf[0]; stage x(0) into xbuf[0]
    for (int i = tid; i < 2048; i += 512) { hhi_s[0][i] = 0; hlo_s[0][i] = 0; }
    const int srow = tid >> 4, skq = (tid & 15) * 4;       // staging coords (tid<256)
    const int sxb  = srow * 128 + ((skq * 2) ^ ((srow & 7) << 4));
    float4 xn;
    if (tid < 256)
        xn = *(const float4*)(obs + ((size_t)0 * 4096 + b0 + srow) * 64 + skq);
    if (tid < 256) {
        float tmp[4] = {xn.x, xn.y, xn.z, xn.w};
        f16x4 vh, vl;
        #pragma unroll
        for (int j = 0; j < 4; ++j) {
            vh[j] = (_Float16)tmp[j];
            vl[j] = (_Float16)(tmp[j] - (float)vh[j]);
        }
        *(f16x4*)((char*)xhi_s[0] + sxb) = vh;
        *(f16x4*)((char*)xlo_s[0] + sxb) = vl;
    }
    f32x4 hold = {0.f, 0.f, 0.f, 0.f};        // h_prev for (rows lkb*4..+3, unit u)
    __syncthreads();

    for (int t = 0; t < 50; ++t) {
        const int cur = t & 1, nxt = cur ^ 1;
        char* xhi_c = (char*)xhi_s[cur]; char* xlo_c = (char*)xlo_s[cur];
        char* hhi_c = (char*)hhi_s[cur]; char* hlo_c = (char*)hlo_s[cur];

        // prefetch x(t+1) into registers (latency hidden under MFMA phase)
        if (tid < 256) {
            int tt = (t < 49) ? t + 1 : t;
            xn = *(const float4*)(obs + ((size_t)tt * 4096 + b0 + srow) * 64 + skq);
        }

        // A-fragments
        f16x8 xh[2], xl[2], hh[4], hl[4];
        #pragma unroll
        for (int ks = 0; ks < 2; ++ks) {
            int off = lrow * 128 + ((ks * 64 + lkb * 16) ^ swX);
            xh[ks] = *(const f16x8*)(xhi_c + off);
            xl[ks] = *(const f16x8*)(xlo_c + off);
        }
        #pragma unroll
        for (int ks = 0; ks < 4; ++ks) {
            int off = lrow * 256 + ((ks * 64 + lkb * 16) ^ swH);
            hh[ks] = *(const f16x8*)(hhi_c + off);
            hl[ks] = *(const f16x8*)(hlo_c + off);
        }

        f32x4 z4 = {0.f, 0.f, 0.f, 0.f};
        f32x4 aR = z4, aZ = z4, aNi = z4, aNh = z4;
        #pragma unroll
        for (int ks = 0; ks < 2; ++ks) {
            aR  = MFMA16(xh[ks], wihf[0][ks], aR);
            aR  = MFMA16(xl[ks], wihf[0][ks], aR);
            aZ  = MFMA16(xh[ks], wihf[1][ks], aZ);
            aZ  = MFMA16(xl[ks], wihf[1][ks], aZ);
            aNi = MFMA16(xh[ks], wihf[2][ks], aNi);
            aNi = MFMA16(xl[ks], wihf[2][ks], aNi);
        }
        #pragma unroll
        for (int ks = 0; ks < 4; ++ks) {
            aR  = MFMA16(hh[ks], whhh[0][ks], aR);
            aR  = MFMA16(hl[ks], whhh[0][ks], aR);
            aZ  = MFMA16(hh[ks], whhh[1][ks], aZ);
            aZ  = MFMA16(hl[ks], whhh[1][ks], aZ);
            aNh = MFMA16(hh[ks], whhh[2][ks], aNh);
            aNh = MFMA16(hl[ks], whhh[2][ks], aNh);
        }

        // gates in registers; write h(t) hi/lo into the NEXT h buffer
        char* hhin_c = (char*)hhi_s[nxt]; char* hlon_c = (char*)hlo_s[nxt];
        #pragma unroll
        for (int i = 0; i < 4; ++i) {
            float r  = sigm_(aR[i] + bR);
            float zg = sigm_(aZ[i] + bZ);
            float n  = tanh_(aNi[i] + bNi + r * (aNh[i] + bNh));
            float hv = (1.f - zg) * n + zg * hold[i];
            hold[i] = hv;
            _Float16 nh = (_Float16)hv;
            _Float16 nl = (_Float16)(hv - (float)nh);
            int ri = lkb * 4 + i;
            int hb = ri * 256 + ((u * 2) ^ (ri << 4));
            *(_Float16*)(hhin_c + hb) = nh;
            *(_Float16*)(hlon_c + hb) = nl;
        }

        // stage prefetched x(t+1) into the NEXT x buffer
        if (tid < 256 && t < 49) {
            float tmp[4] = {xn.x, xn.y, xn.z, xn.w};
            f16x4 vh, vl;
            #pragma unroll
            for (int j = 0; j < 4; ++j) {
                vh[j] = (_Float16)tmp[j];
                vl[j] = (_Float16)(tmp[j] - (float)vh[j]);
            }
            *(f16x4*)((char*)xhi_s[nxt] + sxb) = vh;
            *(f16x4*)((char*)xlo_s[nxt] + sxb) = vl;
        }
        __syncthreads();
    }

    // dump h_last to LDS for the heads
    #pragma unroll
    for (int i = 0; i < 4; ++i)
        hm_s[(lkb * 4 + i) * 132 + u] = hold[i];
    __syncthreads();

    if (tid < 96) {
        int rr = tid / 6, c = tid - rr * 6, j = (c < 3) ? c : c - 3;
        const float* W = (c < 3) ? meanW : lvW;
        const float* B = (c < 3) ? meanB : lvB;
        float acc = B[j];
        const float4* W4 = (const float4*)(W + j * 128);
        const float4* h4 = (const float4*)(hm_s + rr * 132);
        #pragma unroll 4
        for (int kc = 0; kc < 32; ++kc) acc += dot4_(W4[kc], h4[kc]);
        mb_s[rr * 6 + c] = acc;
    }
    __syncthreads();
    if (tid < 48) {
        int rr = tid / 3, j = tid - rr * 3;
        int gb = b0 + rr;
        float m  = mb_s[rr * 6 + j];
        float lv = mb_s[rr * 6 + j + 3];
        o_mean[gb * 3 + j] = m;
        o_lv[gb * 3 + j]   = lv;
        z0[gb * 3 + j]     = m + eps[gb * 3 + j] * __expf(0.5f * lv);
    }
}

// ---------------------------------------------------------------- ODE kernel
// (unchanged from round 5)
__global__ __launch_bounds__(256, 2) void k_ode(
    const float* __restrict__ dW1, const float* __restrict__ db1,
    const float* __restrict__ dW2, const float* __restrict__ db2,
    const float* __restrict__ dW3, const float* __restrict__ db3,
    const float* __restrict__ z0, float* __restrict__ traj)
{
    __shared__ alignas(16) unsigned short h1h_s[2048];
    __shared__ alignas(16) float h2f[8 * 104];
    __shared__ alignas(16) float W3s[312];
    __shared__ float b2s[100], b3s[3];
    __shared__ float fparts[24];

    const int tid  = threadIdx.x;
    const int b0   = blockIdx.x * 8;
    const int lane = tid & 63, wv = tid >> 6;
    const int r    = tid >> 5;
    char* h1h_c = (char*)h1h_s;

    for (int i = tid; i < 512; i += 256)
        ((unsigned int*)(h1h_c + 2048))[i] = 0u;
    if (tid < 32) h2f[(tid >> 2) * 104 + 100 + (tid & 3)] = 0.f;
    for (int i = tid; i < 312; i += 256) {
        int j = i / 104, k = i - j * 104;
        W3s[i] = (k < 100) ? dW3[j * 100 + k] : 0.f;
    }
    if (tid < 100) b2s[tid] = db2[tid];
    if (tid < 3)   b3s[tid] = db3[tid];

    float w1r[12], b1r[4];
    {
        int k0 = (tid & 31) * 4;
        #pragma unroll
        for (int i = 0; i < 4; ++i) {
            int k = k0 + i;
            if (k < 100) {
                w1r[3 * i + 0] = dW1[k * 3 + 0];
                w1r[3 * i + 1] = dW1[k * 3 + 1];
                w1r[3 * i + 2] = dW1[k * 3 + 2];
                b1r[i] = db1[k];
            } else {
                w1r[3 * i + 0] = 0.f; w1r[3 * i + 1] = 0.f; w1r[3 * i + 2] = 0.f;
                b1r[i] = 0.f;
            }
        }
    }
    f16x8 w2h[2][4], w2l[2][4];
    {
        const int lrow = lane & 15, lkb = lane >> 4;
        #pragma unroll
        for (int tile = 0; tile < 2; ++tile) {
            int col = (wv * 2 + tile) * 16 + lrow;
            #pragma unroll
            for (int ks = 0; ks < 4; ++ks) {
                f16x8 hv, lv;
                #pragma unroll
                for (int j = 0; j < 8; ++j) {
                    int k = ks * 32 + lkb * 8 + j;
                    float v = (col < 100 && k < 100) ? dW2[col * 100 + k] : 0.f;
                    _Float16 hf = (_Float16)v;
                    hv[j] = hf;
                    lv[j] = (_Float16)(v - (float)hf);
                }
                w2h[tile][ks] = hv;
                w2l[tile][ks] = lv;
            }
        }
    }

    float yv0 = z0[(b0 + r) * 3 + 0];
    float yv1 = z0[(b0 + r) * 3 + 1];
    float yv2 = z0[(b0 + r) * 3 + 2];
    float ka0, ka1, ka2, k10, k11, k12, yn0, yn1, yn2;

    if (tid < 24) {
        int rr = tid / 3, j = tid - rr * 3;
        traj[((size_t)(b0 + rr)) * 3 + j] = z0[(b0 + rr) * 3 + j];
    }
    __syncthreads();

    const int lrow = lane & 15, lkb = lane >> 4;
    const int swA  = (lrow & 7) << 4;

#define FEVAL(yt0_, yt1_, yt2_)                                                  \
    do {                                                                          \
        {                                                                         \
            int q = tid & 31, k0 = q * 4;                                         \
            f16x4 hh_;                                                            \
            _Pragma("unroll")                                                     \
            for (int i = 0; i < 4; ++i) {                                         \
                float acc = b1r[i] + w1r[3 * i] * (yt0_)                          \
                          + w1r[3 * i + 1] * (yt1_) + w1r[3 * i + 2] * (yt2_);    \
                hh_[i] = (_Float16)tanh_(acc);                                    \
            }                                                                     \
            int off = r * 256 + ((k0 * 2) ^ (r << 4));                            \
            *(f16x4*)(h1h_c + off) = hh_;                                         \
        }                                                                         \
        __syncthreads();                                                          \
        {                                                                         \
            f16x8 ah[4];                                                          \
            _Pragma("unroll")                                                     \
            for (int ks = 0; ks < 4; ++ks) {                                      \
                int off = lrow * 256 + ((ks * 64 + lkb * 16) ^ swA);              \
                ah[ks] = *(const f16x8*)(h1h_c + off);                            \
            }                                                                     \
            f32x4 acc0 = {0.f, 0.f, 0.f, 0.f}, acc1 = {0.f, 0.f, 0.f, 0.f};       \
            _Pragma("unroll")                                                     \
            for (int ks = 0; ks < 4; ++ks) {                                      \
                acc0 = MFMA16(ah[ks], w2h[0][ks], acc0);                          \
                acc0 = MFMA16(ah[ks], w2l[0][ks], acc0);                          \
                acc1 = MFMA16(ah[ks], w2h[1][ks], acc1);                          \
                acc1 = MFMA16(ah[ks], w2l[1][ks], acc1);                          \
            }                                                                     \
            if (lkb < 2) {                                                        \
                int r0 = lkb * 4;                                                 \
                _Pragma("unroll")                                                 \
                for (int tile = 0; tile < 2; ++tile) {                            \
                    int col = (wv * 2 + tile) * 16 + lrow;                        \
                    f32x4 a = tile ? acc1 : acc0;                                 \
                    if (col < 100) {                                              \
                        float bb = b2s[col];                                      \
                        _Pragma("unroll")                                         \
                        for (int i = 0; i < 4; ++i)                               \
                            h2f[(r0 + i) * 104 + col] = tanh_(a[i] + bb);         \
                    }                                                             \
                }                                                                 \
            }                                                                     \
        }                                                                         \
        __syncthreads();                                                          \
        {                                                                         \
            if (tid < 96) {                                                       \
                int rr = tid / 12, rem = tid - rr * 12, j = rem >> 2, qc = rem & 3;\
                const float4* Wj = (const float4*)(W3s + j * 104);                \
                const float4* Hr = (const float4*)(h2f + rr * 104);               \
                float acc = 0.f;                                                  \
                _Pragma("unroll")                                                 \
                for (int kc = 0; kc < 7; ++kc) {                                  \
                    int k = qc + kc * 4;                                          \
                    if (k < 26) acc += dot4_(Wj[k], Hr[k]);                       \
                }                                                                 \
                acc += __shfl_xor(acc, 1);                                        \
                acc += __shfl_xor(acc, 2);                                        \
                if (qc == 0) fparts[rr * 3 + j] = acc + b3s[j];                   \
            }                                                                     \
        }                                                                         \
        __syncthreads();                                                          \
    } while (0)

    FEVAL(yv0, yv1, yv2);

    #pragma unroll 1
    for (int s = 0; s < 13; ++s) {
        const int   nInt = (s < 12) ? 16 : 7;
        const float hh   = 0.01f * (float)nInt;
        const int   t0   = s * 16;
        const float invN = (s < 12) ? 0.0625f : (1.f / 7.f);

        float f0_ = fparts[r * 3 + 0], f1_ = fparts[r * 3 + 1], f2_ = fparts[r * 3 + 2];
        k10 = f0_; k11 = f1_; k12 = f2_;
        ka0 = f0_; ka1 = f1_; ka2 = f2_;
        float yt0 = yv0 + 0.5f * hh * f0_, yt1 = yv1 + 0.5f * hh * f1_, yt2 = yv2 + 0.5f * hh * f2_;
        FEVAL(yt0, yt1, yt2);
        f0_ = fparts[r * 3 + 0]; f1_ = fparts[r * 3 + 1]; f2_ = fparts[r * 3 + 2];
        ka0 += 2.f * f0_; ka1 += 2.f * f1_; ka2 += 2.f * f2_;
        yt0 = yv0 + 0.5f * hh * f0_; yt1 = yv1 + 0.5f * hh * f1_; yt2 = yv2 + 0.5f * hh * f2_;
        FEVAL(yt0, yt1, yt2);
        f0_ = fparts[r * 3 + 0]; f1_ = fparts[r * 3 + 1]; f2_ = fparts[r * 3 + 2];
        ka0 += 2.f * f0_; ka1 += 2.f * f1_; ka2 += 2.f * f2_;
        yt0 = yv0 + hh * f0_; yt1 = yv1 + hh * f1_; yt2 = yv2 + hh * f2_;
        FEVAL(yt0, yt1, yt2);
        f0_ = fparts[r * 3 + 0]; f1_ = fparts[r * 3 + 1]; f2_ = fparts[r * 3 + 2];
        ka0 += f0_; ka1 += f1_; ka2 += f2_;
        const float h6 = hh * (1.f / 6.f);
        yn0 = yv0 + h6 * ka0; yn1 = yv1 + h6 * ka1; yn2 = yv2 + h6 * ka2;
        FEVAL(yn0, yn1, yn2);
        float fn0 = fparts[r * 3 + 0], fn1 = fparts[r * 3 + 1], fn2 = fparts[r * 3 + 2];

        {
            int tot = 3 * nInt;
            for (int ii = (tid & 31); ii < tot; ii += 32) {
                int q = ii / 3, j = ii - q * 3;
                float ysj = (j == 0) ? yv0 : (j == 1) ? yv1 : yv2;
                float f0j = (j == 0) ? k10 : (j == 1) ? k11 : k12;
                float ynj = (j == 0) ? yn0 : (j == 1) ? yn1 : yn2;
                float fnj = (j == 0) ? fn0 : (j == 1) ? fn1 : fn2;
                float th  = (float)(q + 1) * invN;
                float th2 = th * th, th3 = th2 * th;
                float ca = 2.f * th3 - 3.f * th2 + 1.f;
                float cb = th3 - 2.f * th2 + th;
                float cc = 3.f * th2 - 2.f * th3;
                float cd = th3 - th2;
                float v = ca * ysj + cb * hh * f0j + cc * ynj + cd * hh * fnj;
                traj[((size_t)(t0 + 1 + q) * 4096 + b0 + r) * 3 + j] = v;
            }
        }
        yv0 = yn0; yv1 = yn1; yv2 = yn2;
    }
#undef FEVAL
}

// ---------------------------------------------------------------- decoder (MFMA)
// (unchanged from round 4)
__global__ __launch_bounds__(256, 2) void k_dec(
    const float* __restrict__ traj, const float* __restrict__ W1, const float* __restrict__ b1,
    const float* __restrict__ W2, const float* __restrict__ b2, float* __restrict__ recon)
{
    __shared__ alignas(16) unsigned short hdh_s[8192], hdl_s[8192];
    __shared__ alignas(16) float zs[384];
    __shared__ float w1s[192], b1s_[64];

    const int tid  = threadIdx.x;
    const size_t p0 = (size_t)blockIdx.x * 128;
    const int lane = tid & 63, wv = tid >> 6;
    const int lrow = lane & 15, lkb = lane >> 4;

    char* hdh_c = (char*)hdh_s;
    char* hdl_c = (char*)hdl_s;

    if (tid < 96) *(float4*)&zs[tid * 4] = ((const float4*)(traj + p0 * 3))[tid];
    if (tid < 192) w1s[tid] = W1[tid];
    if (tid < 64)  b1s_[tid] = b1[tid];

    f16x8 bh[2], bl[2];
    {
        int col = wv * 16 + lrow;
        #pragma unroll
        for (int ks = 0; ks < 2; ++ks) {
            const float* wp = W2 + col * 64 + ks * 32 + lkb * 8;
            float4 a = *(const float4*)wp, b = *(const float4*)(wp + 4);
            float tmp[8] = {a.x, a.y, a.z, a.w, b.x, b.y, b.z, b.w};
            f16x8 hv, lv;
            #pragma unroll
            for (int j = 0; j < 8; ++j) {
                hv[j] = (_Float16)tmp[j];
                lv[j] = (_Float16)(tmp[j] - (float)hv[j]);
            }
            bh[ks] = hv;
            bl[ks] = lv;
        }
    }
    const float bo = b2[wv * 16 + lrow];
    __syncthreads();

    {
        const int p  = tid >> 1;
        const int u0 = (tid & 1) * 32;
        const float z0v = zs[p * 3 + 0], z1v = zs[p * 3 + 1], z2v = zs[p * 3 + 2];
        const int sw = (p & 7) << 4;
        #pragma unroll
        for (int c = 0; c < 8; ++c) {
            f16x4 hh_, hl_;
            #pragma unroll
            for (int i = 0; i < 4; ++i) {
                int u = u0 + c * 4 + i;
                float acc = b1s_[u] + w1s[u * 3 + 0] * z0v
                                    + w1s[u * 3 + 1] * z1v
                                    + w1s[u * 3 + 2] * z2v;
                float h = fmaxf(acc, 0.f);
                _Float16 hf = (_Float16)h;
                hh_[i] = hf;
                hl_[i] = (_Float16)(h - (float)hf);
            }
            int off = p * 128 + (((u0 + c * 4) * 2) ^ sw);
            *(f16x4*)(hdh_c + off) = hh_;
            *(f16x4*)(hdl_c + off) = hl_;
        }
    }
    __syncthreads();

    const int swA = (lrow & 7) << 4;
    #pragma unroll
    for (int rt = 0; rt < 8; ++rt) {
        f16x8 ahh[2], all_[2];
        #pragma unroll
        for (int ks = 0; ks < 2; ++ks) {
            int off = (rt * 16 + lrow) * 128 + ((ks * 64 + lkb * 16) ^ swA);
            ahh[ks]  = *(const f16x8*)(hdh_c + off);
            all_[ks] = *(const f16x8*)(hdl_c + off);
        }
        f32x4 acc = {0.f, 0.f, 0.f, 0.f};
        #pragma unroll
        for (int ks = 0; ks < 2; ++ks) {
            acc = MFMA16(ahh[ks],  bh[ks], acc);
            acc = MFMA16(all_[ks], bh[ks], acc);
            acc = MFMA16(ahh[ks],  bl[ks], acc);
        }
        const size_t rowg = p0 + rt * 16 + lkb * 4;
        #pragma unroll
        for (int i = 0; i < 4; ++i)
            recon[(rowg + i) * 64 + wv * 16 + lrow] = acc[i] + bo;
    }
}

extern "C" void kernel_launch(void* const* d_in, const int* in_sizes, int n_in,
                              void* d_out, int out_size, void* d_ws, size_t ws_size,
                              hipStream_t stream)
{
    const float* obs   = (const float*)d_in[0];
    const float* eps   = (const float*)d_in[1];
    const float* Wih   = (const float*)d_in[2];
    const float* Whh   = (const float*)d_in[3];
    const float* bih   = (const float*)d_in[4];
    const float* bhh   = (const float*)d_in[5];
    const float* meanW = (const float*)d_in[6];
    const float* meanB = (const float*)d_in[7];
    const float* lvW   = (const float*)d_in[8];
    const float* lvB   = (const float*)d_in[9];
    const float* dW1   = (const float*)d_in[10];
    const float* db1   = (const float*)d_in[11];
    const float* dW2   = (const float*)d_in[12];
    const float* db2   = (const float*)d_in[13];
    const float* dW3   = (const float*)d_in[14];
    const float* db3   = (const float*)d_in[15];
    const float* decW1 = (const float*)d_in[16];
    const float* decb1 = (const float*)d_in[17];
    const float* decW2 = (const float*)d_in[18];
    const float* decb2 = (const float*)d_in[19];

    float* out   = (float*)d_out;
    float* recon = out;
    float* omean = out + OFF_MEAN;
    float* olv   = out + OFF_LV;
    float* traj  = out + OFF_TRAJ;
    float* z0    = (float*)d_ws;

    k_gru<<<dim3(256), dim3(512), 0, stream>>>(obs, eps, Wih, Whh, bih, bhh,
                                               meanW, meanB, lvW, lvB, omean, olv, z0);
    k_ode<<<dim3(512), dim3(256), 0, stream>>>(dW1, db1, dW2, db2, dW3, db3, z0, traj);
    k_dec<<<dim3(6400), dim3(256), 0, stream>>>(traj, decW1, decb1, decW2, decb2, recon);
}

// Round 9
// 183.745 us; speedup vs baseline: 13.5819x; 1.1030x over previous
//
#include <hip/hip_runtime.h>
#include <stddef.h>

// Output layout (fp32):
//   recon    [200,4096,64] @ 0
//   z0_mean  [4096,3]      @ 52428800
//   z0_logvar[4096,3]      @ 52441088
//   traj     [200,4096,3]  @ 52453376
#define OFF_MEAN 52428800
#define OFF_LV   52441088
#define OFF_TRAJ 52453376

typedef _Float16 f16x8 __attribute__((ext_vector_type(8)));
typedef _Float16 f16x4 __attribute__((ext_vector_type(4)));
typedef float    f32x4 __attribute__((ext_vector_type(4)));

#define MFMA16(a, b, c) __builtin_amdgcn_mfma_f32_16x16x32_f16((a), (b), (c), 0, 0, 0)

// fast transcendentals: v_exp_f32 + v_rcp_f32 (error ~1e-6, far below budget)
__device__ __forceinline__ float sigm_(float x) {
    float e = __builtin_amdgcn_exp2f(x * -1.442695041f);
    return __builtin_amdgcn_rcpf(1.f + e);
}
__device__ __forceinline__ float tanh_(float x) {
    float e = __builtin_amdgcn_exp2f(x * 2.885390082f);
    return 1.f - 2.f * __builtin_amdgcn_rcpf(e + 1.f);
}
__device__ __forceinline__ float dot4_(float4 a, float4 b) {
    return a.x * b.x + a.y * b.y + a.z * b.z + a.w * b.w;
}

// ---------------------------------------------------------------- GRU (MFMA, gate-aligned, single-f16)
// 256 blocks x 512 threads (8 waves); 16 batch rows/block; 50 steps.
// Wave w owns gate tiles {w, 8+w, 16+w}: lane (lrow,lkb) owns unit u=w*16+lrow,
// batch rows lkb*4..+3 -> r/z/n accumulators and h_prev all thread-local.
// x and h stored as SINGLE f16 (A-side hi/lo compensation dropped: adds
// ~2e-3 on h_last over 50 steps, far below the 0.16 threshold; integration
// error dominates absmax). 6 ds_read_b128 + 18 MFMA + 4 ds_write_b16 / step.
__global__ __launch_bounds__(512, 2) void k_gru(
    const float* __restrict__ obs, const float* __restrict__ eps,
    const float* __restrict__ Wih, const float* __restrict__ Whh,
    const float* __restrict__ bih, const float* __restrict__ bhh,
    const float* __restrict__ meanW, const float* __restrict__ meanB,
    const float* __restrict__ lvW,  const float* __restrict__ lvB,
    float* __restrict__ o_mean, float* __restrict__ o_lv, float* __restrict__ z0)
{
    __shared__ alignas(16) unsigned short h_s[2][2048];  // [16][128] f16, 4-bit swizzle, dbuf
    __shared__ alignas(16) unsigned short x_s[2][1024];  // [16][64]  f16, 3-bit swizzle, dbuf
    __shared__ alignas(16) float hm_s[16 * 132];
    __shared__ float mb_s[96];

    const int tid  = threadIdx.x;
    const int b0   = blockIdx.x * 16;
    const int lane = tid & 63, wv = tid >> 6;
    const int lrow = lane & 15, lkb = lane >> 4;
    const int swX  = (lrow & 7) << 4;          // x buffer: 128B rows, 3-bit swizzle
    const int swH  = lrow << 4;                // h buffer: 256B rows, 4-bit swizzle
    const int u    = wv * 16 + lrow;           // unit owned by this lane

    // biases (per-lane scalars)
    const float bR  = bih[u]       + bhh[u];
    const float bZ  = bih[128 + u] + bhh[128 + u];
    const float bNi = bih[256 + u];
    const float bNh = bhh[256 + u];

    // Wih B-fragments (f16)
    f16x8 wihf[3][2];
    #pragma unroll
    for (int g = 0; g < 3; ++g) {
        int col = g * 128 + u;
        #pragma unroll
        for (int ks = 0; ks < 2; ++ks) {
            const float* wp = Wih + col * 64 + ks * 32 + lkb * 8;
            float4 a = *(const float4*)wp, b = *(const float4*)(wp + 4);
            float tmp[8] = {a.x, a.y, a.z, a.w, b.x, b.y, b.z, b.w};
            f16x8 hv;
            #pragma unroll
            for (int j = 0; j < 8; ++j) hv[j] = (_Float16)tmp[j];
            wihf[g][ks] = hv;
        }
    }
    // Whh B-fragments (f16)
    f16x8 whhh[3][4];
    #pragma unroll
    for (int g = 0; g < 3; ++g) {
        int col = g * 128 + u;
        #pragma unroll
        for (int ks = 0; ks < 4; ++ks) {
            const float* wp = Whh + col * 128 + ks * 32 + lkb * 8;
            float4 a = *(const float4*)wp, b = *(const float4*)(wp + 4);
            float tmp[8] = {a.x, a.y, a.z, a.w, b.x, b.y, b.z, b.w};
            f16x8 hv;
            #pragma unroll
            for (int j = 0; j < 8; ++j) hv[j] = (_Float16)tmp[j];
            whhh[g][ks] = hv;
        }
    }

    // prologue: zero hbuf[0]; stage x(0) into xbuf[0]
    for (int i = tid; i < 2048; i += 512) h_s[0][i] = 0;
    const int srow = tid >> 4, skq = (tid & 15) * 4;       // staging coords (tid<256)
    const int sxb  = srow * 128 + ((skq * 2) ^ ((srow & 7) << 4));
    float4 xn;
    if (tid < 256) {
        xn = *(const float4*)(obs + ((size_t)0 * 4096 + b0 + srow) * 64 + skq);
        f16x4 vh = {(_Float16)xn.x, (_Float16)xn.y, (_Float16)xn.z, (_Float16)xn.w};
        *(f16x4*)((char*)x_s[0] + sxb) = vh;
    }
    f32x4 hold = {0.f, 0.f, 0.f, 0.f};        // h_prev for (rows lkb*4..+3, unit u)
    __syncthreads();

    for (int t = 0; t < 50; ++t) {
        const int cur = t & 1, nxt = cur ^ 1;
        char* x_c = (char*)x_s[cur];
        char* h_c = (char*)h_s[cur];

        // prefetch x(t+1) into registers (latency hidden under MFMA phase)
        if (tid < 256) {
            int tt = (t < 49) ? t + 1 : t;
            xn = *(const float4*)(obs + ((size_t)tt * 4096 + b0 + srow) * 64 + skq);
        }

        // A-fragments (single f16)
        f16x8 xh[2], hh[4];
        #pragma unroll
        for (int ks = 0; ks < 2; ++ks) {
            int off = lrow * 128 + ((ks * 64 + lkb * 16) ^ swX);
            xh[ks] = *(const f16x8*)(x_c + off);
        }
        #pragma unroll
        for (int ks = 0; ks < 4; ++ks) {
            int off = lrow * 256 + ((ks * 64 + lkb * 16) ^ swH);
            hh[ks] = *(const f16x8*)(h_c + off);
        }

        f32x4 z4 = {0.f, 0.f, 0.f, 0.f};
        f32x4 aR = z4, aZ = z4, aNi = z4, aNh = z4;
        #pragma unroll
        for (int ks = 0; ks < 2; ++ks) {
            aR  = MFMA16(xh[ks], wihf[0][ks], aR);
            aZ  = MFMA16(xh[ks], wihf[1][ks], aZ);
            aNi = MFMA16(xh[ks], wihf[2][ks], aNi);
        }
        #pragma unroll
        for (int ks = 0; ks < 4; ++ks) {
            aR  = MFMA16(hh[ks], whhh[0][ks], aR);
            aZ  = MFMA16(hh[ks], whhh[1][ks], aZ);
            aNh = MFMA16(hh[ks], whhh[2][ks], aNh);
        }

        // gates in registers; write h(t) f16 into the NEXT h buffer
        char* hn_c = (char*)h_s[nxt];
        #pragma unroll
        for (int i = 0; i < 4; ++i) {
            float r  = sigm_(aR[i] + bR);
            float zg = sigm_(aZ[i] + bZ);
            float n  = tanh_(aNi[i] + bNi + r * (aNh[i] + bNh));
            float hv = (1.f - zg) * n + zg * hold[i];
            hold[i] = hv;
            int ri = lkb * 4 + i;
            int hb = ri * 256 + ((u * 2) ^ (ri << 4));
            *(_Float16*)(hn_c + hb) = (_Float16)hv;
        }

        // stage prefetched x(t+1) into the NEXT x buffer
        if (tid < 256 && t < 49) {
            f16x4 vh = {(_Float16)xn.x, (_Float16)xn.y, (_Float16)xn.z, (_Float16)xn.w};
            *(f16x4*)((char*)x_s[nxt] + sxb) = vh;
        }
        __syncthreads();
    }

    // dump h_last to LDS for the heads
    #pragma unroll
    for (int i = 0; i < 4; ++i)
        hm_s[(lkb * 4 + i) * 132 + u] = hold[i];
    __syncthreads();

    if (tid < 96) {
        int rr = tid / 6, c = tid - rr * 6, j = (c < 3) ? c : c - 3;
        const float* W = (c < 3) ? meanW : lvW;
        const float* B = (c < 3) ? meanB : lvB;
        float acc = B[j];
        const float4* W4 = (const float4*)(W + j * 128);
        const float4* h4 = (const float4*)(hm_s + rr * 132);
        #pragma unroll 4
        for (int kc = 0; kc < 32; ++kc) acc += dot4_(W4[kc], h4[kc]);
        mb_s[rr * 6 + c] = acc;
    }
    __syncthreads();
    if (tid < 48) {
        int rr = tid / 3, j = tid - rr * 3;
        int gb = b0 + rr;
        float m  = mb_s[rr * 6 + j];
        float lv = mb_s[rr * 6 + j + 3];
        o_mean[gb * 3 + j] = m;
        o_lv[gb * 3 + j]   = lv;
        z0[gb * 3 + j]     = m + eps[gb * 3 + j] * __expf(0.5f * lv);
    }
}

// ---------------------------------------------------------------- ODE kernel
// (unchanged from round 5)
__global__ __launch_bounds__(256, 2) void k_ode(
    const float* __restrict__ dW1, const float* __restrict__ db1,
    const float* __restrict__ dW2, const float* __restrict__ db2,
    const float* __restrict__ dW3, const float* __restrict__ db3,
    const float* __restrict__ z0, float* __restrict__ traj)
{
    __shared__ alignas(16) unsigned short h1h_s[2048];
    __shared__ alignas(16) float h2f[8 * 104];
    __shared__ alignas(16) float W3s[312];
    __shared__ float b2s[100], b3s[3];
    __shared__ float fparts[24];

    const int tid  = threadIdx.x;
    const int b0   = blockIdx.x * 8;
    const int lane = tid & 63, wv = tid >> 6;
    const int r    = tid >> 5;
    char* h1h_c = (char*)h1h_s;

    for (int i = tid; i < 512; i += 256)
        ((unsigned int*)(h1h_c + 2048))[i] = 0u;
    if (tid < 32) h2f[(tid >> 2) * 104 + 100 + (tid & 3)] = 0.f;
    for (int i = tid; i < 312; i += 256) {
        int j = i / 104, k = i - j * 104;
        W3s[i] = (k < 100) ? dW3[j * 100 + k] : 0.f;
    }
    if (tid < 100) b2s[tid] = db2[tid];
    if (tid < 3)   b3s[tid] = db3[tid];

    float w1r[12], b1r[4];
    {
        int k0 = (tid & 31) * 4;
        #pragma unroll
        for (int i = 0; i < 4; ++i) {
            int k = k0 + i;
            if (k < 100) {
                w1r[3 * i + 0] = dW1[k * 3 + 0];
                w1r[3 * i + 1] = dW1[k * 3 + 1];
                w1r[3 * i + 2] = dW1[k * 3 + 2];
                b1r[i] = db1[k];
            } else {
                w1r[3 * i + 0] = 0.f; w1r[3 * i + 1] = 0.f; w1r[3 * i + 2] = 0.f;
                b1r[i] = 0.f;
            }
        }
    }
    f16x8 w2h[2][4], w2l[2][4];
    {
        const int lrow = lane & 15, lkb = lane >> 4;
        #pragma unroll
        for (int tile = 0; tile < 2; ++tile) {
            int col = (wv * 2 + tile) * 16 + lrow;
            #pragma unroll
            for (int ks = 0; ks < 4; ++ks) {
                f16x8 hv, lv;
                #pragma unroll
                for (int j = 0; j < 8; ++j) {
                    int k = ks * 32 + lkb * 8 + j;
                    float v = (col < 100 && k < 100) ? dW2[col * 100 + k] : 0.f;
                    _Float16 hf = (_Float16)v;
                    hv[j] = hf;
                    lv[j] = (_Float16)(v - (float)hf);
                }
                w2h[tile][ks] = hv;
                w2l[tile][ks] = lv;
            }
        }
    }

    float yv0 = z0[(b0 + r) * 3 + 0];
    float yv1 = z0[(b0 + r) * 3 + 1];
    float yv2 = z0[(b0 + r) * 3 + 2];
    float ka0, ka1, ka2, k10, k11, k12, yn0, yn1, yn2;

    if (tid < 24) {
        int rr = tid / 3, j = tid - rr * 3;
        traj[((size_t)(b0 + rr)) * 3 + j] = z0[(b0 + rr) * 3 + j];
    }
    __syncthreads();

    const int lrow = lane & 15, lkb = lane >> 4;
    const int swA  = (lrow & 7) << 4;

#define FEVAL(yt0_, yt1_, yt2_)                                                  \
    do {                                                                          \
        {                                                                         \
            int q = tid & 31, k0 = q * 4;                                         \
            f16x4 hh_;                                                            \
            _Pragma("unroll")                                                     \
            for (int i = 0; i < 4; ++i) {                                         \
                float acc = b1r[i] + w1r[3 * i] * (yt0_)                          \
                          + w1r[3 * i + 1] * (yt1_) + w1r[3 * i + 2] * (yt2_);    \
                hh_[i] = (_Float16)tanh_(acc);                                    \
            }                                                                     \
            int off = r * 256 + ((k0 * 2) ^ (r << 4));                            \
            *(f16x4*)(h1h_c + off) = hh_;                                         \
        }                                                                         \
        __syncthreads();                                                          \
        {                                                                         \
            f16x8 ah[4];                                                          \
            _Pragma("unroll")                                                     \
            for (int ks = 0; ks < 4; ++ks) {                                      \
                int off = lrow * 256 + ((ks * 64 + lkb * 16) ^ swA);              \
                ah[ks] = *(const f16x8*)(h1h_c + off);                            \
            }                                                                     \
            f32x4 acc0 = {0.f, 0.f, 0.f, 0.f}, acc1 = {0.f, 0.f, 0.f, 0.f};       \
            _Pragma("unroll")                                                     \
            for (int ks = 0; ks < 4; ++ks) {                                      \
                acc0 = MFMA16(ah[ks], w2h[0][ks], acc0);                          \
                acc0 = MFMA16(ah[ks], w2l[0][ks], acc0);                          \
                acc1 = MFMA16(ah[ks], w2h[1][ks], acc1);                          \
                acc1 = MFMA16(ah[ks], w2l[1][ks], acc1);                          \
            }                                                                     \
            if (lkb < 2) {                                                        \
                int r0 = lkb * 4;                                                 \
                _Pragma("unroll")                                                 \
                for (int tile = 0; tile < 2; ++tile) {                            \
                    int col = (wv * 2 + tile) * 16 + lrow;                        \
                    f32x4 a = tile ? acc1 : acc0;                                 \
                    if (col < 100) {                                              \
                        float bb = b2s[col];                                      \
                        _Pragma("unroll")                                         \
                        for (int i = 0; i < 4; ++i)                               \
                            h2f[(r0 + i) * 104 + col] = tanh_(a[i] + bb);         \
                    }                                                             \
                }                                                                 \
            }                                                                     \
        }                                                                         \
        __syncthreads();                                                          \
        {                                                                         \
            if (tid < 96) {                                                       \
                int rr = tid / 12, rem = tid - rr * 12, j = rem >> 2, qc = rem & 3;\
                const float4* Wj = (const float4*)(W3s + j * 104);                \
                const float4* Hr = (const float4*)(h2f + rr * 104);               \
                float acc = 0.f;                                                  \
                _Pragma("unroll")                                                 \
                for (int kc = 0; kc < 7; ++kc) {                                  \
                    int k = qc + kc * 4;                                          \
                    if (k < 26) acc += dot4_(Wj[k], Hr[k]);                       \
                }                                                                 \
                acc += __shfl_xor(acc, 1);                                        \
                acc += __shfl_xor(acc, 2);                                        \
                if (qc == 0) fparts[rr * 3 + j] = acc + b3s[j];                   \
            }                                                                     \
        }                                                                         \
        __syncthreads();                                                          \
    } while (0)

    FEVAL(yv0, yv1, yv2);

    #pragma unroll 1
    for (int s = 0; s < 13; ++s) {
        const int   nInt = (s < 12) ? 16 : 7;
        const float hh   = 0.01f * (float)nInt;
        const int   t0   = s * 16;
        const float invN = (s < 12) ? 0.0625f : (1.f / 7.f);

        float f0_ = fparts[r * 3 + 0], f1_ = fparts[r * 3 + 1], f2_ = fparts[r * 3 + 2];
        k10 = f0_; k11 = f1_; k12 = f2_;
        ka0 = f0_; ka1 = f1_; ka2 = f2_;
        float yt0 = yv0 + 0.5f * hh * f0_, yt1 = yv1 + 0.5f * hh * f1_, yt2 = yv2 + 0.5f * hh * f2_;
        FEVAL(yt0, yt1, yt2);
        f0_ = fparts[r * 3 + 0]; f1_ = fparts[r * 3 + 1]; f2_ = fparts[r * 3 + 2];
        ka0 += 2.f * f0_; ka1 += 2.f * f1_; ka2 += 2.f * f2_;
        yt0 = yv0 + 0.5f * hh * f0_; yt1 = yv1 + 0.5f * hh * f1_; yt2 = yv2 + 0.5f * hh * f2_;
        FEVAL(yt0, yt1, yt2);
        f0_ = fparts[r * 3 + 0]; f1_ = fparts[r * 3 + 1]; f2_ = fparts[r * 3 + 2];
        ka0 += 2.f * f0_; ka1 += 2.f * f1_; ka2 += 2.f * f2_;
        yt0 = yv0 + hh * f0_; yt1 = yv1 + hh * f1_; yt2 = yv2 + hh * f2_;
        FEVAL(yt0, yt1, yt2);
        f0_ = fparts[r * 3 + 0]; f1_ = fparts[r * 3 + 1]; f2_ = fparts[r * 3 + 2];
        ka0 += f0_; ka1 += f1_; ka2 += f2_;
        const float h6 = hh * (1.f / 6.f);
        yn0 = yv0 + h6 * ka0; yn1 = yv1 + h6 * ka1; yn2 = yv2 + h6 * ka2;
        FEVAL(yn0, yn1, yn2);
        float fn0 = fparts[r * 3 + 0], fn1 = fparts[r * 3 + 1], fn2 = fparts[r * 3 + 2];

        {
            int tot = 3 * nInt;
            for (int ii = (tid & 31); ii < tot; ii += 32) {
                int q = ii / 3, j = ii - q * 3;
                float ysj = (j == 0) ? yv0 : (j == 1) ? yv1 : yv2;
                float f0j = (j == 0) ? k10 : (j == 1) ? k11 : k12;
                float ynj = (j == 0) ? yn0 : (j == 1) ? yn1 : yn2;
                float fnj = (j == 0) ? fn0 : (j == 1) ? fn1 : fn2;
                float th  = (float)(q + 1) * invN;
                float th2 = th * th, th3 = th2 * th;
                float ca = 2.f * th3 - 3.f * th2 + 1.f;
                float cb = th3 - 2.f * th2 + th;
                float cc = 3.f * th2 - 2.f * th3;
                float cd = th3 - th2;
                float v = ca * ysj + cb * hh * f0j + cc * ynj + cd * hh * fnj;
                traj[((size_t)(t0 + 1 + q) * 4096 + b0 + r) * 3 + j] = v;
            }
        }
        yv0 = yn0; yv1 = yn1; yv2 = yn2;
    }
#undef FEVAL
}

// ---------------------------------------------------------------- decoder (MFMA)
// (unchanged from round 4)
__global__ __launch_bounds__(256, 2) void k_dec(
    const float* __restrict__ traj, const float* __restrict__ W1, const float* __restrict__ b1,
    const float* __restrict__ W2, const float* __restrict__ b2, float* __restrict__ recon)
{
    __shared__ alignas(16) unsigned short hdh_s[8192], hdl_s[8192];
    __shared__ alignas(16) float zs[384];
    __shared__ float w1s[192], b1s_[64];

    const int tid  = threadIdx.x;
    const size_t p0 = (size_t)blockIdx.x * 128;
    const int lane = tid & 63, wv = tid >> 6;
    const int lrow = lane & 15, lkb = lane >> 4;

    char* hdh_c = (char*)hdh_s;
    char* hdl_c = (char*)hdl_s;

    if (tid < 96) *(float4*)&zs[tid * 4] = ((const float4*)(traj + p0 * 3))[tid];
    if (tid < 192) w1s[tid] = W1[tid];
    if (tid < 64)  b1s_[tid] = b1[tid];

    f16x8 bh[2], bl[2];
    {
        int col = wv * 16 + lrow;
        #pragma unroll
        for (int ks = 0; ks < 2; ++ks) {
            const float* wp = W2 + col * 64 + ks * 32 + lkb * 8;
            float4 a = *(const float4*)wp, b = *(const float4*)(wp + 4);
            float tmp[8] = {a.x, a.y, a.z, a.w, b.x, b.y, b.z, b.w};
            f16x8 hv, lv;
            #pragma unroll
            for (int j = 0; j < 8; ++j) {
                hv[j] = (_Float16)tmp[j];
                lv[j] = (_Float16)(tmp[j] - (float)hv[j]);
            }
            bh[ks] = hv;
            bl[ks] = lv;
        }
    }
    const float bo = b2[wv * 16 + lrow];
    __syncthreads();

    {
        const int p  = tid >> 1;
        const int u0 = (tid & 1) * 32;
        const float z0v = zs[p * 3 + 0], z1v = zs[p * 3 + 1], z2v = zs[p * 3 + 2];
        const int sw = (p & 7) << 4;
        #pragma unroll
        for (int c = 0; c < 8; ++c) {
            f16x4 hh_, hl_;
            #pragma unroll
            for (int i = 0; i < 4; ++i) {
                int u = u0 + c * 4 + i;
                float acc = b1s_[u] + w1s[u * 3 + 0] * z0v
                                    + w1s[u * 3 + 1] * z1v
                                    + w1s[u * 3 + 2] * z2v;
                float h = fmaxf(acc, 0.f);
                _Float16 hf = (_Float16)h;
                hh_[i] = hf;
                hl_[i] = (_Float16)(h - (float)hf);
            }
            int off = p * 128 + (((u0 + c * 4) * 2) ^ sw);
            *(f16x4*)(hdh_c + off) = hh_;
            *(f16x4*)(hdl_c + off) = hl_;
        }
    }
    __syncthreads();

    const int swA = (lrow & 7) << 4;
    #pragma unroll
    for (int rt = 0; rt < 8; ++rt) {
        f16x8 ahh[2], all_[2];
        #pragma unroll
        for (int ks = 0; ks < 2; ++ks) {
            int off = (rt * 16 + lrow) * 128 + ((ks * 64 + lkb * 16) ^ swA);
            ahh[ks]  = *(const f16x8*)(hdh_c + off);
            all_[ks] = *(const f16x8*)(hdl_c + off);
        }
        f32x4 acc = {0.f, 0.f, 0.f, 0.f};
        #pragma unroll
        for (int ks = 0; ks < 2; ++ks) {
            acc = MFMA16(ahh[ks],  bh[ks], acc);
            acc = MFMA16(all_[ks], bh[ks], acc);
            acc = MFMA16(ahh[ks],  bl[ks], acc);
        }
        const size_t rowg = p0 + rt * 16 + lkb * 4;
        #pragma unroll
        for (int i = 0; i < 4; ++i)
            recon[(rowg + i) * 64 + wv * 16 + lrow] = acc[i] + bo;
    }
}

extern "C" void kernel_launch(void* const* d_in, const int* in_sizes, int n_in,
                              void* d_out, int out_size, void* d_ws, size_t ws_size,
                              hipStream_t stream)
{
    const float* obs   = (const float*)d_in[0];
    const float* eps   = (const float*)d_in[1];
    const float* Wih   = (const float*)d_in[2];
    const float* Whh   = (const float*)d_in[3];
    const float* bih   = (const float*)d_in[4];
    const float* bhh   = (const float*)d_in[5];
    const float* meanW = (const float*)d_in[6];
    const float* meanB = (const float*)d_in[7];
    const float* lvW   = (const float*)d_in[8];
    const float* lvB   = (const float*)d_in[9];
    const float* dW1   = (const float*)d_in[10];
    const float* db1   = (const float*)d_in[11];
    const float* dW2   = (const float*)d_in[12];
    const float* db2   = (const float*)d_in[13];
    const float* dW3   = (const float*)d_in[14];
    const float* db3   = (const float*)d_in[15];
    const float* decW1 = (const float*)d_in[16];
    const float* decb1 = (const float*)d_in[17];
    const float* decW2 = (const float*)d_in[18];
    const float* decb2 = (const float*)d_in[19];

    float* out   = (float*)d_out;
    float* recon = out;
    float* omean = out + OFF_MEAN;
    float* olv   = out + OFF_LV;
    float* traj  = out + OFF_TRAJ;
    float* z0    = (float*)d_ws;

    k_gru<<<dim3(256), dim3(512), 0, stream>>>(obs, eps, Wih, Whh, bih, bhh,
                                               meanW, meanB, lvW, lvB, omean, olv, z0);
    k_ode<<<dim3(512), dim3(256), 0, stream>>>(dW1, db1, dW2, db2, dW3, db3, z0, traj);
    k_dec<<<dim3(6400), dim3(256), 0, stream>>>(traj, decW1, decb1, decW2, decb2, recon);
}

// Round 10
// 164.725 us; speedup vs baseline: 15.1501x; 1.1155x over previous
//
#include <hip/hip_runtime.h>
#include <stddef.h>

// Output layout (fp32):
//   recon    [200,4096,64] @ 0
//   z0_mean  [4096,3]      @ 52428800
//   z0_logvar[4096,3]      @ 52441088
//   traj     [200,4096,3]  @ 52453376
#define OFF_MEAN 52428800
#define OFF_LV   52441088
#define OFF_TRAJ 52453376

typedef _Float16 f16x8 __attribute__((ext_vector_type(8)));
typedef _Float16 f16x4 __attribute__((ext_vector_type(4)));
typedef float    f32x4 __attribute__((ext_vector_type(4)));

#define MFMA16(a, b, c) __builtin_amdgcn_mfma_f32_16x16x32_f16((a), (b), (c), 0, 0, 0)

// fast transcendentals: v_exp_f32 + v_rcp_f32 (error ~1e-6, far below budget)
__device__ __forceinline__ float sigm_(float x) {
    float e = __builtin_amdgcn_exp2f(x * -1.442695041f);
    return __builtin_amdgcn_rcpf(1.f + e);
}
__device__ __forceinline__ float tanh_(float x) {
    float e = __builtin_amdgcn_exp2f(x * 2.885390082f);
    return 1.f - 2.f * __builtin_amdgcn_rcpf(e + 1.f);
}
__device__ __forceinline__ float dot4_(float4 a, float4 b) {
    return a.x * b.x + a.y * b.y + a.z * b.z + a.w * b.w;
}

// ---------------------------------------------------------------- GRU (MFMA, gate-aligned, single-f16)
// (unchanged from round 9)
__global__ __launch_bounds__(512, 2) void k_gru(
    const float* __restrict__ obs, const float* __restrict__ eps,
    const float* __restrict__ Wih, const float* __restrict__ Whh,
    const float* __restrict__ bih, const float* __restrict__ bhh,
    const float* __restrict__ meanW, const float* __restrict__ meanB,
    const float* __restrict__ lvW,  const float* __restrict__ lvB,
    float* __restrict__ o_mean, float* __restrict__ o_lv, float* __restrict__ z0)
{
    __shared__ alignas(16) unsigned short h_s[2][2048];  // [16][128] f16, 4-bit swizzle, dbuf
    __shared__ alignas(16) unsigned short x_s[2][1024];  // [16][64]  f16, 3-bit swizzle, dbuf
    __shared__ alignas(16) float hm_s[16 * 132];
    __shared__ float mb_s[96];

    const int tid  = threadIdx.x;
    const int b0   = blockIdx.x * 16;
    const int lane = tid & 63, wv = tid >> 6;
    const int lrow = lane & 15, lkb = lane >> 4;
    const int swX  = (lrow & 7) << 4;
    const int swH  = lrow << 4;
    const int u    = wv * 16 + lrow;

    const float bR  = bih[u]       + bhh[u];
    const float bZ  = bih[128 + u] + bhh[128 + u];
    const float bNi = bih[256 + u];
    const float bNh = bhh[256 + u];

    f16x8 wihf[3][2];
    #pragma unroll
    for (int g = 0; g < 3; ++g) {
        int col = g * 128 + u;
        #pragma unroll
        for (int ks = 0; ks < 2; ++ks) {
            const float* wp = Wih + col * 64 + ks * 32 + lkb * 8;
            float4 a = *(const float4*)wp, b = *(const float4*)(wp + 4);
            float tmp[8] = {a.x, a.y, a.z, a.w, b.x, b.y, b.z, b.w};
            f16x8 hv;
            #pragma unroll
            for (int j = 0; j < 8; ++j) hv[j] = (_Float16)tmp[j];
            wihf[g][ks] = hv;
        }
    }
    f16x8 whhh[3][4];
    #pragma unroll
    for (int g = 0; g < 3; ++g) {
        int col = g * 128 + u;
        #pragma unroll
        for (int ks = 0; ks < 4; ++ks) {
            const float* wp = Whh + col * 128 + ks * 32 + lkb * 8;
            float4 a = *(const float4*)wp, b = *(const float4*)(wp + 4);
            float tmp[8] = {a.x, a.y, a.z, a.w, b.x, b.y, b.z, b.w};
            f16x8 hv;
            #pragma unroll
            for (int j = 0; j < 8; ++j) hv[j] = (_Float16)tmp[j];
            whhh[g][ks] = hv;
        }
    }

    for (int i = tid; i < 2048; i += 512) h_s[0][i] = 0;
    const int srow = tid >> 4, skq = (tid & 15) * 4;
    const int sxb  = srow * 128 + ((skq * 2) ^ ((srow & 7) << 4));
    float4 xn;
    if (tid < 256) {
        xn = *(const float4*)(obs + ((size_t)0 * 4096 + b0 + srow) * 64 + skq);
        f16x4 vh = {(_Float16)xn.x, (_Float16)xn.y, (_Float16)xn.z, (_Float16)xn.w};
        *(f16x4*)((char*)x_s[0] + sxb) = vh;
    }
    f32x4 hold = {0.f, 0.f, 0.f, 0.f};
    __syncthreads();

    for (int t = 0; t < 50; ++t) {
        const int cur = t & 1, nxt = cur ^ 1;
        char* x_c = (char*)x_s[cur];
        char* h_c = (char*)h_s[cur];

        if (tid < 256) {
            int tt = (t < 49) ? t + 1 : t;
            xn = *(const float4*)(obs + ((size_t)tt * 4096 + b0 + srow) * 64 + skq);
        }

        f16x8 xh[2], hh[4];
        #pragma unroll
        for (int ks = 0; ks < 2; ++ks) {
            int off = lrow * 128 + ((ks * 64 + lkb * 16) ^ swX);
            xh[ks] = *(const f16x8*)(x_c + off);
        }
        #pragma unroll
        for (int ks = 0; ks < 4; ++ks) {
            int off = lrow * 256 + ((ks * 64 + lkb * 16) ^ swH);
            hh[ks] = *(const f16x8*)(h_c + off);
        }

        f32x4 z4 = {0.f, 0.f, 0.f, 0.f};
        f32x4 aR = z4, aZ = z4, aNi = z4, aNh = z4;
        #pragma unroll
        for (int ks = 0; ks < 2; ++ks) {
            aR  = MFMA16(xh[ks], wihf[0][ks], aR);
            aZ  = MFMA16(xh[ks], wihf[1][ks], aZ);
            aNi = MFMA16(xh[ks], wihf[2][ks], aNi);
        }
        #pragma unroll
        for (int ks = 0; ks < 4; ++ks) {
            aR  = MFMA16(hh[ks], whhh[0][ks], aR);
            aZ  = MFMA16(hh[ks], whhh[1][ks], aZ);
            aNh = MFMA16(hh[ks], whhh[2][ks], aNh);
        }

        char* hn_c = (char*)h_s[nxt];
        #pragma unroll
        for (int i = 0; i < 4; ++i) {
            float r  = sigm_(aR[i] + bR);
            float zg = sigm_(aZ[i] + bZ);
            float n  = tanh_(aNi[i] + bNi + r * (aNh[i] + bNh));
            float hv = (1.f - zg) * n + zg * hold[i];
            hold[i] = hv;
            int ri = lkb * 4 + i;
            int hb = ri * 256 + ((u * 2) ^ (ri << 4));
            *(_Float16*)(hn_c + hb) = (_Float16)hv;
        }

        if (tid < 256 && t < 49) {
            f16x4 vh = {(_Float16)xn.x, (_Float16)xn.y, (_Float16)xn.z, (_Float16)xn.w};
            *(f16x4*)((char*)x_s[nxt] + sxb) = vh;
        }
        __syncthreads();
    }

    #pragma unroll
    for (int i = 0; i < 4; ++i)
        hm_s[(lkb * 4 + i) * 132 + u] = hold[i];
    __syncthreads();

    if (tid < 96) {
        int rr = tid / 6, c = tid - rr * 6, j = (c < 3) ? c : c - 3;
        const float* W = (c < 3) ? meanW : lvW;
        const float* B = (c < 3) ? meanB : lvB;
        float acc = B[j];
        const float4* W4 = (const float4*)(W + j * 128);
        const float4* h4 = (const float4*)(hm_s + rr * 132);
        #pragma unroll 4
        for (int kc = 0; kc < 32; ++kc) acc += dot4_(W4[kc], h4[kc]);
        mb_s[rr * 6 + c] = acc;
    }
    __syncthreads();
    if (tid < 48) {
        int rr = tid / 3, j = tid - rr * 3;
        int gb = b0 + rr;
        float m  = mb_s[rr * 6 + j];
        float lv = mb_s[rr * 6 + j + 3];
        o_mean[gb * 3 + j] = m;
        o_lv[gb * 3 + j]   = lv;
        z0[gb * 3 + j]     = m + eps[gb * 3 + j] * __expf(0.5f * lv);
    }
}

// ---------------------------------------------------------------- ODE + decoder (fused)
// RK4 h=0.16 (12 steps) + final 0.07; start-inclusive dense windows:
// step s<12 emits t=16s..16s+15 (q/16), s=12 emits t=192..199 (q/7, q=7 -> yn).
// Per step: dense z -> zbuf; hd = relu(W1d z + b1d) -> f16 swizzled LDS;
// per-wave MFMA col-tile (16 outputs) x row-tiles -> recon stores.
// FEVAL: W2-lo term dropped (8 MFMA). 512 blocks x 256 threads, 2 blocks/CU.
__global__ __launch_bounds__(256, 2) void k_odec(
    const float* __restrict__ dW1, const float* __restrict__ db1,
    const float* __restrict__ dW2, const float* __restrict__ db2,
    const float* __restrict__ dW3, const float* __restrict__ db3,
    const float* __restrict__ decW1, const float* __restrict__ decb1,
    const float* __restrict__ decW2, const float* __restrict__ decb2,
    const float* __restrict__ z0, float* __restrict__ traj, float* __restrict__ recon)
{
    __shared__ alignas(16) unsigned short h1h_s[2048];    // [16][128] f16, swizzled
    __shared__ alignas(16) unsigned short hd_s[16384];    // [128][64] f16, swizzled
    __shared__ alignas(16) float h2f[8 * 104];
    __shared__ alignas(16) float W3s[312];
    __shared__ alignas(16) float zbuf[128 * 4];
    __shared__ float w1ds[192], b1ds[64];
    __shared__ float b2s[100], b3s[3];
    __shared__ float fparts[24];

    const int tid  = threadIdx.x;
    const int b0   = blockIdx.x * 8;
    const int lane = tid & 63, wv = tid >> 6;
    const int r    = tid >> 5;
    char* h1h_c = (char*)h1h_s;
    char* hd_c  = (char*)hd_s;

    for (int i = tid; i < 512; i += 256)
        ((unsigned int*)(h1h_c + 2048))[i] = 0u;
    if (tid < 32) h2f[(tid >> 2) * 104 + 100 + (tid & 3)] = 0.f;
    for (int i = tid; i < 312; i += 256) {
        int j = i / 104, k = i - j * 104;
        W3s[i] = (k < 100) ? dW3[j * 100 + k] : 0.f;
    }
    if (tid < 100) b2s[tid] = db2[tid];
    if (tid < 3)   b3s[tid] = db3[tid];
    if (tid < 192) w1ds[tid] = decW1[tid];
    if (tid < 64)  b1ds[tid] = decb1[tid];

    // ODE stage-1 weights in registers
    float w1r[12], b1r[4];
    {
        int k0 = (tid & 31) * 4;
        #pragma unroll
        for (int i = 0; i < 4; ++i) {
            int k = k0 + i;
            if (k < 100) {
                w1r[3 * i + 0] = dW1[k * 3 + 0];
                w1r[3 * i + 1] = dW1[k * 3 + 1];
                w1r[3 * i + 2] = dW1[k * 3 + 2];
                b1r[i] = db1[k];
            } else {
                w1r[3 * i + 0] = 0.f; w1r[3 * i + 1] = 0.f; w1r[3 * i + 2] = 0.f;
                b1r[i] = 0.f;
            }
        }
    }
    const int lrow = lane & 15, lkb = lane >> 4;
    const int swA  = (lrow & 7) << 4;

    // ODE W2 B-fragments (f16, hi only), 2 col-tiles per wave
    f16x8 w2h[2][4];
    #pragma unroll
    for (int tile = 0; tile < 2; ++tile) {
        int col = (wv * 2 + tile) * 16 + lrow;
        #pragma unroll
        for (int ks = 0; ks < 4; ++ks) {
            f16x8 hv;
            #pragma unroll
            for (int j = 0; j < 8; ++j) {
                int k = ks * 32 + lkb * 8 + j;
                float v = (col < 100 && k < 100) ? dW2[col * 100 + k] : 0.f;
                hv[j] = (_Float16)v;
            }
            w2h[tile][ks] = hv;
        }
    }
    // decoder W2 B-fragments (f16), one col-tile per wave (4 waves x 16 = 64)
    const int colD = wv * 16 + lrow;
    f16x8 dbh[2];
    #pragma unroll
    for (int ks = 0; ks < 2; ++ks) {
        const float* wp = decW2 + colD * 64 + ks * 32 + lkb * 8;
        float4 a = *(const float4*)wp, b = *(const float4*)(wp + 4);
        float tmp[8] = {a.x, a.y, a.z, a.w, b.x, b.y, b.z, b.w};
        f16x8 hv;
        #pragma unroll
        for (int j = 0; j < 8; ++j) hv[j] = (_Float16)tmp[j];
        dbh[ks] = hv;
    }
    const float dbo = decb2[colD];

    float yv0 = z0[(b0 + r) * 3 + 0];
    float yv1 = z0[(b0 + r) * 3 + 1];
    float yv2 = z0[(b0 + r) * 3 + 2];
    float ka0, ka1, ka2, k10, k11, k12, yn0, yn1, yn2;
    __syncthreads();

#define FEVAL(yt0_, yt1_, yt2_)                                                  \
    do {                                                                          \
        {                                                                         \
            int q = tid & 31, k0 = q * 4;                                         \
            f16x4 hh_;                                                            \
            _Pragma("unroll")                                                     \
            for (int i = 0; i < 4; ++i) {                                         \
                float acc = b1r[i] + w1r[3 * i] * (yt0_)                          \
                          + w1r[3 * i + 1] * (yt1_) + w1r[3 * i + 2] * (yt2_);    \
                hh_[i] = (_Float16)tanh_(acc);                                    \
            }                                                                     \
            int off = r * 256 + ((k0 * 2) ^ (r << 4));                            \
            *(f16x4*)(h1h_c + off) = hh_;                                         \
        }                                                                         \
        __syncthreads();                                                          \
        {                                                                         \
            f16x8 ah[4];                                                          \
            _Pragma("unroll")                                                     \
            for (int ks = 0; ks < 4; ++ks) {                                      \
                int off = lrow * 256 + ((ks * 64 + lkb * 16) ^ swA);              \
                ah[ks] = *(const f16x8*)(h1h_c + off);                            \
            }                                                                     \
            f32x4 acc0 = {0.f, 0.f, 0.f, 0.f}, acc1 = {0.f, 0.f, 0.f, 0.f};       \
            _Pragma("unroll")                                                     \
            for (int ks = 0; ks < 4; ++ks) {                                      \
                acc0 = MFMA16(ah[ks], w2h[0][ks], acc0);                          \
                acc1 = MFMA16(ah[ks], w2h[1][ks], acc1);                          \
            }                                                                     \
            if (lkb < 2) {                                                        \
                int r0 = lkb * 4;                                                 \
                _Pragma("unroll")                                                 \
                for (int tile = 0; tile < 2; ++tile) {                            \
                    int col = (wv * 2 + tile) * 16 + lrow;                        \
                    f32x4 a = tile ? acc1 : acc0;                                 \
                    if (col < 100) {                                              \
                        float bb = b2s[col];                                      \
                        _Pragma("unroll")                                         \
                        for (int i = 0; i < 4; ++i)                               \
                            h2f[(r0 + i) * 104 + col] = tanh_(a[i] + bb);         \
                    }                                                             \
                }                                                                 \
            }                                                                     \
        }                                                                         \
        __syncthreads();                                                          \
        {                                                                         \
            if (tid < 96) {                                                       \
                int rr = tid / 12, rem = tid - rr * 12, j = rem >> 2, qc = rem & 3;\
                const float4* Wj = (const float4*)(W3s + j * 104);                \
                const float4* Hr = (const float4*)(h2f + rr * 104);               \
                float acc = 0.f;                                                  \
                _Pragma("unroll")                                                 \
                for (int kc = 0; kc < 7; ++kc) {                                  \
                    int k = qc + kc * 4;                                          \
                    if (k < 26) acc += dot4_(Wj[k], Hr[k]);                       \
                }                                                                 \
                acc += __shfl_xor(acc, 1);                                        \
                acc += __shfl_xor(acc, 2);                                        \
                if (qc == 0) fparts[rr * 3 + j] = acc + b3s[j];                   \
            }                                                                     \
        }                                                                         \
        __syncthreads();                                                          \
    } while (0)

    FEVAL(yv0, yv1, yv2);

    #pragma unroll 1
    for (int s = 0; s < 13; ++s) {
        const int   npts = (s < 12) ? 16 : 8;           // dense points this step
        const float hh   = (s < 12) ? 0.16f : 0.07f;
        const int   t0   = s * 16;
        const float invN = (s < 12) ? 0.0625f : (1.f / 7.f);

        // RK4
        float f0_ = fparts[r * 3 + 0], f1_ = fparts[r * 3 + 1], f2_ = fparts[r * 3 + 2];
        k10 = f0_; k11 = f1_; k12 = f2_;
        ka0 = f0_; ka1 = f1_; ka2 = f2_;
        float yt0 = yv0 + 0.5f * hh * f0_, yt1 = yv1 + 0.5f * hh * f1_, yt2 = yv2 + 0.5f * hh * f2_;
        FEVAL(yt0, yt1, yt2);
        f0_ = fparts[r * 3 + 0]; f1_ = fparts[r * 3 + 1]; f2_ = fparts[r * 3 + 2];
        ka0 += 2.f * f0_; ka1 += 2.f * f1_; ka2 += 2.f * f2_;
        yt0 = yv0 + 0.5f * hh * f0_; yt1 = yv1 + 0.5f * hh * f1_; yt2 = yv2 + 0.5f * hh * f2_;
        FEVAL(yt0, yt1, yt2);
        f0_ = fparts[r * 3 + 0]; f1_ = fparts[r * 3 + 1]; f2_ = fparts[r * 3 + 2];
        ka0 += 2.f * f0_; ka1 += 2.f * f1_; ka2 += 2.f * f2_;
        yt0 = yv0 + hh * f0_; yt1 = yv1 + hh * f1_; yt2 = yv2 + hh * f2_;
        FEVAL(yt0, yt1, yt2);
        f0_ = fparts[r * 3 + 0]; f1_ = fparts[r * 3 + 1]; f2_ = fparts[r * 3 + 2];
        ka0 += f0_; ka1 += f1_; ka2 += f2_;
        const float h6 = hh * (1.f / 6.f);
        yn0 = yv0 + h6 * ka0; yn1 = yv1 + h6 * ka1; yn2 = yv2 + h6 * ka2;
        FEVAL(yn0, yn1, yn2);
        float fn0 = fparts[r * 3 + 0], fn1 = fparts[r * 3 + 1], fn2 = fparts[r * 3 + 2];

        // phase Z: dense output -> traj (global) + zbuf (LDS)
        {
            int tot = 3 * npts;
            for (int ii = (tid & 31); ii < tot; ii += 32) {
                int q = ii / 3, j = ii - q * 3;
                float ysj = (j == 0) ? yv0 : (j == 1) ? yv1 : yv2;
                float f0j = (j == 0) ? k10 : (j == 1) ? k11 : k12;
                float ynj = (j == 0) ? yn0 : (j == 1) ? yn1 : yn2;
                float fnj = (j == 0) ? fn0 : (j == 1) ? fn1 : fn2;
                float th  = (float)q * invN;
                float th2 = th * th, th3 = th2 * th;
                float ca = 2.f * th3 - 3.f * th2 + 1.f;
                float cb = th3 - 2.f * th2 + th;
                float cc = 3.f * th2 - 2.f * th3;
                float cd = th3 - th2;
                float v = ca * ysj + cb * hh * f0j + cc * ynj + cd * hh * fnj;
                traj[((size_t)(t0 + q) * 4096 + b0 + r) * 3 + j] = v;
                zbuf[(q * 8 + r) * 4 + j] = v;
            }
        }
        __syncthreads();

        // phase H: hd = relu(W1d z + b1d) -> f16 swizzled LDS
        {
            const int p  = tid >> 1;
            const int u0 = (tid & 1) * 32;
            if (p < npts * 8) {
                const float z0v = zbuf[p * 4 + 0], z1v = zbuf[p * 4 + 1], z2v = zbuf[p * 4 + 2];
                const int sw = (p & 7) << 4;
                #pragma unroll
                for (int c = 0; c < 8; ++c) {
                    f16x4 hh_;
                    #pragma unroll
                    for (int i = 0; i < 4; ++i) {
                        int u = u0 + c * 4 + i;
                        float acc = b1ds[u] + w1ds[u * 3 + 0] * z0v
                                            + w1ds[u * 3 + 1] * z1v
                                            + w1ds[u * 3 + 2] * z2v;
                        hh_[i] = (_Float16)fmaxf(acc, 0.f);
                    }
                    int off = p * 128 + (((u0 + c * 4) * 2) ^ sw);
                    *(f16x4*)(hd_c + off) = hh_;
                }
            }
        }
        __syncthreads();

        // phase M: recon = hd @ decW2^T + b2  (wave wv owns cols wv*16..+15)
        {
            const int nrt = (npts * 8) >> 4;
            for (int rt = 0; rt < nrt; ++rt) {
                f16x8 a0, a1;
                {
                    int base = (rt * 16 + lrow) * 128;
                    a0 = *(const f16x8*)(hd_c + base + ((0 + lkb * 16) ^ swA));
                    a1 = *(const f16x8*)(hd_c + base + ((64 + lkb * 16) ^ swA));
                }
                f32x4 acc = {0.f, 0.f, 0.f, 0.f};
                acc = MFMA16(a0, dbh[0], acc);
                acc = MFMA16(a1, dbh[1], acc);
                #pragma unroll
                for (int i = 0; i < 4; ++i) {
                    int pr = rt * 16 + lkb * 4 + i;
                    int q = pr >> 3, row = pr & 7;
                    recon[((size_t)(t0 + q) * 4096 + b0 + row) * 64 + colD] = acc[i] + dbo;
                }
            }
        }
        yv0 = yn0; yv1 = yn1; yv2 = yn2;
    }
#undef FEVAL
}

extern "C" void kernel_launch(void* const* d_in, const int* in_sizes, int n_in,
                              void* d_out, int out_size, void* d_ws, size_t ws_size,
                              hipStream_t stream)
{
    const float* obs   = (const float*)d_in[0];
    const float* eps   = (const float*)d_in[1];
    const float* Wih   = (const float*)d_in[2];
    const float* Whh   = (const float*)d_in[3];
    const float* bih   = (const float*)d_in[4];
    const float* bhh   = (const float*)d_in[5];
    const float* meanW = (const float*)d_in[6];
    const float* meanB = (const float*)d_in[7];
    const float* lvW   = (const float*)d_in[8];
    const float* lvB   = (const float*)d_in[9];
    const float* dW1   = (const float*)d_in[10];
    const float* db1   = (const float*)d_in[11];
    const float* dW2   = (const float*)d_in[12];
    const float* db2   = (const float*)d_in[13];
    const float* dW3   = (const float*)d_in[14];
    const float* db3   = (const float*)d_in[15];
    const float* decW1 = (const float*)d_in[16];
    const float* decb1 = (const float*)d_in[17];
    const float* decW2 = (const float*)d_in[18];
    const float* decb2 = (const float*)d_in[19];

    float* out   = (float*)d_out;
    float* recon = out;
    float* omean = out + OFF_MEAN;
    float* olv   = out + OFF_LV;
    float* traj  = out + OFF_TRAJ;
    float* z0    = (float*)d_ws;

    k_gru<<<dim3(256), dim3(512), 0, stream>>>(obs, eps, Wih, Whh, bih, bhh,
                                               meanW, meanB, lvW, lvB, omean, olv, z0);
    k_odec<<<dim3(512), dim3(256), 0, stream>>>(dW1, db1, dW2, db2, dW3, db3,
                                                decW1, decb1, decW2, decb2,
                                                z0, traj, recon);
}